// Round 2
// baseline (2351.668 us; speedup 1.0000x reference)
//
#include <hip/hip_runtime.h>
#include <math.h>

#define NN 4096
#define NE 131072

__device__ __forceinline__ float lrelu_f(float x) { return x > 0.0f ? x : 0.01f * x; }

// ---------------- GEMM: O[M,P] = act(A)[M,K] @ W[K,P] + b ----------------
template<bool RELU_A>
__global__ __launch_bounds__(256) void gemm_kernel(const float* __restrict__ A,
    const float* __restrict__ W, const float* __restrict__ bias,
    float* __restrict__ O, int K, int P) {
  __shared__ float As[64][33];
  __shared__ float Ws[32][65];
  int i0 = blockIdx.x * 64, n0 = blockIdx.y * 64;
  int t = threadIdx.x, ty = t >> 4, tx = t & 15;
  float acc[4][4] = {};
  for (int k0 = 0; k0 < K; k0 += 32) {
    __syncthreads();
    for (int idx = t; idx < 64 * 32; idx += 256) {
      int r = idx >> 5, k = idx & 31;
      float v = A[(size_t)(i0 + r) * K + k0 + k];
      if (RELU_A) v = fmaxf(v, 0.0f);
      As[r][k] = v;
    }
    for (int idx = t; idx < 32 * 64; idx += 256) {
      int k = idx >> 6, n = idx & 63;
      Ws[k][n] = W[(size_t)(k0 + k) * P + n0 + n];
    }
    __syncthreads();
    for (int k = 0; k < 32; ++k) {
      float a[4], b[4];
      #pragma unroll
      for (int q = 0; q < 4; ++q) a[q] = As[4 * ty + q][k];
      #pragma unroll
      for (int p = 0; p < 4; ++p) b[p] = Ws[k][4 * tx + p];
      #pragma unroll
      for (int q = 0; q < 4; ++q)
        #pragma unroll
        for (int p = 0; p < 4; ++p) acc[q][p] = fmaf(a[q], b[p], acc[q][p]);
    }
  }
  #pragma unroll
  for (int q = 0; q < 4; ++q)
    #pragma unroll
    for (int p = 0; p < 4; ++p)
      O[(size_t)(i0 + 4 * ty + q) * P + n0 + 4 * tx + p] = acc[q][p] + bias[n0 + 4 * tx + p];
}

// ---------------- row stats: inv_norm, al, ar ----------------
template<int DH>
__global__ __launch_bounds__(256) void rowstats_kernel(const float* __restrict__ h,
    const float* __restrict__ aw, float* __restrict__ al, float* __restrict__ ar,
    float* __restrict__ inv) {
  constexpr int NC = DH / 64;
  int wid = threadIdx.x >> 6, lane = threadIdx.x & 63;
  int i = blockIdx.x * 4 + wid;
  float s2 = 0.f, sl = 0.f, sr = 0.f;
  #pragma unroll
  for (int c = 0; c < NC; ++c) {
    float x = h[(size_t)i * DH + c * 64 + lane];
    s2 = fmaf(x, x, s2);
    sl = fmaf(x, aw[c * 64 + lane], sl);
    sr = fmaf(x, aw[DH + c * 64 + lane], sr);
  }
  #pragma unroll
  for (int m = 32; m > 0; m >>= 1) {
    s2 += __shfl_xor(s2, m);
    sl += __shfl_xor(sl, m);
    sr += __shfl_xor(sr, m);
  }
  if (lane == 0) { al[i] = sl; ar[i] = sr; inv[i] = rsqrtf(s2); }
}

// ---------------- column sum ----------------
template<int DH>
__global__ void colsum_kernel(const float* __restrict__ h, float* __restrict__ cs) {
  int d = threadIdx.x;             // blockDim == DH
  int r0 = blockIdx.x * (NN / 32);
  float s = 0.f;
  for (int i = 0; i < NN / 32; ++i) s += h[(size_t)(r0 + i) * DH + d];
  atomicAdd(&cs[d], s);
}

// ---------------- CSR build ----------------
__global__ void hist_kernel(const int* __restrict__ src, int* __restrict__ counts) {
  int e = blockIdx.x * 256 + threadIdx.x;
  atomicAdd(&counts[src[e]], 1);
}

__global__ __launch_bounds__(1024) void scan_kernel(const int* __restrict__ counts,
    int* __restrict__ offsets, int* __restrict__ cursor) {
  __shared__ int part[1024];
  int t = threadIdx.x;
  int v[4]; int run = 0;
  #pragma unroll
  for (int j = 0; j < 4; ++j) { v[j] = counts[4 * t + j]; run += v[j]; }
  part[t] = run;
  __syncthreads();
  for (int off = 1; off < 1024; off <<= 1) {
    int y = (t >= off) ? part[t - off] : 0;
    __syncthreads();
    part[t] += y;
    __syncthreads();
  }
  int base = part[t] - run;
  #pragma unroll
  for (int j = 0; j < 4; ++j) { offsets[4 * t + j] = base; cursor[4 * t + j] = base; base += v[j]; }
  if (t == 1023) offsets[NN] = base;
}

__global__ void scatter_kernel(const int* __restrict__ src, const int* __restrict__ dst,
    const float* __restrict__ al, const float* __restrict__ ar, const float* __restrict__ ab,
    float* __restrict__ denom, int* __restrict__ cursor,
    int* __restrict__ dstS, float* __restrict__ eS) {
  int e = blockIdx.x * 256 + threadIdx.x;
  int s = src[e], d = dst[e];
  float v = expf(lrelu_f(al[s] + ar[d] + ab[0]));
  atomicAdd(&denom[s], v);
  int p = atomicAdd(&cursor[s], 1);
  dstS[p] = d; eS[p] = v;
}

// ---------------- edge-branch gather: o = 0.5 * nbr ----------------
template<int DH>
__global__ __launch_bounds__(256) void gather_kernel(const float* __restrict__ h,
    const int* __restrict__ offsets, const int* __restrict__ dstS,
    const float* __restrict__ eS, const float* __restrict__ denom,
    float* __restrict__ o) {
  constexpr int NC = DH / 64;
  int wid = threadIdx.x >> 6, lane = threadIdx.x & 63;
  int i = blockIdx.x * 4 + wid;
  int beg = offsets[i], end = offsets[i + 1];
  float rd = (beg < end) ? 1.0f / denom[i] : 0.0f;
  float acc[NC] = {};
  for (int k = beg; k < end; ++k) {
    int d = dstS[k];
    float a = eS[k] * rd;
    #pragma unroll
    for (int c = 0; c < NC; ++c)
      acc[c] = fmaf(a, h[(size_t)d * DH + c * 64 + lane], acc[c]);
  }
  #pragma unroll
  for (int c = 0; c < NC; ++c)
    o[(size_t)i * DH + c * 64 + lane] = 0.5f * acc[c];
}

// ---------------- fused dense attention ----------------
// Partial-store variant: each (i-tile, js) block writes 0.5*(Delta@h) tile into
// outp[js][N][DH] with plain coalesced-ish stores. No atomics.
// ATOMIC variant (fallback for tiny ws): old behavior, atomicAdd into o.
template<int DH, int JSPLIT, bool ATOMIC>
__global__ __launch_bounds__(256, 4) void dense_kernel(const float* __restrict__ h,
    const float* __restrict__ al, const float* __restrict__ ar,
    const float* __restrict__ inv, const float* __restrict__ cs,
    const float* __restrict__ ab, float* __restrict__ outp) {
  constexpr int NKC = DH / 64;
  constexpr int TILES = (NN / 64) / JSPLIT;
  __shared__ float AT[64][68];   // phase A: [k][r] Hi chunk; phase B: [r][j] Delta tile
  __shared__ float BT[64][68];   // [k][r] Hj chunk (both phases)
  __shared__ int sflag;
  int i0 = blockIdx.x * 64;
  int js = blockIdx.y;
  int t = threadIdx.x, ty = t >> 4, tx = t & 15;
  float abv = ab[0];
  float acc[4][4 * NKC] = {};
  float ali[4], invi[4];
  #pragma unroll
  for (int q = 0; q < 4; ++q) { ali[q] = al[i0 + 4 * ty + q]; invi[q] = inv[i0 + 4 * ty + q]; }

  for (int jt = 0; jt < TILES; ++jt) {
    int j0 = (js * TILES + jt) * 64;
    if (t == 0) sflag = 0;
    float G[4][4] = {};
    for (int c = 0; c < NKC; ++c) {
      __syncthreads();
      #pragma unroll
      for (int rnd = 0; rnd < 4; ++rnd) {
        int e = rnd * 256 + t;
        int r = e >> 4;
        int k0 = (e & 15) << 2;
        float4 va = *(const float4*)&h[(size_t)(i0 + r) * DH + c * 64 + k0];
        float4 vb = *(const float4*)&h[(size_t)(j0 + r) * DH + c * 64 + k0];
        AT[k0 + 0][r] = va.x; AT[k0 + 1][r] = va.y; AT[k0 + 2][r] = va.z; AT[k0 + 3][r] = va.w;
        BT[k0 + 0][r] = vb.x; BT[k0 + 1][r] = vb.y; BT[k0 + 2][r] = vb.z; BT[k0 + 3][r] = vb.w;
      }
      __syncthreads();
      for (int k = 0; k < 64; ++k) {
        float4 a4 = *(const float4*)&AT[k][4 * ty];
        float4 b4 = *(const float4*)&BT[k][4 * tx];
        float a[4] = {a4.x, a4.y, a4.z, a4.w};
        float b[4] = {b4.x, b4.y, b4.z, b4.w};
        #pragma unroll
        for (int q = 0; q < 4; ++q)
          #pragma unroll
          for (int p = 0; p < 4; ++p) G[q][p] = fmaf(a[q], b[p], G[q][p]);
      }
    }
    __syncthreads();   // all phase-A reads of AT done; safe to overwrite with Delta
    // transform G -> Delta weights in place
    float arj[4], invj[4];
    #pragma unroll
    for (int p = 0; p < 4; ++p) { arj[p] = ar[j0 + 4 * tx + p]; invj[p] = inv[j0 + 4 * tx + p]; }
    int lany = 0;
    #pragma unroll
    for (int q = 0; q < 4; ++q)
      #pragma unroll
      for (int p = 0; p < 4; ++p) {
        float C = G[q][p] * invi[q] * invj[p];
        float wv = 0.0f;
        if (C > 0.36f) { lany = 1; wv = expm1f(C * lrelu_f(ali[q] + arj[p] + abv)); }
        G[q][p] = wv;
      }
    if (lany) atomicOr(&sflag, 1);
    #pragma unroll
    for (int q = 0; q < 4; ++q)
      *(float4*)&AT[4 * ty + q][4 * tx] = make_float4(G[q][0], G[q][1], G[q][2], G[q][3]);
    __syncthreads();   // Delta tile + sflag visible to all
    if (sflag) {
      for (int c = 0; c < NKC; ++c) {
        __syncthreads();
        #pragma unroll
        for (int rnd = 0; rnd < 4; ++rnd) {
          int e = rnd * 256 + t;
          int r = e >> 4;
          int k0 = (e & 15) << 2;
          float4 vb = *(const float4*)&h[(size_t)(j0 + r) * DH + c * 64 + k0];
          BT[k0 + 0][r] = vb.x; BT[k0 + 1][r] = vb.y; BT[k0 + 2][r] = vb.z; BT[k0 + 3][r] = vb.w;
        }
        __syncthreads();
        for (int jj = 0; jj < 64; jj += 4) {
          float4 wv[4], hv[4];
          #pragma unroll
          for (int q = 0; q < 4; ++q) wv[q] = *(const float4*)&AT[4 * ty + q][jj];
          #pragma unroll
          for (int p = 0; p < 4; ++p) hv[p] = *(const float4*)&BT[tx + 16 * p][jj];
          #pragma unroll
          for (int q = 0; q < 4; ++q)
            #pragma unroll
            for (int p = 0; p < 4; ++p) {
              acc[q][4 * c + p] = fmaf(wv[q].x, hv[p].x, acc[q][4 * c + p]);
              acc[q][4 * c + p] = fmaf(wv[q].y, hv[p].y, acc[q][4 * c + p]);
              acc[q][4 * c + p] = fmaf(wv[q].z, hv[p].z, acc[q][4 * c + p]);
              acc[q][4 * c + p] = fmaf(wv[q].w, hv[p].w, acc[q][4 * c + p]);
            }
        }
      }
    }
  }
  // epilogue
  if (ATOMIC) {
    #pragma unroll
    for (int q = 0; q < 4; ++q) {
      int i = i0 + 4 * ty + q;
      #pragma unroll
      for (int c = 0; c < NKC; ++c)
        #pragma unroll
        for (int p = 0; p < 4; ++p) {
          int d = c * 64 + tx + 16 * p;
          float add = 0.5f * acc[q][4 * c + p];
          if (js == 0) add += h[(size_t)i * DH + d] + 0.5f * cs[d];
          atomicAdd(&outp[(size_t)i * DH + d], add);
        }
    }
  } else {
    float* po = outp + (size_t)js * NN * DH;
    #pragma unroll
    for (int q = 0; q < 4; ++q) {
      int i = i0 + 4 * ty + q;
      #pragma unroll
      for (int c = 0; c < NKC; ++c)
        #pragma unroll
        for (int p = 0; p < 4; ++p) {
          int d = c * 64 + tx + 16 * p;
          po[(size_t)i * DH + d] = 0.5f * acc[q][4 * c + p];
        }
    }
  }
}

// ---------------- reduce partials: o += h + 0.5*cs + 0.5*sum_js parts ----------------
template<int DH>
__global__ __launch_bounds__(256) void reduce_kernel(const float* __restrict__ h,
    const float* __restrict__ cs, const float* __restrict__ parts, int JS,
    float* __restrict__ o) {
  int idx = blockIdx.x * 256 + threadIdx.x;   // over NN*DH
  int d = idx & (DH - 1);
  float s = 0.f;
  for (int js = 0; js < JS; ++js) s += parts[(size_t)js * NN * DH + idx];
  o[idx] = o[idx] + h[idx] + 0.5f * cs[d] + s;   // parts already carry the 0.5 factor
}

// ---------------- final row-normalize (in place on d_out) ----------------
__global__ __launch_bounds__(256) void norm_kernel(float* __restrict__ out) {
  int wid = threadIdx.x >> 6, lane = threadIdx.x & 63;
  int i = blockIdx.x * 4 + wid;
  float x = out[(size_t)i * 64 + lane];
  float s = x * x;
  #pragma unroll
  for (int m = 32; m > 0; m >>= 1) s += __shfl_xor(s, m);
  float n = sqrtf(s);
  out[(size_t)i * 64 + lane] = x / fmaxf(n, 1e-12f);
}

// ---------------- host-side orchestration ----------------
struct Scratch {
  float *al, *ar, *inv, *denom, *cs, *eS;
  int *counts, *offsets, *cursor, *dstS;
  float *parts;   // JS partial buffers, each NN*DH floats (DH<=256)
  int JS;         // 0 => atomic fallback
};

template<int DH>
static void run_attention(const float* h, const float* aw, const float* ab, float* o,
                          const int* src, const int* dst, const Scratch& S, hipStream_t stream) {
  rowstats_kernel<DH><<<NN / 4, 256, 0, stream>>>(h, aw, S.al, S.ar, S.inv);
  hipMemsetAsync(S.cs, 0, DH * sizeof(float), stream);
  colsum_kernel<DH><<<32, DH, 0, stream>>>(h, S.cs);
  hipMemsetAsync(S.counts, 0, NN * sizeof(int), stream);
  hist_kernel<<<NE / 256, 256, 0, stream>>>(src, S.counts);
  scan_kernel<<<1, 1024, 0, stream>>>(S.counts, S.offsets, S.cursor);
  hipMemsetAsync(S.denom, 0, NN * sizeof(float), stream);
  scatter_kernel<<<NE / 256, 256, 0, stream>>>(src, dst, S.al, S.ar, ab,
                                               S.denom, S.cursor, S.dstS, S.eS);
  gather_kernel<DH><<<NN / 4, 256, 0, stream>>>(h, S.offsets, S.dstS, S.eS, S.denom, o);
  if (S.JS == 16) {
    dense_kernel<DH, 16, false><<<dim3(NN / 64, 16), 256, 0, stream>>>(
        h, S.al, S.ar, S.inv, S.cs, ab, S.parts);
    reduce_kernel<DH><<<NN * DH / 256, 256, 0, stream>>>(h, S.cs, S.parts, 16, o);
  } else if (S.JS == 8) {
    dense_kernel<DH, 8, false><<<dim3(NN / 64, 8), 256, 0, stream>>>(
        h, S.al, S.ar, S.inv, S.cs, ab, S.parts);
    reduce_kernel<DH><<<NN * DH / 256, 256, 0, stream>>>(h, S.cs, S.parts, 8, o);
  } else {
    dense_kernel<DH, 8, true><<<dim3(NN / 64, 8), 256, 0, stream>>>(
        h, S.al, S.ar, S.inv, S.cs, ab, o);
  }
}

extern "C" void kernel_launch(void* const* d_in, const int* in_sizes, int n_in,
                              void* d_out, int out_size, void* d_ws, size_t ws_size,
                              hipStream_t stream) {
  const float* X   = (const float*)d_in[0];
  const int*   ei  = (const int*)d_in[1];
  const float* W1  = (const float*)d_in[2];
  const float* b1  = (const float*)d_in[3];
  const float* a1w = (const float*)d_in[4];
  const float* a1b = (const float*)d_in[5];
  const float* W2  = (const float*)d_in[6];
  const float* b2  = (const float*)d_in[7];
  const float* a2w = (const float*)d_in[8];
  const float* a2b = (const float*)d_in[9];
  const float* W3  = (const float*)d_in[10];
  const float* b3  = (const float*)d_in[11];
  float* out = (float*)d_out;

  const int* src = ei;
  const int* dst = ei + NE;

  float* fws = (float*)d_ws;
  float* h1 = fws;                 // 4096*256
  float* o1 = h1 + 1048576;        // 4096*256
  float* h2 = o1 + 1048576;        // 4096*128
  float* o2 = h2 + 524288;         // 4096*128
  Scratch S;
  S.al    = o2 + 524288;
  S.ar    = S.al + NN;
  S.inv   = S.ar + NN;
  S.denom = S.inv + NN;
  S.cs    = S.denom + NN;          // 256 max
  S.eS    = S.cs + 256;            // NE
  S.counts  = (int*)(S.eS + NE);   // NN
  S.offsets = S.counts + NN;       // NN+1
  S.cursor  = S.offsets + NN + 1;  // NN
  S.dstS    = S.cursor + NN;       // NE

  size_t used = (size_t)((char*)(S.dstS + NE) - (char*)d_ws);
  used = (used + 255) & ~(size_t)255;
  size_t perPart = (size_t)NN * 256 * sizeof(float);   // sized for max DH
  if (used + 16 * perPart <= ws_size)      S.JS = 16;
  else if (used + 8 * perPart <= ws_size)  S.JS = 8;
  else                                     S.JS = 0;
  S.parts = (float*)((char*)d_ws + used);

  // layer 1
  gemm_kernel<false><<<dim3(NN / 64, 256 / 64), 256, 0, stream>>>(X, W1, b1, h1, 128, 256);
  run_attention<256>(h1, a1w, a1b, o1, src, dst, S, stream);
  // layer 2
  gemm_kernel<true><<<dim3(NN / 64, 128 / 64), 256, 0, stream>>>(o1, W2, b2, h2, 256, 128);
  run_attention<128>(h2, a2w, a2b, o2, src, dst, S, stream);
  // output layer + normalize
  gemm_kernel<true><<<dim3(NN / 64, 64 / 64), 256, 0, stream>>>(o2, W3, b3, out, 128, 64);
  norm_kernel<<<NN / 4, 256, 0, stream>>>(out);
}

// Round 3
// 645.293 us; speedup vs baseline: 3.6443x; 3.6443x over previous
//
#include <hip/hip_runtime.h>
#include <math.h>

#define NN 4096
#define NE 131072

__device__ __forceinline__ float lrelu_f(float x) { return x > 0.0f ? x : 0.01f * x; }

// ---------------- GEMM: O[M,P] = act(A)[M,K] @ W[K,P] + b ----------------
template<bool RELU_A>
__global__ __launch_bounds__(256) void gemm_kernel(const float* __restrict__ A,
    const float* __restrict__ W, const float* __restrict__ bias,
    float* __restrict__ O, int K, int P) {
  __shared__ float As[64][33];
  __shared__ float Ws[32][65];
  int i0 = blockIdx.x * 64, n0 = blockIdx.y * 64;
  int t = threadIdx.x, ty = t >> 4, tx = t & 15;
  float acc[4][4] = {};
  for (int k0 = 0; k0 < K; k0 += 32) {
    __syncthreads();
    for (int idx = t; idx < 64 * 32; idx += 256) {
      int r = idx >> 5, k = idx & 31;
      float v = A[(size_t)(i0 + r) * K + k0 + k];
      if (RELU_A) v = fmaxf(v, 0.0f);
      As[r][k] = v;
    }
    for (int idx = t; idx < 32 * 64; idx += 256) {
      int k = idx >> 6, n = idx & 63;
      Ws[k][n] = W[(size_t)(k0 + k) * P + n0 + n];
    }
    __syncthreads();
    for (int k = 0; k < 32; ++k) {
      float a[4], b[4];
      #pragma unroll
      for (int q = 0; q < 4; ++q) a[q] = As[4 * ty + q][k];
      #pragma unroll
      for (int p = 0; p < 4; ++p) b[p] = Ws[k][4 * tx + p];
      #pragma unroll
      for (int q = 0; q < 4; ++q)
        #pragma unroll
        for (int p = 0; p < 4; ++p) acc[q][p] = fmaf(a[q], b[p], acc[q][p]);
    }
  }
  #pragma unroll
  for (int q = 0; q < 4; ++q)
    #pragma unroll
    for (int p = 0; p < 4; ++p)
      O[(size_t)(i0 + 4 * ty + q) * P + n0 + 4 * tx + p] = acc[q][p] + bias[n0 + 4 * tx + p];
}

// ---------------- row stats: inv_norm, al, ar ----------------
template<int DH>
__global__ __launch_bounds__(256) void rowstats_kernel(const float* __restrict__ h,
    const float* __restrict__ aw, float* __restrict__ al, float* __restrict__ ar,
    float* __restrict__ inv) {
  constexpr int NC = DH / 64;
  int wid = threadIdx.x >> 6, lane = threadIdx.x & 63;
  int i = blockIdx.x * 4 + wid;
  float s2 = 0.f, sl = 0.f, sr = 0.f;
  #pragma unroll
  for (int c = 0; c < NC; ++c) {
    float x = h[(size_t)i * DH + c * 64 + lane];
    s2 = fmaf(x, x, s2);
    sl = fmaf(x, aw[c * 64 + lane], sl);
    sr = fmaf(x, aw[DH + c * 64 + lane], sr);
  }
  #pragma unroll
  for (int m = 32; m > 0; m >>= 1) {
    s2 += __shfl_xor(s2, m);
    sl += __shfl_xor(sl, m);
    sr += __shfl_xor(sr, m);
  }
  if (lane == 0) { al[i] = sl; ar[i] = sr; inv[i] = rsqrtf(s2); }
}

// ---------------- column sum ----------------
template<int DH>
__global__ void colsum_kernel(const float* __restrict__ h, float* __restrict__ cs) {
  int d = threadIdx.x;             // blockDim == DH
  int r0 = blockIdx.x * (NN / 32);
  float s = 0.f;
  for (int i = 0; i < NN / 32; ++i) s += h[(size_t)(r0 + i) * DH + d];
  atomicAdd(&cs[d], s);
}

// ---------------- CSR build ----------------
__global__ void hist_kernel(const int* __restrict__ src, int* __restrict__ counts) {
  int e = blockIdx.x * 256 + threadIdx.x;
  atomicAdd(&counts[src[e]], 1);
}

__global__ __launch_bounds__(1024) void scan_kernel(const int* __restrict__ counts,
    int* __restrict__ offsets, int* __restrict__ cursor) {
  __shared__ int part[1024];
  int t = threadIdx.x;
  int v[4]; int run = 0;
  #pragma unroll
  for (int j = 0; j < 4; ++j) { v[j] = counts[4 * t + j]; run += v[j]; }
  part[t] = run;
  __syncthreads();
  for (int off = 1; off < 1024; off <<= 1) {
    int y = (t >= off) ? part[t - off] : 0;
    __syncthreads();
    part[t] += y;
    __syncthreads();
  }
  int base = part[t] - run;
  #pragma unroll
  for (int j = 0; j < 4; ++j) { offsets[4 * t + j] = base; cursor[4 * t + j] = base; base += v[j]; }
  if (t == 1023) offsets[NN] = base;
}

__global__ void scatter_kernel(const int* __restrict__ src, const int* __restrict__ dst,
    const float* __restrict__ al, const float* __restrict__ ar, const float* __restrict__ ab,
    float* __restrict__ denom, int* __restrict__ cursor,
    int* __restrict__ dstS, float* __restrict__ eS) {
  int e = blockIdx.x * 256 + threadIdx.x;
  int s = src[e], d = dst[e];
  float v = expf(lrelu_f(al[s] + ar[d] + ab[0]));
  atomicAdd(&denom[s], v);
  int p = atomicAdd(&cursor[s], 1);
  dstS[p] = d; eS[p] = v;
}

// ---------------- edge-branch gather: o = 0.5 * nbr ----------------
template<int DH>
__global__ __launch_bounds__(256) void gather_kernel(const float* __restrict__ h,
    const int* __restrict__ offsets, const int* __restrict__ dstS,
    const float* __restrict__ eS, const float* __restrict__ denom,
    float* __restrict__ o) {
  constexpr int NC = DH / 64;
  int wid = threadIdx.x >> 6, lane = threadIdx.x & 63;
  int i = blockIdx.x * 4 + wid;
  int beg = offsets[i], end = offsets[i + 1];
  float rd = (beg < end) ? 1.0f / denom[i] : 0.0f;
  float acc[NC] = {};
  for (int k = beg; k < end; ++k) {
    int d = dstS[k];
    float a = eS[k] * rd;
    #pragma unroll
    for (int c = 0; c < NC; ++c)
      acc[c] = fmaf(a, h[(size_t)d * DH + c * 64 + lane], acc[c]);
  }
  #pragma unroll
  for (int c = 0; c < NC; ++c)
    o[(size_t)i * DH + c * 64 + lane] = 0.5f * acc[c];
}

// ---------------- fused dense attention ----------------
// Staged tiles use an XOR column-block swizzle: element (row k, col r) lives at
// column ((r>>2) ^ (k>>2))*4 + (r&3). Staging writes go from 8-way to 2-way
// bank conflicts; reads apply the same XOR (both-sides-or-neither).
template<int DH, int JSPLIT, bool ATOMIC>
__global__ __launch_bounds__(256, 2) void dense_kernel(const float* __restrict__ h,
    const float* __restrict__ al, const float* __restrict__ ar,
    const float* __restrict__ inv, const float* __restrict__ cs,
    const float* __restrict__ ab, float* __restrict__ outp) {
  constexpr int NKC = DH / 64;
  constexpr int TILES = (NN / 64) / JSPLIT;
  __shared__ float AT[64][68];   // phase A: [k][swz r] Hi chunk; phase B: [r][j] Delta (linear)
  __shared__ float BT[64][68];   // [k][swz r] Hj chunk (both phases)
  __shared__ int sflag;
  int i0 = blockIdx.x * 64;
  int js = blockIdx.y;
  int t = threadIdx.x, ty = t >> 4, tx = t & 15;
  float abv = ab[0];
  float acc[4][4 * NKC] = {};
  float ali[4], invi[4];
  #pragma unroll
  for (int q = 0; q < 4; ++q) { ali[q] = al[i0 + 4 * ty + q]; invi[q] = inv[i0 + 4 * ty + q]; }

  for (int jt = 0; jt < TILES; ++jt) {
    int j0 = (js * TILES + jt) * 64;
    if (t == 0) sflag = 0;
    float G[4][4] = {};
    for (int c = 0; c < NKC; ++c) {
      __syncthreads();
      #pragma unroll
      for (int rnd = 0; rnd < 4; ++rnd) {
        int e = rnd * 256 + t;
        int r = e >> 4;
        int kb = e & 15;
        int k0 = kb << 2;
        int ccol = (((r >> 2) ^ kb) << 2) | (r & 3);   // swizzled column
        float4 va = *(const float4*)&h[(size_t)(i0 + r) * DH + c * 64 + k0];
        float4 vb = *(const float4*)&h[(size_t)(j0 + r) * DH + c * 64 + k0];
        AT[k0 + 0][ccol] = va.x; AT[k0 + 1][ccol] = va.y; AT[k0 + 2][ccol] = va.z; AT[k0 + 3][ccol] = va.w;
        BT[k0 + 0][ccol] = vb.x; BT[k0 + 1][ccol] = vb.y; BT[k0 + 2][ccol] = vb.z; BT[k0 + 3][ccol] = vb.w;
      }
      __syncthreads();
      for (int k = 0; k < 64; ++k) {
        int kb = k >> 2;
        float4 a4 = *(const float4*)&AT[k][4 * (ty ^ kb)];
        float4 b4 = *(const float4*)&BT[k][4 * (tx ^ kb)];
        float a[4] = {a4.x, a4.y, a4.z, a4.w};
        float b[4] = {b4.x, b4.y, b4.z, b4.w};
        #pragma unroll
        for (int q = 0; q < 4; ++q)
          #pragma unroll
          for (int p = 0; p < 4; ++p) G[q][p] = fmaf(a[q], b[p], G[q][p]);
      }
    }
    __syncthreads();   // all phase-A reads of AT done; safe to overwrite with Delta
    // transform G -> Delta weights in place
    float arj[4], invj[4];
    #pragma unroll
    for (int p = 0; p < 4; ++p) { arj[p] = ar[j0 + 4 * tx + p]; invj[p] = inv[j0 + 4 * tx + p]; }
    int lany = 0;
    #pragma unroll
    for (int q = 0; q < 4; ++q)
      #pragma unroll
      for (int p = 0; p < 4; ++p) {
        float C = G[q][p] * invi[q] * invj[p];
        float wv = 0.0f;
        if (C > 0.36f) { lany = 1; wv = expm1f(C * lrelu_f(ali[q] + arj[p] + abv)); }
        G[q][p] = wv;
      }
    if (lany) atomicOr(&sflag, 1);
    #pragma unroll
    for (int q = 0; q < 4; ++q)
      *(float4*)&AT[4 * ty + q][4 * tx] = make_float4(G[q][0], G[q][1], G[q][2], G[q][3]);
    __syncthreads();   // Delta tile + sflag visible to all
    if (sflag) {
      for (int c = 0; c < NKC; ++c) {
        __syncthreads();
        #pragma unroll
        for (int rnd = 0; rnd < 4; ++rnd) {
          int e = rnd * 256 + t;
          int r = e >> 4;
          int kb = e & 15;
          int k0 = kb << 2;
          int ccol = (((r >> 2) ^ kb) << 2) | (r & 3);
          float4 vb = *(const float4*)&h[(size_t)(j0 + r) * DH + c * 64 + k0];
          BT[k0 + 0][ccol] = vb.x; BT[k0 + 1][ccol] = vb.y; BT[k0 + 2][ccol] = vb.z; BT[k0 + 3][ccol] = vb.w;
        }
        __syncthreads();
        for (int jj = 0; jj < 64; jj += 4) {
          int jb = jj >> 2;
          float4 wv[4], hv[4];
          #pragma unroll
          for (int q = 0; q < 4; ++q) wv[q] = *(const float4*)&AT[4 * ty + q][jj];
          #pragma unroll
          for (int p = 0; p < 4; ++p) {
            int row = tx + 16 * p;
            hv[p] = *(const float4*)&BT[row][4 * (jb ^ (row >> 2))];
          }
          #pragma unroll
          for (int q = 0; q < 4; ++q)
            #pragma unroll
            for (int p = 0; p < 4; ++p) {
              acc[q][4 * c + p] = fmaf(wv[q].x, hv[p].x, acc[q][4 * c + p]);
              acc[q][4 * c + p] = fmaf(wv[q].y, hv[p].y, acc[q][4 * c + p]);
              acc[q][4 * c + p] = fmaf(wv[q].z, hv[p].z, acc[q][4 * c + p]);
              acc[q][4 * c + p] = fmaf(wv[q].w, hv[p].w, acc[q][4 * c + p]);
            }
        }
      }
    }
  }
  // epilogue
  if (ATOMIC) {
    #pragma unroll
    for (int q = 0; q < 4; ++q) {
      int i = i0 + 4 * ty + q;
      #pragma unroll
      for (int c = 0; c < NKC; ++c)
        #pragma unroll
        for (int p = 0; p < 4; ++p) {
          int d = c * 64 + tx + 16 * p;
          float add = 0.5f * acc[q][4 * c + p];
          if (js == 0) add += h[(size_t)i * DH + d] + 0.5f * cs[d];
          atomicAdd(&outp[(size_t)i * DH + d], add);
        }
    }
  } else {
    float* po = outp + (size_t)js * NN * DH;
    #pragma unroll
    for (int q = 0; q < 4; ++q) {
      int i = i0 + 4 * ty + q;
      #pragma unroll
      for (int c = 0; c < NKC; ++c)
        #pragma unroll
        for (int p = 0; p < 4; ++p) {
          int d = c * 64 + tx + 16 * p;
          po[(size_t)i * DH + d] = 0.5f * acc[q][4 * c + p];
        }
    }
  }
}

// ---------------- reduce partials: o += h + 0.5*cs + sum_js parts ----------------
template<int DH>
__global__ __launch_bounds__(256) void reduce_kernel(const float* __restrict__ h,
    const float* __restrict__ cs, const float* __restrict__ parts, int JS,
    float* __restrict__ o) {
  int idx = blockIdx.x * 256 + threadIdx.x;   // over NN*DH
  int d = idx & (DH - 1);
  float s = 0.f;
  for (int js = 0; js < JS; ++js) s += parts[(size_t)js * NN * DH + idx];
  o[idx] = o[idx] + h[idx] + 0.5f * cs[d] + s;   // parts already carry the 0.5 factor
}

// ---------------- final row-normalize (in place on d_out) ----------------
__global__ __launch_bounds__(256) void norm_kernel(float* __restrict__ out) {
  int wid = threadIdx.x >> 6, lane = threadIdx.x & 63;
  int i = blockIdx.x * 4 + wid;
  float x = out[(size_t)i * 64 + lane];
  float s = x * x;
  #pragma unroll
  for (int m = 32; m > 0; m >>= 1) s += __shfl_xor(s, m);
  float n = sqrtf(s);
  out[(size_t)i * 64 + lane] = x / fmaxf(n, 1e-12f);
}

// ---------------- host-side orchestration ----------------
struct Scratch {
  float *al, *ar, *inv, *denom, *cs, *eS;
  int *counts, *offsets, *cursor, *dstS;
  float *parts;   // JS partial buffers, each NN*DH floats (DH<=256)
  int JS;         // 0 => atomic fallback
};

template<int DH>
static void run_attention(const float* h, const float* aw, const float* ab, float* o,
                          const int* src, const int* dst, const Scratch& S, hipStream_t stream) {
  rowstats_kernel<DH><<<NN / 4, 256, 0, stream>>>(h, aw, S.al, S.ar, S.inv);
  hipMemsetAsync(S.cs, 0, DH * sizeof(float), stream);
  colsum_kernel<DH><<<32, DH, 0, stream>>>(h, S.cs);
  hipMemsetAsync(S.counts, 0, NN * sizeof(int), stream);
  hist_kernel<<<NE / 256, 256, 0, stream>>>(src, S.counts);
  scan_kernel<<<1, 1024, 0, stream>>>(S.counts, S.offsets, S.cursor);
  hipMemsetAsync(S.denom, 0, NN * sizeof(float), stream);
  scatter_kernel<<<NE / 256, 256, 0, stream>>>(src, dst, S.al, S.ar, ab,
                                               S.denom, S.cursor, S.dstS, S.eS);
  gather_kernel<DH><<<NN / 4, 256, 0, stream>>>(h, S.offsets, S.dstS, S.eS, S.denom, o);
  if (S.JS == 16) {
    dense_kernel<DH, 16, false><<<dim3(NN / 64, 16), 256, 0, stream>>>(
        h, S.al, S.ar, S.inv, S.cs, ab, S.parts);
    reduce_kernel<DH><<<NN * DH / 256, 256, 0, stream>>>(h, S.cs, S.parts, 16, o);
  } else if (S.JS == 8) {
    dense_kernel<DH, 8, false><<<dim3(NN / 64, 8), 256, 0, stream>>>(
        h, S.al, S.ar, S.inv, S.cs, ab, S.parts);
    reduce_kernel<DH><<<NN * DH / 256, 256, 0, stream>>>(h, S.cs, S.parts, 8, o);
  } else {
    dense_kernel<DH, 8, true><<<dim3(NN / 64, 8), 256, 0, stream>>>(
        h, S.al, S.ar, S.inv, S.cs, ab, o);
  }
}

extern "C" void kernel_launch(void* const* d_in, const int* in_sizes, int n_in,
                              void* d_out, int out_size, void* d_ws, size_t ws_size,
                              hipStream_t stream) {
  const float* X   = (const float*)d_in[0];
  const int*   ei  = (const int*)d_in[1];
  const float* W1  = (const float*)d_in[2];
  const float* b1  = (const float*)d_in[3];
  const float* a1w = (const float*)d_in[4];
  const float* a1b = (const float*)d_in[5];
  const float* W2  = (const float*)d_in[6];
  const float* b2  = (const float*)d_in[7];
  const float* a2w = (const float*)d_in[8];
  const float* a2b = (const float*)d_in[9];
  const float* W3  = (const float*)d_in[10];
  const float* b3  = (const float*)d_in[11];
  float* out = (float*)d_out;

  const int* src = ei;
  const int* dst = ei + NE;

  float* fws = (float*)d_ws;
  float* h1 = fws;                 // 4096*256
  float* o1 = h1 + 1048576;        // 4096*256
  float* h2 = o1 + 1048576;        // 4096*128
  float* o2 = h2 + 524288;         // 4096*128
  Scratch S;
  S.al    = o2 + 524288;
  S.ar    = S.al + NN;
  S.inv   = S.ar + NN;
  S.denom = S.inv + NN;
  S.cs    = S.denom + NN;          // 256 max
  S.eS    = S.cs + 256;            // NE
  S.counts  = (int*)(S.eS + NE);   // NN
  S.offsets = S.counts + NN;       // NN+1
  S.cursor  = S.offsets + NN + 1;  // NN
  S.dstS    = S.cursor + NN;       // NE

  size_t used = (size_t)((char*)(S.dstS + NE) - (char*)d_ws);
  used = (used + 255) & ~(size_t)255;
  size_t perPart = (size_t)NN * 256 * sizeof(float);   // sized for max DH
  if (used + 16 * perPart <= ws_size)      S.JS = 16;
  else if (used + 8 * perPart <= ws_size)  S.JS = 8;
  else                                     S.JS = 0;
  S.parts = (float*)((char*)d_ws + used);

  // layer 1
  gemm_kernel<false><<<dim3(NN / 64, 256 / 64), 256, 0, stream>>>(X, W1, b1, h1, 128, 256);
  run_attention<256>(h1, a1w, a1b, o1, src, dst, S, stream);
  // layer 2
  gemm_kernel<true><<<dim3(NN / 64, 128 / 64), 256, 0, stream>>>(o1, W2, b2, h2, 256, 128);
  run_attention<128>(h2, a2w, a2b, o2, src, dst, S, stream);
  // output layer + normalize
  gemm_kernel<true><<<dim3(NN / 64, 64 / 64), 256, 0, stream>>>(o2, W3, b3, out, 128, 64);
  norm_kernel<<<NN / 4, 256, 0, stream>>>(out);
}

// Round 4
// 625.709 us; speedup vs baseline: 3.7584x; 1.0313x over previous
//
#include <hip/hip_runtime.h>
#include <math.h>

#define NN 4096
#define NE 131072

typedef short short8 __attribute__((ext_vector_type(8)));
typedef float f32x4 __attribute__((ext_vector_type(4)));
typedef unsigned short u16;

__device__ __forceinline__ float lrelu_f(float x) { return x > 0.0f ? x : 0.01f * x; }

__device__ __forceinline__ u16 f2bf(float x) {
  unsigned int u = __float_as_uint(x);
  unsigned int r = (u + 0x7FFF + ((u >> 16) & 1)) >> 16;   // RNE
  return (u16)r;
}
__device__ __forceinline__ float bf2f(u16 b) { return __uint_as_float(((unsigned int)b) << 16); }

// ---------------- GEMM: O[M,P] = act(A)[M,K] @ W[K,P] + b ----------------
template<bool RELU_A>
__global__ __launch_bounds__(256) void gemm_kernel(const float* __restrict__ A,
    const float* __restrict__ W, const float* __restrict__ bias,
    float* __restrict__ O, int K, int P) {
  __shared__ float As[64][33];
  __shared__ float Ws[32][65];
  int i0 = blockIdx.x * 64, n0 = blockIdx.y * 64;
  int t = threadIdx.x, ty = t >> 4, tx = t & 15;
  float acc[4][4] = {};
  for (int k0 = 0; k0 < K; k0 += 32) {
    __syncthreads();
    for (int idx = t; idx < 64 * 32; idx += 256) {
      int r = idx >> 5, k = idx & 31;
      float v = A[(size_t)(i0 + r) * K + k0 + k];
      if (RELU_A) v = fmaxf(v, 0.0f);
      As[r][k] = v;
    }
    for (int idx = t; idx < 32 * 64; idx += 256) {
      int k = idx >> 6, n = idx & 63;
      Ws[k][n] = W[(size_t)(k0 + k) * P + n0 + n];
    }
    __syncthreads();
    for (int k = 0; k < 32; ++k) {
      float a[4], b[4];
      #pragma unroll
      for (int q = 0; q < 4; ++q) a[q] = As[4 * ty + q][k];
      #pragma unroll
      for (int p = 0; p < 4; ++p) b[p] = Ws[k][4 * tx + p];
      #pragma unroll
      for (int q = 0; q < 4; ++q)
        #pragma unroll
        for (int p = 0; p < 4; ++p) acc[q][p] = fmaf(a[q], b[p], acc[q][p]);
    }
  }
  #pragma unroll
  for (int q = 0; q < 4; ++q)
    #pragma unroll
    for (int p = 0; p < 4; ++p)
      O[(size_t)(i0 + 4 * ty + q) * P + n0 + 4 * tx + p] = acc[q][p] + bias[n0 + 4 * tx + p];
}

// ---------------- row stats: inv_norm, al, ar ----------------
template<int DH>
__global__ __launch_bounds__(256) void rowstats_kernel(const float* __restrict__ h,
    const float* __restrict__ aw, float* __restrict__ al, float* __restrict__ ar,
    float* __restrict__ inv) {
  constexpr int NC = DH / 64;
  int wid = threadIdx.x >> 6, lane = threadIdx.x & 63;
  int i = blockIdx.x * 4 + wid;
  float s2 = 0.f, sl = 0.f, sr = 0.f;
  #pragma unroll
  for (int c = 0; c < NC; ++c) {
    float x = h[(size_t)i * DH + c * 64 + lane];
    s2 = fmaf(x, x, s2);
    sl = fmaf(x, aw[c * 64 + lane], sl);
    sr = fmaf(x, aw[DH + c * 64 + lane], sr);
  }
  #pragma unroll
  for (int m = 32; m > 0; m >>= 1) {
    s2 += __shfl_xor(s2, m);
    sl += __shfl_xor(sl, m);
    sr += __shfl_xor(sr, m);
  }
  if (lane == 0) { al[i] = sl; ar[i] = sr; inv[i] = rsqrtf(s2); }
}

// ---------------- column sum ----------------
template<int DH>
__global__ void colsum_kernel(const float* __restrict__ h, float* __restrict__ cs) {
  int d = threadIdx.x;             // blockDim == DH
  int r0 = blockIdx.x * (NN / 32);
  float s = 0.f;
  for (int i = 0; i < NN / 32; ++i) s += h[(size_t)(r0 + i) * DH + d];
  atomicAdd(&cs[d], s);
}

// ---------------- convert h -> bf16 hi/lo (row-major) ----------------
__global__ __launch_bounds__(256) void convert_kernel(const float* __restrict__ h,
    u16* __restrict__ hhi, u16* __restrict__ hlo) {
  int idx = blockIdx.x * 256 + threadIdx.x;
  float x = h[idx];
  u16 hi = f2bf(x);
  float lo = x - bf2f(hi);
  hhi[idx] = hi;
  hlo[idx] = f2bf(lo);
}

// ---------------- transpose h(fp32 [NN][DH]) -> hT(bf16 [DH][NN]) ----------------
template<int DH>
__global__ __launch_bounds__(256) void transpose_kernel(const float* __restrict__ h,
    u16* __restrict__ hT) {
  __shared__ u16 tile[32][33];
  int bx = blockIdx.x;   // d / 32
  int by = blockIdx.y;   // i / 32
  int t = threadIdx.x, tx = t & 31, ty8 = t >> 5;   // 32 x 8
  #pragma unroll
  for (int r = 0; r < 4; ++r) {
    int i = by * 32 + ty8 + r * 8;
    int d = bx * 32 + tx;
    tile[ty8 + r * 8][tx] = f2bf(h[(size_t)i * DH + d]);
  }
  __syncthreads();
  #pragma unroll
  for (int r = 0; r < 4; ++r) {
    int d = bx * 32 + ty8 + r * 8;
    int i = by * 32 + tx;
    hT[(size_t)d * NN + i] = tile[tx][ty8 + r * 8];
  }
}

// ---------------- CSR build ----------------
__global__ void hist_kernel(const int* __restrict__ src, int* __restrict__ counts) {
  int e = blockIdx.x * 256 + threadIdx.x;
  atomicAdd(&counts[src[e]], 1);
}

__global__ __launch_bounds__(1024) void scan_kernel(const int* __restrict__ counts,
    int* __restrict__ offsets, int* __restrict__ cursor) {
  __shared__ int part[1024];
  int t = threadIdx.x;
  int v[4]; int run = 0;
  #pragma unroll
  for (int j = 0; j < 4; ++j) { v[j] = counts[4 * t + j]; run += v[j]; }
  part[t] = run;
  __syncthreads();
  for (int off = 1; off < 1024; off <<= 1) {
    int y = (t >= off) ? part[t - off] : 0;
    __syncthreads();
    part[t] += y;
    __syncthreads();
  }
  int base = part[t] - run;
  #pragma unroll
  for (int j = 0; j < 4; ++j) { offsets[4 * t + j] = base; cursor[4 * t + j] = base; base += v[j]; }
  if (t == 1023) offsets[NN] = base;
}

__global__ void scatter_kernel(const int* __restrict__ src, const int* __restrict__ dst,
    const float* __restrict__ al, const float* __restrict__ ar, const float* __restrict__ ab,
    float* __restrict__ denom, int* __restrict__ cursor,
    int* __restrict__ dstS, float* __restrict__ eS) {
  int e = blockIdx.x * 256 + threadIdx.x;
  int s = src[e], d = dst[e];
  float v = expf(lrelu_f(al[s] + ar[d] + ab[0]));
  atomicAdd(&denom[s], v);
  int p = atomicAdd(&cursor[s], 1);
  dstS[p] = d; eS[p] = v;
}

// ---------------- edge-branch gather: o = 0.5 * nbr ----------------
template<int DH>
__global__ __launch_bounds__(256) void gather_kernel(const float* __restrict__ h,
    const int* __restrict__ offsets, const int* __restrict__ dstS,
    const float* __restrict__ eS, const float* __restrict__ denom,
    float* __restrict__ o) {
  constexpr int NC = DH / 64;
  int wid = threadIdx.x >> 6, lane = threadIdx.x & 63;
  int i = blockIdx.x * 4 + wid;
  int beg = offsets[i], end = offsets[i + 1];
  float rd = (beg < end) ? 1.0f / denom[i] : 0.0f;
  float acc[NC] = {};
  for (int k = beg; k < end; ++k) {
    int d = dstS[k];
    float a = eS[k] * rd;
    #pragma unroll
    for (int c = 0; c < NC; ++c)
      acc[c] = fmaf(a, h[(size_t)d * DH + c * 64 + lane], acc[c]);
  }
  #pragma unroll
  for (int c = 0; c < NC; ++c)
    o[(size_t)i * DH + c * 64 + lane] = 0.5f * acc[c];
}

// ---------------- Pass 1: QK^T (split bf16 MFMA) -> Delta weights W (bf16) + tile flags ----
// Grid (NN/64, JS). Block 256 = 4 waves; wave w owns i-rows [i0+16w, i0+16w+16).
// mfma_f32_16x16x32_bf16: A/B frag = lane(row/col = l&15, kgrp = l>>4) 8 consecutive k.
// C/D: col = l&15, row = (l>>4)*4 + q.
template<int DH, int JS>
__global__ __launch_bounds__(256) void qk_kernel(
    const u16* __restrict__ hhi, const u16* __restrict__ hlo,
    const float* __restrict__ al, const float* __restrict__ ar,
    const float* __restrict__ inv, const float* __restrict__ ab,
    u16* __restrict__ W, int* __restrict__ flags) {
  constexpr int KC = DH / 32;
  constexpr int JT = (NN / 64) / JS;
  int i0 = blockIdx.x * 64;
  int w = threadIdx.x >> 6, l = threadIdx.x & 63;
  int lr = l & 15, lk = l >> 4;
  int iw = i0 + 16 * w;
  // A-fragments for this wave's 16 i-rows, all K, hi+lo — live in registers all kernel
  short8 Ahi[KC], Alo[KC];
  {
    const u16* arh = hhi + (size_t)(iw + lr) * DH + lk * 8;
    const u16* arl = hlo + (size_t)(iw + lr) * DH + lk * 8;
    #pragma unroll
    for (int c = 0; c < KC; ++c) {
      Ahi[c] = *(const short8*)(arh + 32 * c);
      Alo[c] = *(const short8*)(arl + 32 * c);
    }
  }
  float ali[4], invi[4];
  #pragma unroll
  for (int q = 0; q < 4; ++q) { int i = iw + 4 * lk + q; ali[q] = al[i]; invi[q] = inv[i]; }
  float abv = ab[0];

  for (int jt = 0; jt < JT; ++jt) {
    int j0 = (blockIdx.y * JT + jt) * 64;
    int wany = 0;
    for (int s = 0; s < 4; ++s) {
      int js0 = j0 + 16 * s;
      const u16* brh = hhi + (size_t)(js0 + lr) * DH + lk * 8;
      const u16* brl = hlo + (size_t)(js0 + lr) * DH + lk * 8;
      f32x4 acc = {0.f, 0.f, 0.f, 0.f};
      #pragma unroll
      for (int c = 0; c < KC; ++c) {
        short8 Bhi = *(const short8*)(brh + 32 * c);
        short8 Blo = *(const short8*)(brl + 32 * c);
        acc = __builtin_amdgcn_mfma_f32_16x16x32_bf16(Ahi[c], Bhi, acc, 0, 0, 0);
        acc = __builtin_amdgcn_mfma_f32_16x16x32_bf16(Ahi[c], Blo, acc, 0, 0, 0);
        acc = __builtin_amdgcn_mfma_f32_16x16x32_bf16(Alo[c], Bhi, acc, 0, 0, 0);
      }
      int j = js0 + lr;
      float sv = ar[j] + abv;
      float invj = inv[j];
      #pragma unroll
      for (int q = 0; q < 4; ++q) {
        float C = acc[q] * invi[q] * invj;
        float wv = 0.0f;
        if (C > 0.36f) wv = expm1f(C * lrelu_f(ali[q] + sv));
        if (wv != 0.0f) wany = 1;
        W[(size_t)(iw + 4 * lk + q) * NN + j] = f2bf(wv);
      }
    }
    if (__any(wany) && l == 0) atomicOr(&flags[(i0 >> 6) * 64 + (j0 >> 6)], 1);
  }
}

// ---------------- Pass 2: o += h + 0.5*cs + 0.5*(W @ h), flag-gated ----------------
// Grid (NN/16, DH/64). Block 256 = 4 waves; wave w owns d-cols [dblk*64+16w, +16).
template<int DH>
__global__ __launch_bounds__(256) void pv_kernel(
    const u16* __restrict__ W, const u16* __restrict__ hT,
    const int* __restrict__ flags, const float* __restrict__ h,
    const float* __restrict__ cs, float* __restrict__ o) {
  int ib = blockIdx.x;
  int w = threadIdx.x >> 6, l = threadIdx.x & 63;
  int lr = l & 15, lk = l >> 4;
  int i0 = ib * 16;
  int d0 = blockIdx.y * 64 + w * 16;
  const int* frow = flags + (i0 >> 6) * 64;
  f32x4 acc = {0.f, 0.f, 0.f, 0.f};
  for (int jt = 0; jt < 64; ++jt) {
    if (!frow[jt]) continue;
    int j0 = jt * 64;
    #pragma unroll
    for (int jc = 0; jc < 2; ++jc) {
      short8 a = *(const short8*)&W[(size_t)(i0 + lr) * NN + j0 + jc * 32 + lk * 8];
      short8 b = *(const short8*)&hT[(size_t)(d0 + lr) * NN + j0 + jc * 32 + lk * 8];
      acc = __builtin_amdgcn_mfma_f32_16x16x32_bf16(a, b, acc, 0, 0, 0);
    }
  }
  int d = d0 + lr;
  #pragma unroll
  for (int q = 0; q < 4; ++q) {
    int i = i0 + 4 * lk + q;
    size_t idx = (size_t)i * DH + d;
    o[idx] = o[idx] + h[idx] + 0.5f * cs[d] + 0.5f * acc[q];
  }
}

// ---------------- final row-normalize (in place on d_out) ----------------
__global__ __launch_bounds__(256) void norm_kernel(float* __restrict__ out) {
  int wid = threadIdx.x >> 6, lane = threadIdx.x & 63;
  int i = blockIdx.x * 4 + wid;
  float x = out[(size_t)i * 64 + lane];
  float s = x * x;
  #pragma unroll
  for (int m = 32; m > 0; m >>= 1) s += __shfl_xor(s, m);
  float n = sqrtf(s);
  out[(size_t)i * 64 + lane] = x / fmaxf(n, 1e-12f);
}

// ---------------- host-side orchestration ----------------
struct Scratch {
  float *al, *ar, *inv, *denom, *cs, *eS;
  int *counts, *offsets, *cursor, *dstS, *flags;
  u16 *hhi, *hlo, *hT, *W;
};

template<int DH>
static void run_attention(const float* h, const float* aw, const float* ab, float* o,
                          const int* src, const int* dst, const Scratch& S, hipStream_t stream) {
  rowstats_kernel<DH><<<NN / 4, 256, 0, stream>>>(h, aw, S.al, S.ar, S.inv);
  hipMemsetAsync(S.cs, 0, DH * sizeof(float), stream);
  colsum_kernel<DH><<<32, DH, 0, stream>>>(h, S.cs);
  convert_kernel<<<NN * DH / 256, 256, 0, stream>>>(h, S.hhi, S.hlo);
  transpose_kernel<DH><<<dim3(DH / 32, NN / 32), 256, 0, stream>>>(h, S.hT);
  hipMemsetAsync(S.flags, 0, 4096 * sizeof(int), stream);
  hipMemsetAsync(S.counts, 0, NN * sizeof(int), stream);
  hist_kernel<<<NE / 256, 256, 0, stream>>>(src, S.counts);
  scan_kernel<<<1, 1024, 0, stream>>>(S.counts, S.offsets, S.cursor);
  hipMemsetAsync(S.denom, 0, NN * sizeof(float), stream);
  scatter_kernel<<<NE / 256, 256, 0, stream>>>(src, dst, S.al, S.ar, ab,
                                               S.denom, S.cursor, S.dstS, S.eS);
  gather_kernel<DH><<<NN / 4, 256, 0, stream>>>(h, S.offsets, S.dstS, S.eS, S.denom, o);
  qk_kernel<DH, 16><<<dim3(NN / 64, 16), 256, 0, stream>>>(
      S.hhi, S.hlo, S.al, S.ar, S.inv, ab, S.W, S.flags);
  pv_kernel<DH><<<dim3(NN / 16, DH / 64), 256, 0, stream>>>(
      S.W, S.hT, S.flags, h, S.cs, o);
}

extern "C" void kernel_launch(void* const* d_in, const int* in_sizes, int n_in,
                              void* d_out, int out_size, void* d_ws, size_t ws_size,
                              hipStream_t stream) {
  const float* X   = (const float*)d_in[0];
  const int*   ei  = (const int*)d_in[1];
  const float* W1  = (const float*)d_in[2];
  const float* b1  = (const float*)d_in[3];
  const float* a1w = (const float*)d_in[4];
  const float* a1b = (const float*)d_in[5];
  const float* W2  = (const float*)d_in[6];
  const float* b2  = (const float*)d_in[7];
  const float* a2w = (const float*)d_in[8];
  const float* a2b = (const float*)d_in[9];
  const float* W3  = (const float*)d_in[10];
  const float* b3  = (const float*)d_in[11];
  float* out = (float*)d_out;

  const int* src = ei;
  const int* dst = ei + NE;

  char* p = (char*)d_ws;
  auto alloc = [&](size_t bytes) { char* r = p; p += (bytes + 255) & ~(size_t)255; return r; };
  float* h1 = (float*)alloc((size_t)NN * 256 * 4);
  float* o1 = (float*)alloc((size_t)NN * 256 * 4);
  float* h2 = (float*)alloc((size_t)NN * 128 * 4);
  float* o2 = (float*)alloc((size_t)NN * 128 * 4);
  Scratch S;
  S.hhi = (u16*)alloc((size_t)NN * 256 * 2);
  S.hlo = (u16*)alloc((size_t)NN * 256 * 2);
  S.hT  = (u16*)alloc((size_t)NN * 256 * 2);
  S.W   = (u16*)alloc((size_t)NN * NN * 2);
  S.flags = (int*)alloc(4096 * 4);
  S.al    = (float*)alloc(NN * 4);
  S.ar    = (float*)alloc(NN * 4);
  S.inv   = (float*)alloc(NN * 4);
  S.denom = (float*)alloc(NN * 4);
  S.cs    = (float*)alloc(256 * 4);
  S.eS    = (float*)alloc((size_t)NE * 4);
  S.counts  = (int*)alloc(NN * 4);
  S.offsets = (int*)alloc((NN + 1) * 4);
  S.cursor  = (int*)alloc(NN * 4);
  S.dstS    = (int*)alloc((size_t)NE * 4);

  // layer 1
  gemm_kernel<false><<<dim3(NN / 64, 256 / 64), 256, 0, stream>>>(X, W1, b1, h1, 128, 256);
  run_attention<256>(h1, a1w, a1b, o1, src, dst, S, stream);
  // layer 2
  gemm_kernel<true><<<dim3(NN / 64, 128 / 64), 256, 0, stream>>>(o1, W2, b2, h2, 256, 128);
  run_attention<128>(h2, a2w, a2b, o2, src, dst, S, stream);
  // output layer + normalize
  gemm_kernel<true><<<dim3(NN / 64, 64 / 64), 256, 0, stream>>>(o2, W3, b3, out, 128, 64);
  norm_kernel<<<NN / 4, 256, 0, stream>>>(out);
}

// Round 5
// 623.158 us; speedup vs baseline: 3.7738x; 1.0041x over previous
//
#include <hip/hip_runtime.h>
#include <math.h>

#define NN 4096
#define NE 131072

typedef short short8 __attribute__((ext_vector_type(8)));
typedef float f32x4 __attribute__((ext_vector_type(4)));
typedef unsigned short u16;

__device__ __forceinline__ float lrelu_f(float x) { return x > 0.0f ? x : 0.01f * x; }

__device__ __forceinline__ u16 f2bf(float x) {
  unsigned int u = __float_as_uint(x);
  unsigned int r = (u + 0x7FFF + ((u >> 16) & 1)) >> 16;   // RNE
  return (u16)r;
}
__device__ __forceinline__ float bf2f(u16 b) { return __uint_as_float(((unsigned int)b) << 16); }

// ---------------- GEMM: O[M,P] = act(A)[M,K] @ W[K,P] + b ----------------
template<bool RELU_A>
__global__ __launch_bounds__(256) void gemm_kernel(const float* __restrict__ A,
    const float* __restrict__ W, const float* __restrict__ bias,
    float* __restrict__ O, int K, int P) {
  __shared__ float As[64][33];
  __shared__ float Ws[32][65];
  int i0 = blockIdx.x * 64, n0 = blockIdx.y * 64;
  int t = threadIdx.x, ty = t >> 4, tx = t & 15;
  float acc[4][4] = {};
  for (int k0 = 0; k0 < K; k0 += 32) {
    __syncthreads();
    for (int idx = t; idx < 64 * 32; idx += 256) {
      int r = idx >> 5, k = idx & 31;
      float v = A[(size_t)(i0 + r) * K + k0 + k];
      if (RELU_A) v = fmaxf(v, 0.0f);
      As[r][k] = v;
    }
    for (int idx = t; idx < 32 * 64; idx += 256) {
      int k = idx >> 6, n = idx & 63;
      Ws[k][n] = W[(size_t)(k0 + k) * P + n0 + n];
    }
    __syncthreads();
    for (int k = 0; k < 32; ++k) {
      float a[4], b[4];
      #pragma unroll
      for (int q = 0; q < 4; ++q) a[q] = As[4 * ty + q][k];
      #pragma unroll
      for (int p = 0; p < 4; ++p) b[p] = Ws[k][4 * tx + p];
      #pragma unroll
      for (int q = 0; q < 4; ++q)
        #pragma unroll
        for (int p = 0; p < 4; ++p) acc[q][p] = fmaf(a[q], b[p], acc[q][p]);
    }
  }
  #pragma unroll
  for (int q = 0; q < 4; ++q)
    #pragma unroll
    for (int p = 0; p < 4; ++p)
      O[(size_t)(i0 + 4 * ty + q) * P + n0 + 4 * tx + p] = acc[q][p] + bias[n0 + 4 * tx + p];
}

// ---------------- row stats: inv_norm, al, ar ----------------
template<int DH>
__global__ __launch_bounds__(256) void rowstats_kernel(const float* __restrict__ h,
    const float* __restrict__ aw, float* __restrict__ al, float* __restrict__ ar,
    float* __restrict__ inv) {
  constexpr int NC = DH / 64;
  int wid = threadIdx.x >> 6, lane = threadIdx.x & 63;
  int i = blockIdx.x * 4 + wid;
  float s2 = 0.f, sl = 0.f, sr = 0.f;
  #pragma unroll
  for (int c = 0; c < NC; ++c) {
    float x = h[(size_t)i * DH + c * 64 + lane];
    s2 = fmaf(x, x, s2);
    sl = fmaf(x, aw[c * 64 + lane], sl);
    sr = fmaf(x, aw[DH + c * 64 + lane], sr);
  }
  #pragma unroll
  for (int m = 32; m > 0; m >>= 1) {
    s2 += __shfl_xor(s2, m);
    sl += __shfl_xor(sl, m);
    sr += __shfl_xor(sr, m);
  }
  if (lane == 0) { al[i] = sl; ar[i] = sr; inv[i] = rsqrtf(s2); }
}

// ---------------- column sum ----------------
template<int DH>
__global__ void colsum_kernel(const float* __restrict__ h, float* __restrict__ cs) {
  int d = threadIdx.x;             // blockDim == DH
  int r0 = blockIdx.x * (NN / 32);
  float s = 0.f;
  for (int i = 0; i < NN / 32; ++i) s += h[(size_t)(r0 + i) * DH + d];
  atomicAdd(&cs[d], s);
}

// ---------------- convert h -> bf16 hi/lo (row-major) ----------------
__global__ __launch_bounds__(256) void convert_kernel(const float* __restrict__ h,
    u16* __restrict__ hhi, u16* __restrict__ hlo) {
  int idx = blockIdx.x * 256 + threadIdx.x;
  float x = h[idx];
  u16 hi = f2bf(x);
  float lo = x - bf2f(hi);
  hhi[idx] = hi;
  hlo[idx] = f2bf(lo);
}

// ---------------- transpose h(fp32 [NN][DH]) -> hT(bf16 [DH][NN]) ----------------
template<int DH>
__global__ __launch_bounds__(256) void transpose_kernel(const float* __restrict__ h,
    u16* __restrict__ hT) {
  __shared__ u16 tile[32][33];
  int bx = blockIdx.x;   // d / 32
  int by = blockIdx.y;   // i / 32
  int t = threadIdx.x, tx = t & 31, ty8 = t >> 5;   // 32 x 8
  #pragma unroll
  for (int r = 0; r < 4; ++r) {
    int i = by * 32 + ty8 + r * 8;
    int d = bx * 32 + tx;
    tile[ty8 + r * 8][tx] = f2bf(h[(size_t)i * DH + d]);
  }
  __syncthreads();
  #pragma unroll
  for (int r = 0; r < 4; ++r) {
    int d = bx * 32 + ty8 + r * 8;
    int i = by * 32 + tx;
    hT[(size_t)d * NN + i] = tile[tx][ty8 + r * 8];
  }
}

// ---------------- CSR build ----------------
__global__ void hist_kernel(const int* __restrict__ src, int* __restrict__ counts) {
  int e = blockIdx.x * 256 + threadIdx.x;
  atomicAdd(&counts[src[e]], 1);
}

__global__ __launch_bounds__(1024) void scan_kernel(const int* __restrict__ counts,
    int* __restrict__ offsets, int* __restrict__ cursor) {
  __shared__ int part[1024];
  int t = threadIdx.x;
  int v[4]; int run = 0;
  #pragma unroll
  for (int j = 0; j < 4; ++j) { v[j] = counts[4 * t + j]; run += v[j]; }
  part[t] = run;
  __syncthreads();
  for (int off = 1; off < 1024; off <<= 1) {
    int y = (t >= off) ? part[t - off] : 0;
    __syncthreads();
    part[t] += y;
    __syncthreads();
  }
  int base = part[t] - run;
  #pragma unroll
  for (int j = 0; j < 4; ++j) { offsets[4 * t + j] = base; cursor[4 * t + j] = base; base += v[j]; }
  if (t == 1023) offsets[NN] = base;
}

__global__ void scatter_kernel(const int* __restrict__ src, const int* __restrict__ dst,
    const float* __restrict__ al, const float* __restrict__ ar, const float* __restrict__ ab,
    float* __restrict__ denom, int* __restrict__ cursor,
    int* __restrict__ dstS, float* __restrict__ eS) {
  int e = blockIdx.x * 256 + threadIdx.x;
  int s = src[e], d = dst[e];
  float v = expf(lrelu_f(al[s] + ar[d] + ab[0]));
  atomicAdd(&denom[s], v);
  int p = atomicAdd(&cursor[s], 1);
  dstS[p] = d; eS[p] = v;
}

// ---------------- edge-branch gather: o = 0.5 * nbr ----------------
template<int DH>
__global__ __launch_bounds__(256) void gather_kernel(const float* __restrict__ h,
    const int* __restrict__ offsets, const int* __restrict__ dstS,
    const float* __restrict__ eS, const float* __restrict__ denom,
    float* __restrict__ o) {
  constexpr int NC = DH / 64;
  int wid = threadIdx.x >> 6, lane = threadIdx.x & 63;
  int i = blockIdx.x * 4 + wid;
  int beg = offsets[i], end = offsets[i + 1];
  float rd = (beg < end) ? 1.0f / denom[i] : 0.0f;
  float acc[NC] = {};
  for (int k = beg; k < end; ++k) {
    int d = dstS[k];
    float a = eS[k] * rd;
    #pragma unroll
    for (int c = 0; c < NC; ++c)
      acc[c] = fmaf(a, h[(size_t)d * DH + c * 64 + lane], acc[c]);
  }
  #pragma unroll
  for (int c = 0; c < NC; ++c)
    o[(size_t)i * DH + c * 64 + lane] = 0.5f * acc[c];
}

// ---------------- Pass 1: QK^T (split bf16 MFMA) -> Delta weights W (bf16) + tile flags ----
// Grid (NN/64, JS). Block 256 = 4 waves; wave w owns i-rows [i0+16w, i0+16w+16).
// ILP structure: 12 independent accumulators (4 j-subtiles x 3 precision terms),
// c-loop outer so each c-step issues 12 independent MFMAs.
template<int DH, int JS>
__global__ __launch_bounds__(256) void qk_kernel(
    const u16* __restrict__ hhi, const u16* __restrict__ hlo,
    const float* __restrict__ al, const float* __restrict__ ar,
    const float* __restrict__ inv, const float* __restrict__ ab,
    u16* __restrict__ W, int* __restrict__ flags) {
  constexpr int KC = DH / 32;
  constexpr int JT = (NN / 64) / JS;
  int i0 = blockIdx.x * 64;
  int w = threadIdx.x >> 6, l = threadIdx.x & 63;
  int lr = l & 15, lk = l >> 4;
  int iw = i0 + 16 * w;
  // A-fragments for this wave's 16 i-rows, all K, hi+lo — live in registers all kernel
  short8 Ahi[KC], Alo[KC];
  {
    const u16* arh = hhi + (size_t)(iw + lr) * DH + lk * 8;
    const u16* arl = hlo + (size_t)(iw + lr) * DH + lk * 8;
    #pragma unroll
    for (int c = 0; c < KC; ++c) {
      Ahi[c] = *(const short8*)(arh + 32 * c);
      Alo[c] = *(const short8*)(arl + 32 * c);
    }
  }
  float ali[4], invi[4];
  #pragma unroll
  for (int q = 0; q < 4; ++q) { int i = iw + 4 * lk + q; ali[q] = al[i]; invi[q] = inv[i]; }
  float abv = ab[0];

  for (int jt = 0; jt < JT; ++jt) {
    int j0 = (blockIdx.y * JT + jt) * 64;
    f32x4 ahh[4], ahl[4], alh[4];
    #pragma unroll
    for (int s = 0; s < 4; ++s) {
      ahh[s] = (f32x4){0.f, 0.f, 0.f, 0.f};
      ahl[s] = (f32x4){0.f, 0.f, 0.f, 0.f};
      alh[s] = (f32x4){0.f, 0.f, 0.f, 0.f};
    }
    #pragma unroll
    for (int c = 0; c < KC; ++c) {
      #pragma unroll
      for (int s = 0; s < 4; ++s) {
        const u16* brh = hhi + (size_t)(j0 + 16 * s + lr) * DH + lk * 8 + 32 * c;
        const u16* brl = hlo + (size_t)(j0 + 16 * s + lr) * DH + lk * 8 + 32 * c;
        short8 Bhi = *(const short8*)brh;
        short8 Blo = *(const short8*)brl;
        ahh[s] = __builtin_amdgcn_mfma_f32_16x16x32_bf16(Ahi[c], Bhi, ahh[s], 0, 0, 0);
        ahl[s] = __builtin_amdgcn_mfma_f32_16x16x32_bf16(Ahi[c], Blo, ahl[s], 0, 0, 0);
        alh[s] = __builtin_amdgcn_mfma_f32_16x16x32_bf16(Alo[c], Bhi, alh[s], 0, 0, 0);
      }
    }
    int wany = 0;
    #pragma unroll
    for (int s = 0; s < 4; ++s) {
      int j = j0 + 16 * s + lr;
      float sv = ar[j] + abv;
      float invj = inv[j];
      #pragma unroll
      for (int q = 0; q < 4; ++q) {
        float sum = ahh[s][q] + ahl[s][q] + alh[s][q];
        float C = sum * invi[q] * invj;
        float wv = 0.0f;
        if (C > 0.36f) wv = expm1f(C * lrelu_f(ali[q] + sv));
        if (wv != 0.0f) wany = 1;
        W[(size_t)(iw + 4 * lk + q) * NN + j] = f2bf(wv);
      }
    }
    if (__any(wany) && l == 0) atomicOr(&flags[(i0 >> 6) * 64 + (j0 >> 6)], 1);
  }
}

// ---------------- Pass 2: o += h + 0.5*cs + 0.5*(W @ h), flag-gated ----------------
// Grid (NN/16, DH/64). Block 256 = 4 waves; wave w owns d-cols [dblk*64+16w, +16).
template<int DH>
__global__ __launch_bounds__(256) void pv_kernel(
    const u16* __restrict__ W, const u16* __restrict__ hT,
    const int* __restrict__ flags, const float* __restrict__ h,
    const float* __restrict__ cs, float* __restrict__ o) {
  int ib = blockIdx.x;
  int w = threadIdx.x >> 6, l = threadIdx.x & 63;
  int lr = l & 15, lk = l >> 4;
  int i0 = ib * 16;
  int d0 = blockIdx.y * 64 + w * 16;
  const int* frow = flags + (i0 >> 6) * 64;
  f32x4 acc0 = {0.f, 0.f, 0.f, 0.f};
  f32x4 acc1 = {0.f, 0.f, 0.f, 0.f};
  for (int jt = 0; jt < 64; ++jt) {
    if (!frow[jt]) continue;
    int j0 = jt * 64;
    short8 a0 = *(const short8*)&W[(size_t)(i0 + lr) * NN + j0 + lk * 8];
    short8 b0 = *(const short8*)&hT[(size_t)(d0 + lr) * NN + j0 + lk * 8];
    short8 a1 = *(const short8*)&W[(size_t)(i0 + lr) * NN + j0 + 32 + lk * 8];
    short8 b1 = *(const short8*)&hT[(size_t)(d0 + lr) * NN + j0 + 32 + lk * 8];
    acc0 = __builtin_amdgcn_mfma_f32_16x16x32_bf16(a0, b0, acc0, 0, 0, 0);
    acc1 = __builtin_amdgcn_mfma_f32_16x16x32_bf16(a1, b1, acc1, 0, 0, 0);
  }
  int d = d0 + lr;
  #pragma unroll
  for (int q = 0; q < 4; ++q) {
    int i = i0 + 4 * lk + q;
    size_t idx = (size_t)i * DH + d;
    o[idx] = o[idx] + h[idx] + 0.5f * cs[d] + 0.5f * (acc0[q] + acc1[q]);
  }
}

// ---------------- final row-normalize (in place on d_out) ----------------
__global__ __launch_bounds__(256) void norm_kernel(float* __restrict__ out) {
  int wid = threadIdx.x >> 6, lane = threadIdx.x & 63;
  int i = blockIdx.x * 4 + wid;
  float x = out[(size_t)i * 64 + lane];
  float s = x * x;
  #pragma unroll
  for (int m = 32; m > 0; m >>= 1) s += __shfl_xor(s, m);
  float n = sqrtf(s);
  out[(size_t)i * 64 + lane] = x / fmaxf(n, 1e-12f);
}

// ---------------- host-side orchestration ----------------
struct Scratch {
  float *al, *ar, *inv, *denom, *cs, *eS;
  int *counts, *offsets, *cursor, *dstS, *flags;
  u16 *hhi, *hlo, *hT, *W;
};

template<int DH>
static void run_attention(const float* h, const float* aw, const float* ab, float* o,
                          const int* src, const int* dst, const Scratch& S, hipStream_t stream) {
  rowstats_kernel<DH><<<NN / 4, 256, 0, stream>>>(h, aw, S.al, S.ar, S.inv);
  hipMemsetAsync(S.cs, 0, DH * sizeof(float), stream);
  colsum_kernel<DH><<<32, DH, 0, stream>>>(h, S.cs);
  convert_kernel<<<NN * DH / 256, 256, 0, stream>>>(h, S.hhi, S.hlo);
  transpose_kernel<DH><<<dim3(DH / 32, NN / 32), 256, 0, stream>>>(h, S.hT);
  hipMemsetAsync(S.flags, 0, 4096 * sizeof(int), stream);
  hipMemsetAsync(S.counts, 0, NN * sizeof(int), stream);
  hist_kernel<<<NE / 256, 256, 0, stream>>>(src, S.counts);
  scan_kernel<<<1, 1024, 0, stream>>>(S.counts, S.offsets, S.cursor);
  hipMemsetAsync(S.denom, 0, NN * sizeof(float), stream);
  scatter_kernel<<<NE / 256, 256, 0, stream>>>(src, dst, S.al, S.ar, ab,
                                               S.denom, S.cursor, S.dstS, S.eS);
  gather_kernel<DH><<<NN / 4, 256, 0, stream>>>(h, S.offsets, S.dstS, S.eS, S.denom, o);
  qk_kernel<DH, 16><<<dim3(NN / 64, 16), 256, 0, stream>>>(
      S.hhi, S.hlo, S.al, S.ar, S.inv, ab, S.W, S.flags);
  pv_kernel<DH><<<dim3(NN / 16, DH / 64), 256, 0, stream>>>(
      S.W, S.hT, S.flags, h, S.cs, o);
}

extern "C" void kernel_launch(void* const* d_in, const int* in_sizes, int n_in,
                              void* d_out, int out_size, void* d_ws, size_t ws_size,
                              hipStream_t stream) {
  const float* X   = (const float*)d_in[0];
  const int*   ei  = (const int*)d_in[1];
  const float* W1  = (const float*)d_in[2];
  const float* b1  = (const float*)d_in[3];
  const float* a1w = (const float*)d_in[4];
  const float* a1b = (const float*)d_in[5];
  const float* W2  = (const float*)d_in[6];
  const float* b2  = (const float*)d_in[7];
  const float* a2w = (const float*)d_in[8];
  const float* a2b = (const float*)d_in[9];
  const float* W3  = (const float*)d_in[10];
  const float* b3  = (const float*)d_in[11];
  float* out = (float*)d_out;

  const int* src = ei;
  const int* dst = ei + NE;

  char* p = (char*)d_ws;
  auto alloc = [&](size_t bytes) { char* r = p; p += (bytes + 255) & ~(size_t)255; return r; };
  float* h1 = (float*)alloc((size_t)NN * 256 * 4);
  float* o1 = (float*)alloc((size_t)NN * 256 * 4);
  float* h2 = (float*)alloc((size_t)NN * 128 * 4);
  float* o2 = (float*)alloc((size_t)NN * 128 * 4);
  Scratch S;
  S.hhi = (u16*)alloc((size_t)NN * 256 * 2);
  S.hlo = (u16*)alloc((size_t)NN * 256 * 2);
  S.hT  = (u16*)alloc((size_t)NN * 256 * 2);
  S.W   = (u16*)alloc((size_t)NN * NN * 2);
  S.flags = (int*)alloc(4096 * 4);
  S.al    = (float*)alloc(NN * 4);
  S.ar    = (float*)alloc(NN * 4);
  S.inv   = (float*)alloc(NN * 4);
  S.denom = (float*)alloc(NN * 4);
  S.cs    = (float*)alloc(256 * 4);
  S.eS    = (float*)alloc((size_t)NE * 4);
  S.counts  = (int*)alloc(NN * 4);
  S.offsets = (int*)alloc((NN + 1) * 4);
  S.cursor  = (int*)alloc(NN * 4);
  S.dstS    = (int*)alloc((size_t)NE * 4);

  // layer 1
  gemm_kernel<false><<<dim3(NN / 64, 256 / 64), 256, 0, stream>>>(X, W1, b1, h1, 128, 256);
  run_attention<256>(h1, a1w, a1b, o1, src, dst, S, stream);
  // layer 2
  gemm_kernel<true><<<dim3(NN / 64, 128 / 64), 256, 0, stream>>>(o1, W2, b2, h2, 256, 128);
  run_attention<128>(h2, a2w, a2b, o2, src, dst, S, stream);
  // output layer + normalize
  gemm_kernel<true><<<dim3(NN / 64, 64 / 64), 256, 0, stream>>>(o2, W3, b3, out, 128, 64);
  norm_kernel<<<NN / 4, 256, 0, stream>>>(out);
}

// Round 6
// 478.298 us; speedup vs baseline: 4.9167x; 1.3029x over previous
//
#include <hip/hip_runtime.h>
#include <math.h>

#define NN 4096
#define NE 131072

typedef short short8 __attribute__((ext_vector_type(8)));
typedef float f32x4 __attribute__((ext_vector_type(4)));
typedef unsigned short u16;

__device__ __forceinline__ float lrelu_f(float x) { return x > 0.0f ? x : 0.01f * x; }

__device__ __forceinline__ u16 f2bf(float x) {
  unsigned int u = __float_as_uint(x);
  unsigned int r = (u + 0x7FFF + ((u >> 16) & 1)) >> 16;   // RNE
  return (u16)r;
}
__device__ __forceinline__ float bf2f(u16 b) { return __uint_as_float(((unsigned int)b) << 16); }

__device__ __forceinline__ void gload_lds16(const u16* g, u16* l) {
  __builtin_amdgcn_global_load_lds((const __attribute__((address_space(1))) void*)g,
                                   (__attribute__((address_space(3))) void*)l, 16, 0, 0);
}

// ---------------- GEMM: O[M,P] = act(A)[M,K] @ W[K,P] + b ----------------
template<bool RELU_A>
__global__ __launch_bounds__(256) void gemm_kernel(const float* __restrict__ A,
    const float* __restrict__ W, const float* __restrict__ bias,
    float* __restrict__ O, int K, int P) {
  __shared__ float As[64][33];
  __shared__ float Ws[32][65];
  int i0 = blockIdx.x * 64, n0 = blockIdx.y * 64;
  int t = threadIdx.x, ty = t >> 4, tx = t & 15;
  float acc[4][4] = {};
  for (int k0 = 0; k0 < K; k0 += 32) {
    __syncthreads();
    for (int idx = t; idx < 64 * 32; idx += 256) {
      int r = idx >> 5, k = idx & 31;
      float v = A[(size_t)(i0 + r) * K + k0 + k];
      if (RELU_A) v = fmaxf(v, 0.0f);
      As[r][k] = v;
    }
    for (int idx = t; idx < 32 * 64; idx += 256) {
      int k = idx >> 6, n = idx & 63;
      Ws[k][n] = W[(size_t)(k0 + k) * P + n0 + n];
    }
    __syncthreads();
    for (int k = 0; k < 32; ++k) {
      float a[4], b[4];
      #pragma unroll
      for (int q = 0; q < 4; ++q) a[q] = As[4 * ty + q][k];
      #pragma unroll
      for (int p = 0; p < 4; ++p) b[p] = Ws[k][4 * tx + p];
      #pragma unroll
      for (int q = 0; q < 4; ++q)
        #pragma unroll
        for (int p = 0; p < 4; ++p) acc[q][p] = fmaf(a[q], b[p], acc[q][p]);
    }
  }
  #pragma unroll
  for (int q = 0; q < 4; ++q)
    #pragma unroll
    for (int p = 0; p < 4; ++p)
      O[(size_t)(i0 + 4 * ty + q) * P + n0 + 4 * tx + p] = acc[q][p] + bias[n0 + 4 * tx + p];
}

// ---------------- row stats: inv_norm, al, ar ----------------
template<int DH>
__global__ __launch_bounds__(256) void rowstats_kernel(const float* __restrict__ h,
    const float* __restrict__ aw, float* __restrict__ al, float* __restrict__ ar,
    float* __restrict__ inv) {
  constexpr int NC = DH / 64;
  int wid = threadIdx.x >> 6, lane = threadIdx.x & 63;
  int i = blockIdx.x * 4 + wid;
  float s2 = 0.f, sl = 0.f, sr = 0.f;
  #pragma unroll
  for (int c = 0; c < NC; ++c) {
    float x = h[(size_t)i * DH + c * 64 + lane];
    s2 = fmaf(x, x, s2);
    sl = fmaf(x, aw[c * 64 + lane], sl);
    sr = fmaf(x, aw[DH + c * 64 + lane], sr);
  }
  #pragma unroll
  for (int m = 32; m > 0; m >>= 1) {
    s2 += __shfl_xor(s2, m);
    sl += __shfl_xor(sl, m);
    sr += __shfl_xor(sr, m);
  }
  if (lane == 0) { al[i] = sl; ar[i] = sr; inv[i] = rsqrtf(s2); }
}

// ---------------- column sum ----------------
template<int DH>
__global__ void colsum_kernel(const float* __restrict__ h, float* __restrict__ cs) {
  int d = threadIdx.x;             // blockDim == DH
  int r0 = blockIdx.x * (NN / 32);
  float s = 0.f;
  for (int i = 0; i < NN / 32; ++i) s += h[(size_t)(r0 + i) * DH + d];
  atomicAdd(&cs[d], s);
}

// ---------------- convert h -> bf16 hi/lo (row-major) ----------------
__global__ __launch_bounds__(256) void convert_kernel(const float* __restrict__ h,
    u16* __restrict__ hhi, u16* __restrict__ hlo) {
  int idx = blockIdx.x * 256 + threadIdx.x;
  float x = h[idx];
  u16 hi = f2bf(x);
  float lo = x - bf2f(hi);
  hhi[idx] = hi;
  hlo[idx] = f2bf(lo);
}

// ---------------- transpose h(fp32 [NN][DH]) -> hT(bf16 [DH][NN]) ----------------
template<int DH>
__global__ __launch_bounds__(256) void transpose_kernel(const float* __restrict__ h,
    u16* __restrict__ hT) {
  __shared__ u16 tile[32][33];
  int bx = blockIdx.x;   // d / 32
  int by = blockIdx.y;   // i / 32
  int t = threadIdx.x, tx = t & 31, ty8 = t >> 5;   // 32 x 8
  #pragma unroll
  for (int r = 0; r < 4; ++r) {
    int i = by * 32 + ty8 + r * 8;
    int d = bx * 32 + tx;
    tile[ty8 + r * 8][tx] = f2bf(h[(size_t)i * DH + d]);
  }
  __syncthreads();
  #pragma unroll
  for (int r = 0; r < 4; ++r) {
    int d = bx * 32 + ty8 + r * 8;
    int i = by * 32 + tx;
    hT[(size_t)d * NN + i] = tile[tx][ty8 + r * 8];
  }
}

// ---------------- CSR build ----------------
__global__ void hist_kernel(const int* __restrict__ src, int* __restrict__ counts) {
  int e = blockIdx.x * 256 + threadIdx.x;
  atomicAdd(&counts[src[e]], 1);
}

__global__ __launch_bounds__(1024) void scan_kernel(const int* __restrict__ counts,
    int* __restrict__ offsets, int* __restrict__ cursor) {
  __shared__ int part[1024];
  int t = threadIdx.x;
  int v[4]; int run = 0;
  #pragma unroll
  for (int j = 0; j < 4; ++j) { v[j] = counts[4 * t + j]; run += v[j]; }
  part[t] = run;
  __syncthreads();
  for (int off = 1; off < 1024; off <<= 1) {
    int y = (t >= off) ? part[t - off] : 0;
    __syncthreads();
    part[t] += y;
    __syncthreads();
  }
  int base = part[t] - run;
  #pragma unroll
  for (int j = 0; j < 4; ++j) { offsets[4 * t + j] = base; cursor[4 * t + j] = base; base += v[j]; }
  if (t == 1023) offsets[NN] = base;
}

__global__ void scatter_kernel(const int* __restrict__ src, const int* __restrict__ dst,
    const float* __restrict__ al, const float* __restrict__ ar, const float* __restrict__ ab,
    float* __restrict__ denom, int* __restrict__ cursor,
    int* __restrict__ dstS, float* __restrict__ eS) {
  int e = blockIdx.x * 256 + threadIdx.x;
  int s = src[e], d = dst[e];
  float v = expf(lrelu_f(al[s] + ar[d] + ab[0]));
  atomicAdd(&denom[s], v);
  int p = atomicAdd(&cursor[s], 1);
  dstS[p] = d; eS[p] = v;
}

// ---------------- edge-branch gather: o = 0.5 * nbr ----------------
template<int DH>
__global__ __launch_bounds__(256) void gather_kernel(const float* __restrict__ h,
    const int* __restrict__ offsets, const int* __restrict__ dstS,
    const float* __restrict__ eS, const float* __restrict__ denom,
    float* __restrict__ o) {
  constexpr int NC = DH / 64;
  int wid = threadIdx.x >> 6, lane = threadIdx.x & 63;
  int i = blockIdx.x * 4 + wid;
  int beg = offsets[i], end = offsets[i + 1];
  float rd = (beg < end) ? 1.0f / denom[i] : 0.0f;
  float acc[NC] = {};
  for (int k = beg; k < end; ++k) {
    int d = dstS[k];
    float a = eS[k] * rd;
    #pragma unroll
    for (int c = 0; c < NC; ++c)
      acc[c] = fmaf(a, h[(size_t)d * DH + c * 64 + lane], acc[c]);
  }
  #pragma unroll
  for (int c = 0; c < NC; ++c)
    o[(size_t)i * DH + c * 64 + lane] = 0.5f * acc[c];
}

// ---------------- Pass 1: QK^T (split bf16 MFMA) -> Delta weights W (bf16) + tile flags ----
// Grid (NN/64, NN/64) — full j-split. Block 256 = 4 waves; wave w owns i-rows
// [i0+16w, i0+16w+16). A+B hi/lo tiles staged to LDS via global_load_lds (16B),
// double-buffered per 32-wide k-chunk; B shared by all 4 waves.
template<int DH>
__global__ __launch_bounds__(256) void qk_kernel(
    const u16* __restrict__ hhi, const u16* __restrict__ hlo,
    const float* __restrict__ al, const float* __restrict__ ar,
    const float* __restrict__ inv, const float* __restrict__ ab,
    u16* __restrict__ W, int* __restrict__ flags) {
  constexpr int KC = DH / 32;
  __shared__ u16 sA[2][2][64][32];   // [buf][hi/lo][row][col]
  __shared__ u16 sB[2][2][64][32];
  int i0 = blockIdx.x * 64;
  int j0 = blockIdx.y * 64;
  int w = threadIdx.x >> 6, l = threadIdx.x & 63;
  int lr = l & 15, lk = l >> 4;
  int iw = i0 + 16 * w;
  int srow = l >> 2, scol = (l & 3) * 8;   // staging: lane -> (row srow, col scol) of wave quarter

  const u16* gAh = hhi + (size_t)(i0 + 16 * w + srow) * DH + scol;
  const u16* gAl = hlo + (size_t)(i0 + 16 * w + srow) * DH + scol;
  const u16* gBh = hhi + (size_t)(j0 + 16 * w + srow) * DH + scol;
  const u16* gBl = hlo + (size_t)(j0 + 16 * w + srow) * DH + scol;

  f32x4 ahh[4], ahl[4], alh[4];
  #pragma unroll
  for (int s = 0; s < 4; ++s) {
    ahh[s] = (f32x4){0.f, 0.f, 0.f, 0.f};
    ahl[s] = (f32x4){0.f, 0.f, 0.f, 0.f};
    alh[s] = (f32x4){0.f, 0.f, 0.f, 0.f};
  }

  // prologue: stage chunk 0 into buf 0
  gload_lds16(gAh, &sA[0][0][16 * w][0]);
  gload_lds16(gAl, &sA[0][1][16 * w][0]);
  gload_lds16(gBh, &sB[0][0][16 * w][0]);
  gload_lds16(gBl, &sB[0][1][16 * w][0]);
  __syncthreads();

  int cur = 0;
  for (int c = 0; c < KC; ++c) {
    if (c + 1 < KC) {
      int nb = cur ^ 1;
      gload_lds16(gAh + (c + 1) * 32, &sA[nb][0][16 * w][0]);
      gload_lds16(gAl + (c + 1) * 32, &sA[nb][1][16 * w][0]);
      gload_lds16(gBh + (c + 1) * 32, &sB[nb][0][16 * w][0]);
      gload_lds16(gBl + (c + 1) * 32, &sB[nb][1][16 * w][0]);
    }
    short8 Ah = *(const short8*)&sA[cur][0][16 * w + lr][lk * 8];
    short8 Al = *(const short8*)&sA[cur][1][16 * w + lr][lk * 8];
    #pragma unroll
    for (int s = 0; s < 4; ++s) {
      short8 Bh = *(const short8*)&sB[cur][0][16 * s + lr][lk * 8];
      short8 Bl = *(const short8*)&sB[cur][1][16 * s + lr][lk * 8];
      ahh[s] = __builtin_amdgcn_mfma_f32_16x16x32_bf16(Ah, Bh, ahh[s], 0, 0, 0);
      ahl[s] = __builtin_amdgcn_mfma_f32_16x16x32_bf16(Ah, Bl, ahl[s], 0, 0, 0);
      alh[s] = __builtin_amdgcn_mfma_f32_16x16x32_bf16(Al, Bh, alh[s], 0, 0, 0);
    }
    __syncthreads();   // drains vmcnt (next chunk staged) + all reads of cur done
    cur ^= 1;
  }

  float ali[4], invi[4];
  #pragma unroll
  for (int q = 0; q < 4; ++q) { int i = iw + 4 * lk + q; ali[q] = al[i]; invi[q] = inv[i]; }
  float abv = ab[0];
  int wany = 0;
  #pragma unroll
  for (int s = 0; s < 4; ++s) {
    int j = j0 + 16 * s + lr;
    float sv = ar[j] + abv;
    float invj = inv[j];
    #pragma unroll
    for (int q = 0; q < 4; ++q) {
      float sum = ahh[s][q] + ahl[s][q] + alh[s][q];
      float C = sum * invi[q] * invj;
      float wv = 0.0f;
      if (C > 0.36f) wv = expm1f(C * lrelu_f(ali[q] + sv));
      if (wv != 0.0f) wany = 1;
      W[(size_t)(iw + 4 * lk + q) * NN + j] = f2bf(wv);
    }
  }
  if (__any(wany) && l == 0) atomicOr(&flags[(i0 >> 6) * 64 + (j0 >> 6)], 1);
}

// ---------------- Pass 2: o += h + 0.5*cs + 0.5*(W @ h), flag-gated ----------------
// Grid (NN/16, DH/64). Block 256 = 4 waves; wave w owns d-cols [dblk*64+16w, +16).
template<int DH>
__global__ __launch_bounds__(256) void pv_kernel(
    const u16* __restrict__ W, const u16* __restrict__ hT,
    const int* __restrict__ flags, const float* __restrict__ h,
    const float* __restrict__ cs, float* __restrict__ o) {
  int ib = blockIdx.x;
  int w = threadIdx.x >> 6, l = threadIdx.x & 63;
  int lr = l & 15, lk = l >> 4;
  int i0 = ib * 16;
  int d0 = blockIdx.y * 64 + w * 16;
  const int* frow = flags + (i0 >> 6) * 64;
  f32x4 acc0 = {0.f, 0.f, 0.f, 0.f};
  f32x4 acc1 = {0.f, 0.f, 0.f, 0.f};
  for (int jt = 0; jt < 64; ++jt) {
    if (!frow[jt]) continue;
    int j0 = jt * 64;
    short8 a0 = *(const short8*)&W[(size_t)(i0 + lr) * NN + j0 + lk * 8];
    short8 b0 = *(const short8*)&hT[(size_t)(d0 + lr) * NN + j0 + lk * 8];
    short8 a1 = *(const short8*)&W[(size_t)(i0 + lr) * NN + j0 + 32 + lk * 8];
    short8 b1 = *(const short8*)&hT[(size_t)(d0 + lr) * NN + j0 + 32 + lk * 8];
    acc0 = __builtin_amdgcn_mfma_f32_16x16x32_bf16(a0, b0, acc0, 0, 0, 0);
    acc1 = __builtin_amdgcn_mfma_f32_16x16x32_bf16(a1, b1, acc1, 0, 0, 0);
  }
  int d = d0 + lr;
  #pragma unroll
  for (int q = 0; q < 4; ++q) {
    int i = i0 + 4 * lk + q;
    size_t idx = (size_t)i * DH + d;
    o[idx] = o[idx] + h[idx] + 0.5f * cs[d] + 0.5f * (acc0[q] + acc1[q]);
  }
}

// ---------------- final row-normalize (in place on d_out) ----------------
__global__ __launch_bounds__(256) void norm_kernel(float* __restrict__ out) {
  int wid = threadIdx.x >> 6, lane = threadIdx.x & 63;
  int i = blockIdx.x * 4 + wid;
  float x = out[(size_t)i * 64 + lane];
  float s = x * x;
  #pragma unroll
  for (int m = 32; m > 0; m >>= 1) s += __shfl_xor(s, m);
  float n = sqrtf(s);
  out[(size_t)i * 64 + lane] = x / fmaxf(n, 1e-12f);
}

// ---------------- host-side orchestration ----------------
struct Scratch {
  float *al, *ar, *inv, *denom, *cs, *eS;
  int *counts, *offsets, *cursor, *dstS, *flags;
  u16 *hhi, *hlo, *hT, *W;
};

template<int DH>
static void run_attention(const float* h, const float* aw, const float* ab, float* o,
                          const int* src, const int* dst, const Scratch& S, hipStream_t stream) {
  rowstats_kernel<DH><<<NN / 4, 256, 0, stream>>>(h, aw, S.al, S.ar, S.inv);
  hipMemsetAsync(S.cs, 0, DH * sizeof(float), stream);
  colsum_kernel<DH><<<32, DH, 0, stream>>>(h, S.cs);
  convert_kernel<<<NN * DH / 256, 256, 0, stream>>>(h, S.hhi, S.hlo);
  transpose_kernel<DH><<<dim3(DH / 32, NN / 32), 256, 0, stream>>>(h, S.hT);
  hipMemsetAsync(S.flags, 0, 4096 * sizeof(int), stream);
  hipMemsetAsync(S.counts, 0, NN * sizeof(int), stream);
  hist_kernel<<<NE / 256, 256, 0, stream>>>(src, S.counts);
  scan_kernel<<<1, 1024, 0, stream>>>(S.counts, S.offsets, S.cursor);
  hipMemsetAsync(S.denom, 0, NN * sizeof(float), stream);
  scatter_kernel<<<NE / 256, 256, 0, stream>>>(src, dst, S.al, S.ar, ab,
                                               S.denom, S.cursor, S.dstS, S.eS);
  gather_kernel<DH><<<NN / 4, 256, 0, stream>>>(h, S.offsets, S.dstS, S.eS, S.denom, o);
  qk_kernel<DH><<<dim3(NN / 64, NN / 64), 256, 0, stream>>>(
      S.hhi, S.hlo, S.al, S.ar, S.inv, ab, S.W, S.flags);
  pv_kernel<DH><<<dim3(NN / 16, DH / 64), 256, 0, stream>>>(
      S.W, S.hT, S.flags, h, S.cs, o);
}

extern "C" void kernel_launch(void* const* d_in, const int* in_sizes, int n_in,
                              void* d_out, int out_size, void* d_ws, size_t ws_size,
                              hipStream_t stream) {
  const float* X   = (const float*)d_in[0];
  const int*   ei  = (const int*)d_in[1];
  const float* W1  = (const float*)d_in[2];
  const float* b1  = (const float*)d_in[3];
  const float* a1w = (const float*)d_in[4];
  const float* a1b = (const float*)d_in[5];
  const float* W2  = (const float*)d_in[6];
  const float* b2  = (const float*)d_in[7];
  const float* a2w = (const float*)d_in[8];
  const float* a2b = (const float*)d_in[9];
  const float* W3  = (const float*)d_in[10];
  const float* b3  = (const float*)d_in[11];
  float* out = (float*)d_out;

  const int* src = ei;
  const int* dst = ei + NE;

  char* p = (char*)d_ws;
  auto alloc = [&](size_t bytes) { char* r = p; p += (bytes + 255) & ~(size_t)255; return r; };
  float* h1 = (float*)alloc((size_t)NN * 256 * 4);
  float* o1 = (float*)alloc((size_t)NN * 256 * 4);
  float* h2 = (float*)alloc((size_t)NN * 128 * 4);
  float* o2 = (float*)alloc((size_t)NN * 128 * 4);
  Scratch S;
  S.hhi = (u16*)alloc((size_t)NN * 256 * 2);
  S.hlo = (u16*)alloc((size_t)NN * 256 * 2);
  S.hT  = (u16*)alloc((size_t)NN * 256 * 2);
  S.W   = (u16*)alloc((size_t)NN * NN * 2);
  S.flags = (int*)alloc(4096 * 4);
  S.al    = (float*)alloc(NN * 4);
  S.ar    = (float*)alloc(NN * 4);
  S.inv   = (float*)alloc(NN * 4);
  S.denom = (float*)alloc(NN * 4);
  S.cs    = (float*)alloc(256 * 4);
  S.eS    = (float*)alloc((size_t)NE * 4);
  S.counts  = (int*)alloc(NN * 4);
  S.offsets = (int*)alloc((NN + 1) * 4);
  S.cursor  = (int*)alloc(NN * 4);
  S.dstS    = (int*)alloc((size_t)NE * 4);

  // layer 1
  gemm_kernel<false><<<dim3(NN / 64, 256 / 64), 256, 0, stream>>>(X, W1, b1, h1, 128, 256);
  run_attention<256>(h1, a1w, a1b, o1, src, dst, S, stream);
  // layer 2
  gemm_kernel<true><<<dim3(NN / 64, 128 / 64), 256, 0, stream>>>(o1, W2, b2, h2, 256, 128);
  run_attention<128>(h2, a2w, a2b, o2, src, dst, S, stream);
  // output layer + normalize
  gemm_kernel<true><<<dim3(NN / 64, 64 / 64), 256, 0, stream>>>(o2, W3, b3, out, 128, 64);
  norm_kernel<<<NN / 4, 256, 0, stream>>>(out);
}

// Round 7
// 477.989 us; speedup vs baseline: 4.9199x; 1.0006x over previous
//
#include <hip/hip_runtime.h>
#include <math.h>

#define NN 4096
#define NE 131072

typedef short short8 __attribute__((ext_vector_type(8)));
typedef float f32x4 __attribute__((ext_vector_type(4)));
typedef unsigned short u16;

__device__ __forceinline__ float lrelu_f(float x) { return x > 0.0f ? x : 0.01f * x; }

__device__ __forceinline__ u16 f2bf(float x) {
  unsigned int u = __float_as_uint(x);
  unsigned int r = (u + 0x7FFF + ((u >> 16) & 1)) >> 16;   // RNE
  return (u16)r;
}
__device__ __forceinline__ float bf2f(u16 b) { return __uint_as_float(((unsigned int)b) << 16); }

__device__ __forceinline__ void gload_lds16(const u16* g, u16* l) {
  __builtin_amdgcn_global_load_lds((const __attribute__((address_space(1))) void*)g,
                                   (__attribute__((address_space(3))) void*)l, 16, 0, 0);
}

// ---------------- GEMM: O[M,P] = act(A)[M,K] @ W[K,P] + b ----------------
template<bool RELU_A>
__global__ __launch_bounds__(256) void gemm_kernel(const float* __restrict__ A,
    const float* __restrict__ W, const float* __restrict__ bias,
    float* __restrict__ O, int K, int P) {
  __shared__ float As[64][33];
  __shared__ float Ws[32][65];
  int i0 = blockIdx.x * 64, n0 = blockIdx.y * 64;
  int t = threadIdx.x, ty = t >> 4, tx = t & 15;
  float acc[4][4] = {};
  for (int k0 = 0; k0 < K; k0 += 32) {
    __syncthreads();
    for (int idx = t; idx < 64 * 32; idx += 256) {
      int r = idx >> 5, k = idx & 31;
      float v = A[(size_t)(i0 + r) * K + k0 + k];
      if (RELU_A) v = fmaxf(v, 0.0f);
      As[r][k] = v;
    }
    for (int idx = t; idx < 32 * 64; idx += 256) {
      int k = idx >> 6, n = idx & 63;
      Ws[k][n] = W[(size_t)(k0 + k) * P + n0 + n];
    }
    __syncthreads();
    for (int k = 0; k < 32; ++k) {
      float a[4], b[4];
      #pragma unroll
      for (int q = 0; q < 4; ++q) a[q] = As[4 * ty + q][k];
      #pragma unroll
      for (int p = 0; p < 4; ++p) b[p] = Ws[k][4 * tx + p];
      #pragma unroll
      for (int q = 0; q < 4; ++q)
        #pragma unroll
        for (int p = 0; p < 4; ++p) acc[q][p] = fmaf(a[q], b[p], acc[q][p]);
    }
  }
  #pragma unroll
  for (int q = 0; q < 4; ++q)
    #pragma unroll
    for (int p = 0; p < 4; ++p)
      O[(size_t)(i0 + 4 * ty + q) * P + n0 + 4 * tx + p] = acc[q][p] + bias[n0 + 4 * tx + p];
}

// ---------------- row stats: inv_norm, al, ar ----------------
template<int DH>
__global__ __launch_bounds__(256) void rowstats_kernel(const float* __restrict__ h,
    const float* __restrict__ aw, float* __restrict__ al, float* __restrict__ ar,
    float* __restrict__ inv) {
  constexpr int NC = DH / 64;
  int wid = threadIdx.x >> 6, lane = threadIdx.x & 63;
  int i = blockIdx.x * 4 + wid;
  float s2 = 0.f, sl = 0.f, sr = 0.f;
  #pragma unroll
  for (int c = 0; c < NC; ++c) {
    float x = h[(size_t)i * DH + c * 64 + lane];
    s2 = fmaf(x, x, s2);
    sl = fmaf(x, aw[c * 64 + lane], sl);
    sr = fmaf(x, aw[DH + c * 64 + lane], sr);
  }
  #pragma unroll
  for (int m = 32; m > 0; m >>= 1) {
    s2 += __shfl_xor(s2, m);
    sl += __shfl_xor(sl, m);
    sr += __shfl_xor(sr, m);
  }
  if (lane == 0) { al[i] = sl; ar[i] = sr; inv[i] = rsqrtf(s2); }
}

// ---------------- column sum ----------------
template<int DH>
__global__ void colsum_kernel(const float* __restrict__ h, float* __restrict__ cs) {
  int d = threadIdx.x;             // blockDim == DH
  int r0 = blockIdx.x * (NN / 32);
  float s = 0.f;
  for (int i = 0; i < NN / 32; ++i) s += h[(size_t)(r0 + i) * DH + d];
  atomicAdd(&cs[d], s);
}

// ---------------- convert h -> bf16 hi/lo (row-major) ----------------
__global__ __launch_bounds__(256) void convert_kernel(const float* __restrict__ h,
    u16* __restrict__ hhi, u16* __restrict__ hlo) {
  int idx = blockIdx.x * 256 + threadIdx.x;
  float x = h[idx];
  u16 hi = f2bf(x);
  float lo = x - bf2f(hi);
  hhi[idx] = hi;
  hlo[idx] = f2bf(lo);
}

// ---------------- transpose h(fp32 [NN][DH]) -> hT(bf16 [DH][NN]) ----------------
template<int DH>
__global__ __launch_bounds__(256) void transpose_kernel(const float* __restrict__ h,
    u16* __restrict__ hT) {
  __shared__ u16 tile[32][33];
  int bx = blockIdx.x;   // d / 32
  int by = blockIdx.y;   // i / 32
  int t = threadIdx.x, tx = t & 31, ty8 = t >> 5;   // 32 x 8
  #pragma unroll
  for (int r = 0; r < 4; ++r) {
    int i = by * 32 + ty8 + r * 8;
    int d = bx * 32 + tx;
    tile[ty8 + r * 8][tx] = f2bf(h[(size_t)i * DH + d]);
  }
  __syncthreads();
  #pragma unroll
  for (int r = 0; r < 4; ++r) {
    int d = bx * 32 + ty8 + r * 8;
    int i = by * 32 + tx;
    hT[(size_t)d * NN + i] = tile[tx][ty8 + r * 8];
  }
}

// ---------------- CSR build ----------------
__global__ void hist_kernel(const int* __restrict__ src, int* __restrict__ counts) {
  int e = blockIdx.x * 256 + threadIdx.x;
  atomicAdd(&counts[src[e]], 1);
}

__global__ __launch_bounds__(1024) void scan_kernel(const int* __restrict__ counts,
    int* __restrict__ offsets, int* __restrict__ cursor) {
  __shared__ int part[1024];
  int t = threadIdx.x;
  int v[4]; int run = 0;
  #pragma unroll
  for (int j = 0; j < 4; ++j) { v[j] = counts[4 * t + j]; run += v[j]; }
  part[t] = run;
  __syncthreads();
  for (int off = 1; off < 1024; off <<= 1) {
    int y = (t >= off) ? part[t - off] : 0;
    __syncthreads();
    part[t] += y;
    __syncthreads();
  }
  int base = part[t] - run;
  #pragma unroll
  for (int j = 0; j < 4; ++j) { offsets[4 * t + j] = base; cursor[4 * t + j] = base; base += v[j]; }
  if (t == 1023) offsets[NN] = base;
}

__global__ void scatter_kernel(const int* __restrict__ src, const int* __restrict__ dst,
    const float* __restrict__ al, const float* __restrict__ ar, const float* __restrict__ ab,
    float* __restrict__ denom, int* __restrict__ cursor,
    int* __restrict__ dstS, float* __restrict__ eS) {
  int e = blockIdx.x * 256 + threadIdx.x;
  int s = src[e], d = dst[e];
  float v = expf(lrelu_f(al[s] + ar[d] + ab[0]));
  atomicAdd(&denom[s], v);
  int p = atomicAdd(&cursor[s], 1);
  dstS[p] = d; eS[p] = v;
}

// ---------------- edge-branch gather: o = 0.5 * nbr ----------------
template<int DH>
__global__ __launch_bounds__(256) void gather_kernel(const float* __restrict__ h,
    const int* __restrict__ offsets, const int* __restrict__ dstS,
    const float* __restrict__ eS, const float* __restrict__ denom,
    float* __restrict__ o) {
  constexpr int NC = DH / 64;
  int wid = threadIdx.x >> 6, lane = threadIdx.x & 63;
  int i = blockIdx.x * 4 + wid;
  int beg = offsets[i], end = offsets[i + 1];
  float rd = (beg < end) ? 1.0f / denom[i] : 0.0f;
  float acc[NC] = {};
  for (int k = beg; k < end; ++k) {
    int d = dstS[k];
    float a = eS[k] * rd;
    #pragma unroll
    for (int c = 0; c < NC; ++c)
      acc[c] = fmaf(a, h[(size_t)d * DH + c * 64 + lane], acc[c]);
  }
  #pragma unroll
  for (int c = 0; c < NC; ++c)
    o[(size_t)i * DH + c * 64 + lane] = 0.5f * acc[c];
}

// ---------------- Pass 1: QK^T (split bf16 MFMA) -> Delta weights W (bf16) + tile flags ----
// Grid (NN/64, NN/64) — full j-split. Block 256 = 4 waves; wave w owns i-rows
// [i0+16w, i0+16w+16). A+B hi/lo tiles staged to LDS via global_load_lds (16B),
// double-buffered per 32-wide k-chunk; B shared by all 4 waves.
template<int DH>
__global__ __launch_bounds__(256) void qk_kernel(
    const u16* __restrict__ hhi, const u16* __restrict__ hlo,
    const float* __restrict__ al, const float* __restrict__ ar,
    const float* __restrict__ inv, const float* __restrict__ ab,
    u16* __restrict__ W, int* __restrict__ flags) {
  constexpr int KC = DH / 32;
  __shared__ u16 sA[2][2][64][32];   // [buf][hi/lo][row][col]
  __shared__ u16 sB[2][2][64][32];
  int i0 = blockIdx.x * 64;
  int j0 = blockIdx.y * 64;
  int w = threadIdx.x >> 6, l = threadIdx.x & 63;
  int lr = l & 15, lk = l >> 4;
  int iw = i0 + 16 * w;
  int srow = l >> 2, scol = (l & 3) * 8;   // staging: lane -> (row srow, col scol) of wave quarter

  const u16* gAh = hhi + (size_t)(i0 + 16 * w + srow) * DH + scol;
  const u16* gAl = hlo + (size_t)(i0 + 16 * w + srow) * DH + scol;
  const u16* gBh = hhi + (size_t)(j0 + 16 * w + srow) * DH + scol;
  const u16* gBl = hlo + (size_t)(j0 + 16 * w + srow) * DH + scol;

  f32x4 ahh[4], ahl[4], alh[4];
  #pragma unroll
  for (int s = 0; s < 4; ++s) {
    ahh[s] = (f32x4){0.f, 0.f, 0.f, 0.f};
    ahl[s] = (f32x4){0.f, 0.f, 0.f, 0.f};
    alh[s] = (f32x4){0.f, 0.f, 0.f, 0.f};
  }

  // prologue: stage chunk 0 into buf 0
  gload_lds16(gAh, &sA[0][0][16 * w][0]);
  gload_lds16(gAl, &sA[0][1][16 * w][0]);
  gload_lds16(gBh, &sB[0][0][16 * w][0]);
  gload_lds16(gBl, &sB[0][1][16 * w][0]);
  __syncthreads();

  int cur = 0;
  for (int c = 0; c < KC; ++c) {
    if (c + 1 < KC) {
      int nb = cur ^ 1;
      gload_lds16(gAh + (c + 1) * 32, &sA[nb][0][16 * w][0]);
      gload_lds16(gAl + (c + 1) * 32, &sA[nb][1][16 * w][0]);
      gload_lds16(gBh + (c + 1) * 32, &sB[nb][0][16 * w][0]);
      gload_lds16(gBl + (c + 1) * 32, &sB[nb][1][16 * w][0]);
    }
    short8 Ah = *(const short8*)&sA[cur][0][16 * w + lr][lk * 8];
    short8 Al = *(const short8*)&sA[cur][1][16 * w + lr][lk * 8];
    #pragma unroll
    for (int s = 0; s < 4; ++s) {
      short8 Bh = *(const short8*)&sB[cur][0][16 * s + lr][lk * 8];
      short8 Bl = *(const short8*)&sB[cur][1][16 * s + lr][lk * 8];
      ahh[s] = __builtin_amdgcn_mfma_f32_16x16x32_bf16(Ah, Bh, ahh[s], 0, 0, 0);
      ahl[s] = __builtin_amdgcn_mfma_f32_16x16x32_bf16(Ah, Bl, ahl[s], 0, 0, 0);
      alh[s] = __builtin_amdgcn_mfma_f32_16x16x32_bf16(Al, Bh, alh[s], 0, 0, 0);
    }
    __syncthreads();   // drains vmcnt (next chunk staged) + all reads of cur done
    cur ^= 1;
  }

  float ali[4], invi[4];
  #pragma unroll
  for (int q = 0; q < 4; ++q) { int i = iw + 4 * lk + q; ali[q] = al[i]; invi[q] = inv[i]; }
  float abv = ab[0];
  int wany = 0;
  #pragma unroll
  for (int s = 0; s < 4; ++s) {
    int j = j0 + 16 * s + lr;
    float sv = ar[j] + abv;
    float invj = inv[j];
    #pragma unroll
    for (int q = 0; q < 4; ++q) {
      float sum = ahh[s][q] + ahl[s][q] + alh[s][q];
      float C = sum * invi[q] * invj;
      float wv = 0.0f;
      if (C > 0.36f) wv = expm1f(C * lrelu_f(ali[q] + sv));
      if (wv != 0.0f) wany = 1;
      W[(size_t)(iw + 4 * lk + q) * NN + j] = f2bf(wv);
    }
  }
  if (__any(wany) && l == 0) atomicOr(&flags[(i0 >> 6) * 64 + (j0 >> 6)], 1);
}

// ---------------- Pass 2: o += h + 0.5*cs + 0.5*(W @ h), flag-gated ----------------
// Grid (NN/16, DH/64). Block 256 = 4 waves; wave w owns d-cols [dblk*64+16w, +16).
// Active j-tiles compacted into an LDS list (ballot), then a 4-tile-unrolled
// branch-free main loop: 16 independent loads in flight, 8 independent MFMA chains.
template<int DH>
__global__ __launch_bounds__(256) void pv_kernel(
    const u16* __restrict__ W, const u16* __restrict__ hT,
    const int* __restrict__ flags, const float* __restrict__ h,
    const float* __restrict__ cs, float* __restrict__ o) {
  __shared__ int list[64];
  __shared__ int nact_s;
  int ib = blockIdx.x;
  int w = threadIdx.x >> 6, l = threadIdx.x & 63;
  int lr = l & 15, lk = l >> 4;
  int i0 = ib * 16;
  int d0 = blockIdx.y * 64 + w * 16;
  const int* frow = flags + (i0 >> 6) * 64;
  if (threadIdx.x < 64) {
    int f = frow[threadIdx.x] != 0;
    unsigned long long m = __ballot(f);
    int pos = __popcll(m & ((1ULL << threadIdx.x) - 1ULL));
    if (f) list[pos] = threadIdx.x;
    if (threadIdx.x == 0) nact_s = __popcll(m);
  }
  __syncthreads();
  int nact = nact_s;

  const u16* Wrow = W + (size_t)(i0 + lr) * NN + lk * 8;
  const u16* Trow = hT + (size_t)(d0 + lr) * NN + lk * 8;
  f32x4 acc[8];
  #pragma unroll
  for (int u = 0; u < 8; ++u) acc[u] = (f32x4){0.f, 0.f, 0.f, 0.f};

  int t = 0;
  for (; t + 4 <= nact; t += 4) {
    short8 av[8], bv[8];
    #pragma unroll
    for (int u = 0; u < 4; ++u) {
      int j0 = list[t + u] * 64;
      av[2 * u]     = *(const short8*)(Wrow + j0);
      av[2 * u + 1] = *(const short8*)(Wrow + j0 + 32);
      bv[2 * u]     = *(const short8*)(Trow + j0);
      bv[2 * u + 1] = *(const short8*)(Trow + j0 + 32);
    }
    #pragma unroll
    for (int u = 0; u < 8; ++u)
      acc[u] = __builtin_amdgcn_mfma_f32_16x16x32_bf16(av[u], bv[u], acc[u], 0, 0, 0);
  }
  for (; t < nact; ++t) {
    int j0 = list[t] * 64;
    short8 a0 = *(const short8*)(Wrow + j0);
    short8 a1 = *(const short8*)(Wrow + j0 + 32);
    short8 b0 = *(const short8*)(Trow + j0);
    short8 b1 = *(const short8*)(Trow + j0 + 32);
    acc[0] = __builtin_amdgcn_mfma_f32_16x16x32_bf16(a0, b0, acc[0], 0, 0, 0);
    acc[1] = __builtin_amdgcn_mfma_f32_16x16x32_bf16(a1, b1, acc[1], 0, 0, 0);
  }

  int d = d0 + lr;
  #pragma unroll
  for (int q = 0; q < 4; ++q) {
    int i = i0 + 4 * lk + q;
    size_t idx = (size_t)i * DH + d;
    float s = 0.f;
    #pragma unroll
    for (int u = 0; u < 8; ++u) s += acc[u][q];
    o[idx] = o[idx] + h[idx] + 0.5f * cs[d] + 0.5f * s;
  }
}

// ---------------- final row-normalize (in place on d_out) ----------------
__global__ __launch_bounds__(256) void norm_kernel(float* __restrict__ out) {
  int wid = threadIdx.x >> 6, lane = threadIdx.x & 63;
  int i = blockIdx.x * 4 + wid;
  float x = out[(size_t)i * 64 + lane];
  float s = x * x;
  #pragma unroll
  for (int m = 32; m > 0; m >>= 1) s += __shfl_xor(s, m);
  float n = sqrtf(s);
  out[(size_t)i * 64 + lane] = x / fmaxf(n, 1e-12f);
}

// ---------------- host-side orchestration ----------------
struct Scratch {
  float *al, *ar, *inv, *denom, *cs, *eS;
  int *counts, *offsets, *cursor, *dstS, *flags;
  u16 *hhi, *hlo, *hT, *W;
};

template<int DH>
static void run_attention(const float* h, const float* aw, const float* ab, float* o,
                          const int* src, const int* dst, const Scratch& S, hipStream_t stream) {
  rowstats_kernel<DH><<<NN / 4, 256, 0, stream>>>(h, aw, S.al, S.ar, S.inv);
  hipMemsetAsync(S.cs, 0, DH * sizeof(float), stream);
  colsum_kernel<DH><<<32, DH, 0, stream>>>(h, S.cs);
  convert_kernel<<<NN * DH / 256, 256, 0, stream>>>(h, S.hhi, S.hlo);
  transpose_kernel<DH><<<dim3(DH / 32, NN / 32), 256, 0, stream>>>(h, S.hT);
  hipMemsetAsync(S.flags, 0, 4096 * sizeof(int), stream);
  hipMemsetAsync(S.counts, 0, NN * sizeof(int), stream);
  hist_kernel<<<NE / 256, 256, 0, stream>>>(src, S.counts);
  scan_kernel<<<1, 1024, 0, stream>>>(S.counts, S.offsets, S.cursor);
  hipMemsetAsync(S.denom, 0, NN * sizeof(float), stream);
  scatter_kernel<<<NE / 256, 256, 0, stream>>>(src, dst, S.al, S.ar, ab,
                                               S.denom, S.cursor, S.dstS, S.eS);
  gather_kernel<DH><<<NN / 4, 256, 0, stream>>>(h, S.offsets, S.dstS, S.eS, S.denom, o);
  qk_kernel<DH><<<dim3(NN / 64, NN / 64), 256, 0, stream>>>(
      S.hhi, S.hlo, S.al, S.ar, S.inv, ab, S.W, S.flags);
  pv_kernel<DH><<<dim3(NN / 16, DH / 64), 256, 0, stream>>>(
      S.W, S.hT, S.flags, h, S.cs, o);
}

extern "C" void kernel_launch(void* const* d_in, const int* in_sizes, int n_in,
                              void* d_out, int out_size, void* d_ws, size_t ws_size,
                              hipStream_t stream) {
  const float* X   = (const float*)d_in[0];
  const int*   ei  = (const int*)d_in[1];
  const float* W1  = (const float*)d_in[2];
  const float* b1  = (const float*)d_in[3];
  const float* a1w = (const float*)d_in[4];
  const float* a1b = (const float*)d_in[5];
  const float* W2  = (const float*)d_in[6];
  const float* b2  = (const float*)d_in[7];
  const float* a2w = (const float*)d_in[8];
  const float* a2b = (const float*)d_in[9];
  const float* W3  = (const float*)d_in[10];
  const float* b3  = (const float*)d_in[11];
  float* out = (float*)d_out;

  const int* src = ei;
  const int* dst = ei + NE;

  char* p = (char*)d_ws;
  auto alloc = [&](size_t bytes) { char* r = p; p += (bytes + 255) & ~(size_t)255; return r; };
  float* h1 = (float*)alloc((size_t)NN * 256 * 4);
  float* o1 = (float*)alloc((size_t)NN * 256 * 4);
  float* h2 = (float*)alloc((size_t)NN * 128 * 4);
  float* o2 = (float*)alloc((size_t)NN * 128 * 4);
  Scratch S;
  S.hhi = (u16*)alloc((size_t)NN * 256 * 2);
  S.hlo = (u16*)alloc((size_t)NN * 256 * 2);
  S.hT  = (u16*)alloc((size_t)NN * 256 * 2);
  S.W   = (u16*)alloc((size_t)NN * NN * 2);
  S.flags = (int*)alloc(4096 * 4);
  S.al    = (float*)alloc(NN * 4);
  S.ar    = (float*)alloc(NN * 4);
  S.inv   = (float*)alloc(NN * 4);
  S.denom = (float*)alloc(NN * 4);
  S.cs    = (float*)alloc(256 * 4);
  S.eS    = (float*)alloc((size_t)NE * 4);
  S.counts  = (int*)alloc(NN * 4);
  S.offsets = (int*)alloc((NN + 1) * 4);
  S.cursor  = (int*)alloc(NN * 4);
  S.dstS    = (int*)alloc((size_t)NE * 4);

  // layer 1
  gemm_kernel<false><<<dim3(NN / 64, 256 / 64), 256, 0, stream>>>(X, W1, b1, h1, 128, 256);
  run_attention<256>(h1, a1w, a1b, o1, src, dst, S, stream);
  // layer 2
  gemm_kernel<true><<<dim3(NN / 64, 128 / 64), 256, 0, stream>>>(o1, W2, b2, h2, 256, 128);
  run_attention<128>(h2, a2w, a2b, o2, src, dst, S, stream);
  // output layer + normalize
  gemm_kernel<true><<<dim3(NN / 64, 64 / 64), 256, 0, stream>>>(o2, W3, b3, out, 128, 64);
  norm_kernel<<<NN / 4, 256, 0, stream>>>(out);
}

// Round 8
// 397.487 us; speedup vs baseline: 5.9163x; 1.2025x over previous
//
#include <hip/hip_runtime.h>
#include <math.h>

#define NN 4096
#define NE 131072

typedef short short8 __attribute__((ext_vector_type(8)));
typedef float f32x4 __attribute__((ext_vector_type(4)));
typedef unsigned short u16;

__device__ __forceinline__ float lrelu_f(float x) { return x > 0.0f ? x : 0.01f * x; }

__device__ __forceinline__ u16 f2bf(float x) {
  unsigned int u = __float_as_uint(x);
  unsigned int r = (u + 0x7FFF + ((u >> 16) & 1)) >> 16;   // RNE
  return (u16)r;
}
__device__ __forceinline__ float bf2f(u16 b) { return __uint_as_float(((unsigned int)b) << 16); }

__device__ __forceinline__ void gload_lds16(const u16* g, u16* l) {
  __builtin_amdgcn_global_load_lds((const __attribute__((address_space(1))) void*)g,
                                   (__attribute__((address_space(3))) void*)l, 16, 0, 0);
}

// ---------------- GEMM: O[M,P] = act(A)[M,K] @ W[K,P] + b ----------------
template<bool RELU_A>
__global__ __launch_bounds__(256) void gemm_kernel(const float* __restrict__ A,
    const float* __restrict__ W, const float* __restrict__ bias,
    float* __restrict__ O, int K, int P) {
  __shared__ float As[64][33];
  __shared__ float Ws[32][65];
  int i0 = blockIdx.x * 64, n0 = blockIdx.y * 64;
  int t = threadIdx.x, ty = t >> 4, tx = t & 15;
  float acc[4][4] = {};
  for (int k0 = 0; k0 < K; k0 += 32) {
    __syncthreads();
    for (int idx = t; idx < 64 * 32; idx += 256) {
      int r = idx >> 5, k = idx & 31;
      float v = A[(size_t)(i0 + r) * K + k0 + k];
      if (RELU_A) v = fmaxf(v, 0.0f);
      As[r][k] = v;
    }
    for (int idx = t; idx < 32 * 64; idx += 256) {
      int k = idx >> 6, n = idx & 63;
      Ws[k][n] = W[(size_t)(k0 + k) * P + n0 + n];
    }
    __syncthreads();
    for (int k = 0; k < 32; ++k) {
      float a[4], b[4];
      #pragma unroll
      for (int q = 0; q < 4; ++q) a[q] = As[4 * ty + q][k];
      #pragma unroll
      for (int p = 0; p < 4; ++p) b[p] = Ws[k][4 * tx + p];
      #pragma unroll
      for (int q = 0; q < 4; ++q)
        #pragma unroll
        for (int p = 0; p < 4; ++p) acc[q][p] = fmaf(a[q], b[p], acc[q][p]);
    }
  }
  #pragma unroll
  for (int q = 0; q < 4; ++q)
    #pragma unroll
    for (int p = 0; p < 4; ++p)
      O[(size_t)(i0 + 4 * ty + q) * P + n0 + 4 * tx + p] = acc[q][p] + bias[n0 + 4 * tx + p];
}

// ---------------- row stats: inv_norm, al, ar ----------------
template<int DH>
__global__ __launch_bounds__(256) void rowstats_kernel(const float* __restrict__ h,
    const float* __restrict__ aw, float* __restrict__ al, float* __restrict__ ar,
    float* __restrict__ inv) {
  constexpr int NC = DH / 64;
  int wid = threadIdx.x >> 6, lane = threadIdx.x & 63;
  int i = blockIdx.x * 4 + wid;
  float s2 = 0.f, sl = 0.f, sr = 0.f;
  #pragma unroll
  for (int c = 0; c < NC; ++c) {
    float x = h[(size_t)i * DH + c * 64 + lane];
    s2 = fmaf(x, x, s2);
    sl = fmaf(x, aw[c * 64 + lane], sl);
    sr = fmaf(x, aw[DH + c * 64 + lane], sr);
  }
  #pragma unroll
  for (int m = 32; m > 0; m >>= 1) {
    s2 += __shfl_xor(s2, m);
    sl += __shfl_xor(sl, m);
    sr += __shfl_xor(sr, m);
  }
  if (lane == 0) { al[i] = sl; ar[i] = sr; inv[i] = rsqrtf(s2); }
}

// ---------------- column sum ----------------
template<int DH>
__global__ void colsum_kernel(const float* __restrict__ h, float* __restrict__ cs) {
  int d = threadIdx.x;             // blockDim == DH
  int r0 = blockIdx.x * (NN / 32);
  float s = 0.f;
  for (int i = 0; i < NN / 32; ++i) s += h[(size_t)(r0 + i) * DH + d];
  atomicAdd(&cs[d], s);
}

// ---------------- convert h -> bf16 hi/lo (row-major) ----------------
__global__ __launch_bounds__(256) void convert_kernel(const float* __restrict__ h,
    u16* __restrict__ hhi, u16* __restrict__ hlo) {
  int idx = blockIdx.x * 256 + threadIdx.x;
  float x = h[idx];
  u16 hi = f2bf(x);
  float lo = x - bf2f(hi);
  hhi[idx] = hi;
  hlo[idx] = f2bf(lo);
}

// ---------------- transpose h(fp32 [NN][DH]) -> hT(bf16 [DH][NN]) ----------------
template<int DH>
__global__ __launch_bounds__(256) void transpose_kernel(const float* __restrict__ h,
    u16* __restrict__ hT) {
  __shared__ u16 tile[32][33];
  int bx = blockIdx.x;   // d / 32
  int by = blockIdx.y;   // i / 32
  int t = threadIdx.x, tx = t & 31, ty8 = t >> 5;   // 32 x 8
  #pragma unroll
  for (int r = 0; r < 4; ++r) {
    int i = by * 32 + ty8 + r * 8;
    int d = bx * 32 + tx;
    tile[ty8 + r * 8][tx] = f2bf(h[(size_t)i * DH + d]);
  }
  __syncthreads();
  #pragma unroll
  for (int r = 0; r < 4; ++r) {
    int d = bx * 32 + ty8 + r * 8;
    int i = by * 32 + tx;
    hT[(size_t)d * NN + i] = tile[tx][ty8 + r * 8];
  }
}

// ---------------- CSR build ----------------
__global__ void hist_kernel(const int* __restrict__ src, int* __restrict__ counts) {
  int e = blockIdx.x * 256 + threadIdx.x;
  atomicAdd(&counts[src[e]], 1);
}

__global__ __launch_bounds__(1024) void scan_kernel(const int* __restrict__ counts,
    int* __restrict__ offsets, int* __restrict__ cursor) {
  __shared__ int part[1024];
  int t = threadIdx.x;
  int v[4]; int run = 0;
  #pragma unroll
  for (int j = 0; j < 4; ++j) { v[j] = counts[4 * t + j]; run += v[j]; }
  part[t] = run;
  __syncthreads();
  for (int off = 1; off < 1024; off <<= 1) {
    int y = (t >= off) ? part[t - off] : 0;
    __syncthreads();
    part[t] += y;
    __syncthreads();
  }
  int base = part[t] - run;
  #pragma unroll
  for (int j = 0; j < 4; ++j) { offsets[4 * t + j] = base; cursor[4 * t + j] = base; base += v[j]; }
  if (t == 1023) offsets[NN] = base;
}

__global__ void scatter_kernel(const int* __restrict__ src, const int* __restrict__ dst,
    const float* __restrict__ al, const float* __restrict__ ar, const float* __restrict__ ab,
    float* __restrict__ denom, int* __restrict__ cursor,
    int* __restrict__ dstS, float* __restrict__ eS) {
  int e = blockIdx.x * 256 + threadIdx.x;
  int s = src[e], d = dst[e];
  float v = expf(lrelu_f(al[s] + ar[d] + ab[0]));
  atomicAdd(&denom[s], v);
  int p = atomicAdd(&cursor[s], 1);
  dstS[p] = d; eS[p] = v;
}

// ---------------- edge-branch gather: o = 0.5 * nbr ----------------
template<int DH>
__global__ __launch_bounds__(256) void gather_kernel(const float* __restrict__ h,
    const int* __restrict__ offsets, const int* __restrict__ dstS,
    const float* __restrict__ eS, const float* __restrict__ denom,
    float* __restrict__ o) {
  constexpr int NC = DH / 64;
  int wid = threadIdx.x >> 6, lane = threadIdx.x & 63;
  int i = blockIdx.x * 4 + wid;
  int beg = offsets[i], end = offsets[i + 1];
  float rd = (beg < end) ? 1.0f / denom[i] : 0.0f;
  float acc[NC] = {};
  for (int k = beg; k < end; ++k) {
    int d = dstS[k];
    float a = eS[k] * rd;
    #pragma unroll
    for (int c = 0; c < NC; ++c)
      acc[c] = fmaf(a, h[(size_t)d * DH + c * 64 + lane], acc[c]);
  }
  #pragma unroll
  for (int c = 0; c < NC; ++c)
    o[(size_t)i * DH + c * 64 + lane] = 0.5f * acc[c];
}

// ---------------- Pass 1: QK^T (split bf16 MFMA) -> Delta weights W (bf16) + tile flags ----
// Grid (NN/64, NN/64) — full j-split. Block 256 = 4 waves; wave w owns i-rows
// [i0+16w, i0+16w+16). A+B hi/lo tiles staged to LDS via global_load_lds (16B),
// double-buffered per 32-wide k-chunk; B shared by all 4 waves.
template<int DH>
__global__ __launch_bounds__(256) void qk_kernel(
    const u16* __restrict__ hhi, const u16* __restrict__ hlo,
    const float* __restrict__ al, const float* __restrict__ ar,
    const float* __restrict__ inv, const float* __restrict__ ab,
    u16* __restrict__ W, int* __restrict__ flags) {
  constexpr int KC = DH / 32;
  __shared__ u16 sA[2][2][64][32];   // [buf][hi/lo][row][col]
  __shared__ u16 sB[2][2][64][32];
  int i0 = blockIdx.x * 64;
  int j0 = blockIdx.y * 64;
  int w = threadIdx.x >> 6, l = threadIdx.x & 63;
  int lr = l & 15, lk = l >> 4;
  int iw = i0 + 16 * w;
  int srow = l >> 2, scol = (l & 3) * 8;   // staging: lane -> (row srow, col scol) of wave quarter

  const u16* gAh = hhi + (size_t)(i0 + 16 * w + srow) * DH + scol;
  const u16* gAl = hlo + (size_t)(i0 + 16 * w + srow) * DH + scol;
  const u16* gBh = hhi + (size_t)(j0 + 16 * w + srow) * DH + scol;
  const u16* gBl = hlo + (size_t)(j0 + 16 * w + srow) * DH + scol;

  f32x4 ahh[4], ahl[4], alh[4];
  #pragma unroll
  for (int s = 0; s < 4; ++s) {
    ahh[s] = (f32x4){0.f, 0.f, 0.f, 0.f};
    ahl[s] = (f32x4){0.f, 0.f, 0.f, 0.f};
    alh[s] = (f32x4){0.f, 0.f, 0.f, 0.f};
  }

  // prologue: stage chunk 0 into buf 0
  gload_lds16(gAh, &sA[0][0][16 * w][0]);
  gload_lds16(gAl, &sA[0][1][16 * w][0]);
  gload_lds16(gBh, &sB[0][0][16 * w][0]);
  gload_lds16(gBl, &sB[0][1][16 * w][0]);
  __syncthreads();

  int cur = 0;
  for (int c = 0; c < KC; ++c) {
    if (c + 1 < KC) {
      int nb = cur ^ 1;
      gload_lds16(gAh + (c + 1) * 32, &sA[nb][0][16 * w][0]);
      gload_lds16(gAl + (c + 1) * 32, &sA[nb][1][16 * w][0]);
      gload_lds16(gBh + (c + 1) * 32, &sB[nb][0][16 * w][0]);
      gload_lds16(gBl + (c + 1) * 32, &sB[nb][1][16 * w][0]);
    }
    short8 Ah = *(const short8*)&sA[cur][0][16 * w + lr][lk * 8];
    short8 Al = *(const short8*)&sA[cur][1][16 * w + lr][lk * 8];
    #pragma unroll
    for (int s = 0; s < 4; ++s) {
      short8 Bh = *(const short8*)&sB[cur][0][16 * s + lr][lk * 8];
      short8 Bl = *(const short8*)&sB[cur][1][16 * s + lr][lk * 8];
      ahh[s] = __builtin_amdgcn_mfma_f32_16x16x32_bf16(Ah, Bh, ahh[s], 0, 0, 0);
      ahl[s] = __builtin_amdgcn_mfma_f32_16x16x32_bf16(Ah, Bl, ahl[s], 0, 0, 0);
      alh[s] = __builtin_amdgcn_mfma_f32_16x16x32_bf16(Al, Bh, alh[s], 0, 0, 0);
    }
    __syncthreads();   // drains vmcnt (next chunk staged) + all reads of cur done
    cur ^= 1;
  }

  float ali[4], invi[4];
  #pragma unroll
  for (int q = 0; q < 4; ++q) { int i = iw + 4 * lk + q; ali[q] = al[i]; invi[q] = inv[i]; }
  float abv = ab[0];
  int wany = 0;
  #pragma unroll
  for (int s = 0; s < 4; ++s) {
    int j = j0 + 16 * s + lr;
    float sv = ar[j] + abv;
    float invj = inv[j];
    #pragma unroll
    for (int q = 0; q < 4; ++q) {
      float sum = ahh[s][q] + ahl[s][q] + alh[s][q];
      float C = sum * invi[q] * invj;
      float wv = 0.0f;
      if (C > 0.36f) wv = expm1f(C * lrelu_f(ali[q] + sv));
      if (wv != 0.0f) wany = 1;
      W[(size_t)(iw + 4 * lk + q) * NN + j] = f2bf(wv);
    }
  }
  if (__any(wany) && l == 0) atomicOr(&flags[(i0 >> 6) * 64 + (j0 >> 6)], 1);
}

// ---------------- Pass 2: o += h + 0.5*cs + 0.5*(W @ h), flag-gated ----------------
// Grid (NN/16, DH/64). Block 256 = 4 waves; wave w owns d-cols [dblk*64+16w, +16).
// Latency hidden via global_load_lds double-buffering (zero-VGPR prefetch).
// LDS is staged with a source-column XOR swizzle (col' = col ^ ((row&7)<<3), 8-u16
// granule) so the strided fragment reads are bank-conflict-free; the same XOR is
// applied on the ds_read side (both-sides-or-neither).
template<int DH>
__global__ __launch_bounds__(256) void pv_kernel(
    const u16* __restrict__ W, const u16* __restrict__ hT,
    const int* __restrict__ flags, const float* __restrict__ h,
    const float* __restrict__ cs, float* __restrict__ o) {
  __shared__ u16 sW[2][16][64];      // W tile: rows i0..i0+15, 64 j (swizzled cols)
  __shared__ u16 sT[2][4][16][64];   // per-wave hT tile: rows d0..d0+15, 64 j
  __shared__ int list[64];
  __shared__ int nact_s;
  int ib = blockIdx.x;
  int w = threadIdx.x >> 6, l = threadIdx.x & 63;
  int lr = l & 15, lk = l >> 4;
  int i0 = ib * 16;
  int d0 = blockIdx.y * 64 + w * 16;
  const int* frow = flags + (i0 >> 6) * 64;
  if (threadIdx.x < 64) {
    int f = frow[threadIdx.x] != 0;
    unsigned long long m = __ballot(f);
    int pos = __popcll(m & ((1ULL << threadIdx.x) - 1ULL));
    if (f) list[pos] = threadIdx.x;
    if (threadIdx.x == 0) nact_s = __popcll(m);
  }
  __syncthreads();
  int nact = nact_s;

  // staging geometry: instr m covers rows m*8 + (l>>3), col chunk (l&7)*8,
  // source col pre-swizzled: scol = ((l&7)*8) ^ ((row&7)<<3)
  int srow0 = l >> 3;                      // row within 8-row group
  int scol = ((l & 7) * 8) ^ ((srow0 & 7) << 3);
  const u16* gW0 = W + (size_t)(i0 + srow0) * NN + scol;       // + m*8*NN + j0
  const u16* gT0 = hT + (size_t)(d0 + srow0) * NN + scol;
  f32x4 acc0 = {0.f, 0.f, 0.f, 0.f};
  f32x4 acc1 = {0.f, 0.f, 0.f, 0.f};

  if (nact > 0) {
    // prologue: stage tile list[0] into buf 0
    {
      int j0 = list[0] * 64;
      if (w == 0) {
        gload_lds16(gW0 + j0, &sW[0][0][0]);
        gload_lds16(gW0 + 8 * NN + j0, &sW[0][8][0]);
      }
      gload_lds16(gT0 + j0, &sT[0][w][0][0]);
      gload_lds16(gT0 + 8 * NN + j0, &sT[0][w][8][0]);
    }
    __syncthreads();
    int cur = 0;
    for (int t = 0; t < nact; ++t) {
      if (t + 1 < nact) {
        int jn = list[t + 1] * 64;
        int nb = cur ^ 1;
        if (w == 0) {
          gload_lds16(gW0 + jn, &sW[nb][0][0]);
          gload_lds16(gW0 + 8 * NN + jn, &sW[nb][8][0]);
        }
        gload_lds16(gT0 + jn, &sT[nb][w][0][0]);
        gload_lds16(gT0 + 8 * NN + jn, &sT[nb][w][8][0]);
      }
      int sx = (lr & 7) << 3;                    // read-side XOR for row lr
      short8 a0 = *(const short8*)&sW[cur][lr][(lk * 8) ^ sx];
      short8 a1 = *(const short8*)&sW[cur][lr][(32 + lk * 8) ^ sx];
      short8 b0 = *(const short8*)&sT[cur][w][lr][(lk * 8) ^ sx];
      short8 b1 = *(const short8*)&sT[cur][w][lr][(32 + lk * 8) ^ sx];
      acc0 = __builtin_amdgcn_mfma_f32_16x16x32_bf16(a0, b0, acc0, 0, 0, 0);
      acc1 = __builtin_amdgcn_mfma_f32_16x16x32_bf16(a1, b1, acc1, 0, 0, 0);
      __syncthreads();   // drains vmcnt (next tile staged) + all reads of cur done
      cur ^= 1;
    }
  }

  int d = d0 + lr;
  #pragma unroll
  for (int q = 0; q < 4; ++q) {
    int i = i0 + 4 * lk + q;
    size_t idx = (size_t)i * DH + d;
    o[idx] = o[idx] + h[idx] + 0.5f * cs[d] + 0.5f * (acc0[q] + acc1[q]);
  }
}

// ---------------- final row-normalize (in place on d_out) ----------------
__global__ __launch_bounds__(256) void norm_kernel(float* __restrict__ out) {
  int wid = threadIdx.x >> 6, lane = threadIdx.x & 63;
  int i = blockIdx.x * 4 + wid;
  float x = out[(size_t)i * 64 + lane];
  float s = x * x;
  #pragma unroll
  for (int m = 32; m > 0; m >>= 1) s += __shfl_xor(s, m);
  float n = sqrtf(s);
  out[(size_t)i * 64 + lane] = x / fmaxf(n, 1e-12f);
}

// ---------------- host-side orchestration ----------------
struct Scratch {
  float *al, *ar, *inv, *denom, *cs, *eS;
  int *counts, *offsets, *cursor, *dstS, *flags;
  u16 *hhi, *hlo, *hT, *W;
};

template<int DH>
static void run_attention(const float* h, const float* aw, const float* ab, float* o,
                          const int* src, const int* dst, const Scratch& S, hipStream_t stream) {
  rowstats_kernel<DH><<<NN / 4, 256, 0, stream>>>(h, aw, S.al, S.ar, S.inv);
  hipMemsetAsync(S.cs, 0, DH * sizeof(float), stream);
  colsum_kernel<DH><<<32, DH, 0, stream>>>(h, S.cs);
  convert_kernel<<<NN * DH / 256, 256, 0, stream>>>(h, S.hhi, S.hlo);
  transpose_kernel<DH><<<dim3(DH / 32, NN / 32), 256, 0, stream>>>(h, S.hT);
  hipMemsetAsync(S.flags, 0, 4096 * sizeof(int), stream);
  hipMemsetAsync(S.counts, 0, NN * sizeof(int), stream);
  hist_kernel<<<NE / 256, 256, 0, stream>>>(src, S.counts);
  scan_kernel<<<1, 1024, 0, stream>>>(S.counts, S.offsets, S.cursor);
  hipMemsetAsync(S.denom, 0, NN * sizeof(float), stream);
  scatter_kernel<<<NE / 256, 256, 0, stream>>>(src, dst, S.al, S.ar, ab,
                                               S.denom, S.cursor, S.dstS, S.eS);
  gather_kernel<DH><<<NN / 4, 256, 0, stream>>>(h, S.offsets, S.dstS, S.eS, S.denom, o);
  qk_kernel<DH><<<dim3(NN / 64, NN / 64), 256, 0, stream>>>(
      S.hhi, S.hlo, S.al, S.ar, S.inv, ab, S.W, S.flags);
  pv_kernel<DH><<<dim3(NN / 16, DH / 64), 256, 0, stream>>>(
      S.W, S.hT, S.flags, h, S.cs, o);
}

extern "C" void kernel_launch(void* const* d_in, const int* in_sizes, int n_in,
                              void* d_out, int out_size, void* d_ws, size_t ws_size,
                              hipStream_t stream) {
  const float* X   = (const float*)d_in[0];
  const int*   ei  = (const int*)d_in[1];
  const float* W1  = (const float*)d_in[2];
  const float* b1  = (const float*)d_in[3];
  const float* a1w = (const float*)d_in[4];
  const float* a1b = (const float*)d_in[5];
  const float* W2  = (const float*)d_in[6];
  const float* b2  = (const float*)d_in[7];
  const float* a2w = (const float*)d_in[8];
  const float* a2b = (const float*)d_in[9];
  const float* W3  = (const float*)d_in[10];
  const float* b3  = (const float*)d_in[11];
  float* out = (float*)d_out;

  const int* src = ei;
  const int* dst = ei + NE;

  char* p = (char*)d_ws;
  auto alloc = [&](size_t bytes) { char* r = p; p += (bytes + 255) & ~(size_t)255; return r; };
  float* h1 = (float*)alloc((size_t)NN * 256 * 4);
  float* o1 = (float*)alloc((size_t)NN * 256 * 4);
  float* h2 = (float*)alloc((size_t)NN * 128 * 4);
  float* o2 = (float*)alloc((size_t)NN * 128 * 4);
  Scratch S;
  S.hhi = (u16*)alloc((size_t)NN * 256 * 2);
  S.hlo = (u16*)alloc((size_t)NN * 256 * 2);
  S.hT  = (u16*)alloc((size_t)NN * 256 * 2);
  S.W   = (u16*)alloc((size_t)NN * NN * 2);
  S.flags = (int*)alloc(4096 * 4);
  S.al    = (float*)alloc(NN * 4);
  S.ar    = (float*)alloc(NN * 4);
  S.inv   = (float*)alloc(NN * 4);
  S.denom = (float*)alloc(NN * 4);
  S.cs    = (float*)alloc(256 * 4);
  S.eS    = (float*)alloc((size_t)NE * 4);
  S.counts  = (int*)alloc(NN * 4);
  S.offsets = (int*)alloc((NN + 1) * 4);
  S.cursor  = (int*)alloc(NN * 4);
  S.dstS    = (int*)alloc((size_t)NE * 4);

  // layer 1
  gemm_kernel<false><<<dim3(NN / 64, 256 / 64), 256, 0, stream>>>(X, W1, b1, h1, 128, 256);
  run_attention<256>(h1, a1w, a1b, o1, src, dst, S, stream);
  // layer 2
  gemm_kernel<true><<<dim3(NN / 64, 128 / 64), 256, 0, stream>>>(o1, W2, b2, h2, 256, 128);
  run_attention<128>(h2, a2w, a2b, o2, src, dst, S, stream);
  // output layer + normalize
  gemm_kernel<true><<<dim3(NN / 64, 64 / 64), 256, 0, stream>>>(o2, W3, b3, out, 128, 64);
  norm_kernel<<<NN / 4, 256, 0, stream>>>(out);
}

// Round 9
// 345.916 us; speedup vs baseline: 6.7984x; 1.1491x over previous
//
#include <hip/hip_runtime.h>
#include <math.h>

#define NN 4096
#define NE 131072

typedef short short8 __attribute__((ext_vector_type(8)));
typedef float f32x4 __attribute__((ext_vector_type(4)));
typedef unsigned short u16;

__device__ __forceinline__ float lrelu_f(float x) { return x > 0.0f ? x : 0.01f * x; }

__device__ __forceinline__ u16 f2bf(float x) {
  unsigned int u = __float_as_uint(x);
  unsigned int r = (u + 0x7FFF + ((u >> 16) & 1)) >> 16;   // RNE
  return (u16)r;
}
__device__ __forceinline__ float bf2f(u16 b) { return __uint_as_float(((unsigned int)b) << 16); }

__device__ __forceinline__ void gload_lds16(const u16* g, u16* l) {
  __builtin_amdgcn_global_load_lds((const __attribute__((address_space(1))) void*)g,
                                   (__attribute__((address_space(3))) void*)l, 16, 0, 0);
}

// ---------------- weight transpose+split: W[K][P] fp32 -> WT[P][K] bf16 hi/lo ----------------
__global__ __launch_bounds__(256) void wtrans_kernel(const float* __restrict__ W,
    u16* __restrict__ WThi, u16* __restrict__ WTlo, int K, int P) {
  __shared__ u16 th[32][33], tl[32][33];
  int bp = blockIdx.x, bk = blockIdx.y;
  int t = threadIdx.x, tx = t & 31, ty8 = t >> 5;
  #pragma unroll
  for (int r = 0; r < 4; ++r) {
    int k = bk * 32 + ty8 + r * 8;
    int p = bp * 32 + tx;
    float x = W[(size_t)k * P + p];
    u16 hi = f2bf(x);
    th[ty8 + r * 8][tx] = hi;
    tl[ty8 + r * 8][tx] = f2bf(x - bf2f(hi));
  }
  __syncthreads();
  #pragma unroll
  for (int r = 0; r < 4; ++r) {
    int p = bp * 32 + ty8 + r * 8;
    int k = bk * 32 + tx;
    WThi[(size_t)p * K + k] = th[tx][ty8 + r * 8];
    WTlo[(size_t)p * K + k] = tl[tx][ty8 + r * 8];
  }
}

// ---------------- gemm input convert: ghi/glo = bf16 split of (relu?) x ----------------
template<bool RELU>
__global__ __launch_bounds__(256) void convert_io_kernel(const float* __restrict__ x,
    u16* __restrict__ ghi, u16* __restrict__ glo) {
  int idx = blockIdx.x * 256 + threadIdx.x;
  float v = x[idx];
  if (RELU) v = fmaxf(v, 0.0f);
  u16 hi = f2bf(v);
  ghi[idx] = hi;
  glo[idx] = f2bf(v - bf2f(hi));
}

// ---------------- MFMA GEMM: O[NN][P] = Asplit @ WTsplit^T + bias ----------------
// Grid (NN/16, P/64). Block 256 = 4 waves; wave w owns cols [p0+16w, +16).
// 3-term split (hi*hi + hi*lo + lo*hi) = fp32-grade precision; 3 independent chains.
template<int K, int P>
__global__ __launch_bounds__(256) void mgemm_kernel(
    const u16* __restrict__ Ahi, const u16* __restrict__ Alo,
    const u16* __restrict__ WThi, const u16* __restrict__ WTlo,
    const float* __restrict__ bias, float* __restrict__ O) {
  constexpr int KC = K / 32;
  int w = threadIdx.x >> 6, l = threadIdx.x & 63;
  int lr = l & 15, lk = l >> 4;
  int i0 = blockIdx.x * 16;
  int p0 = blockIdx.y * 64 + w * 16;
  const u16* arh = Ahi + (size_t)(i0 + lr) * K + lk * 8;
  const u16* arl = Alo + (size_t)(i0 + lr) * K + lk * 8;
  const u16* brh = WThi + (size_t)(p0 + lr) * K + lk * 8;
  const u16* brl = WTlo + (size_t)(p0 + lr) * K + lk * 8;
  f32x4 ahh = {0.f, 0.f, 0.f, 0.f};
  f32x4 ahl = {0.f, 0.f, 0.f, 0.f};
  f32x4 alh = {0.f, 0.f, 0.f, 0.f};
  #pragma unroll
  for (int c = 0; c < KC; ++c) {
    short8 Ah = *(const short8*)(arh + 32 * c);
    short8 Al = *(const short8*)(arl + 32 * c);
    short8 Bh = *(const short8*)(brh + 32 * c);
    short8 Bl = *(const short8*)(brl + 32 * c);
    ahh = __builtin_amdgcn_mfma_f32_16x16x32_bf16(Ah, Bh, ahh, 0, 0, 0);
    ahl = __builtin_amdgcn_mfma_f32_16x16x32_bf16(Ah, Bl, ahl, 0, 0, 0);
    alh = __builtin_amdgcn_mfma_f32_16x16x32_bf16(Al, Bh, alh, 0, 0, 0);
  }
  int p = p0 + lr;
  float bv = bias[p];
  #pragma unroll
  for (int q = 0; q < 4; ++q) {
    int i = i0 + 4 * lk + q;
    O[(size_t)i * P + p] = ahh[q] + ahl[q] + alh[q] + bv;
  }
}

// ---------------- row stats: inv_norm, al, ar ----------------
template<int DH>
__global__ __launch_bounds__(256) void rowstats_kernel(const float* __restrict__ h,
    const float* __restrict__ aw, float* __restrict__ al, float* __restrict__ ar,
    float* __restrict__ inv) {
  constexpr int NC = DH / 64;
  int wid = threadIdx.x >> 6, lane = threadIdx.x & 63;
  int i = blockIdx.x * 4 + wid;
  float s2 = 0.f, sl = 0.f, sr = 0.f;
  #pragma unroll
  for (int c = 0; c < NC; ++c) {
    float x = h[(size_t)i * DH + c * 64 + lane];
    s2 = fmaf(x, x, s2);
    sl = fmaf(x, aw[c * 64 + lane], sl);
    sr = fmaf(x, aw[DH + c * 64 + lane], sr);
  }
  #pragma unroll
  for (int m = 32; m > 0; m >>= 1) {
    s2 += __shfl_xor(s2, m);
    sl += __shfl_xor(sl, m);
    sr += __shfl_xor(sr, m);
  }
  if (lane == 0) { al[i] = sl; ar[i] = sr; inv[i] = rsqrtf(s2); }
}

// ---------------- column sum ----------------
template<int DH>
__global__ void colsum_kernel(const float* __restrict__ h, float* __restrict__ cs) {
  int d = threadIdx.x;             // blockDim == DH
  int r0 = blockIdx.x * (NN / 32);
  float s = 0.f;
  for (int i = 0; i < NN / 32; ++i) s += h[(size_t)(r0 + i) * DH + d];
  atomicAdd(&cs[d], s);
}

// ---------------- convert h -> bf16 hi/lo (row-major) ----------------
__global__ __launch_bounds__(256) void convert_kernel(const float* __restrict__ h,
    u16* __restrict__ hhi, u16* __restrict__ hlo) {
  int idx = blockIdx.x * 256 + threadIdx.x;
  float x = h[idx];
  u16 hi = f2bf(x);
  float lo = x - bf2f(hi);
  hhi[idx] = hi;
  hlo[idx] = f2bf(lo);
}

// ---------------- transpose h(fp32 [NN][DH]) -> hT(bf16 [DH][NN]) ----------------
template<int DH>
__global__ __launch_bounds__(256) void transpose_kernel(const float* __restrict__ h,
    u16* __restrict__ hT) {
  __shared__ u16 tile[32][33];
  int bx = blockIdx.x;   // d / 32
  int by = blockIdx.y;   // i / 32
  int t = threadIdx.x, tx = t & 31, ty8 = t >> 5;   // 32 x 8
  #pragma unroll
  for (int r = 0; r < 4; ++r) {
    int i = by * 32 + ty8 + r * 8;
    int d = bx * 32 + tx;
    tile[ty8 + r * 8][tx] = f2bf(h[(size_t)i * DH + d]);
  }
  __syncthreads();
  #pragma unroll
  for (int r = 0; r < 4; ++r) {
    int d = bx * 32 + ty8 + r * 8;
    int i = by * 32 + tx;
    hT[(size_t)d * NN + i] = tile[tx][ty8 + r * 8];
  }
}

// ---------------- CSR build ----------------
__global__ void hist_kernel(const int* __restrict__ src, int* __restrict__ counts) {
  int e = blockIdx.x * 256 + threadIdx.x;
  atomicAdd(&counts[src[e]], 1);
}

__global__ __launch_bounds__(1024) void scan_kernel(const int* __restrict__ counts,
    int* __restrict__ offsets, int* __restrict__ cursor) {
  __shared__ int part[1024];
  int t = threadIdx.x;
  int v[4]; int run = 0;
  #pragma unroll
  for (int j = 0; j < 4; ++j) { v[j] = counts[4 * t + j]; run += v[j]; }
  part[t] = run;
  __syncthreads();
  for (int off = 1; off < 1024; off <<= 1) {
    int y = (t >= off) ? part[t - off] : 0;
    __syncthreads();
    part[t] += y;
    __syncthreads();
  }
  int base = part[t] - run;
  #pragma unroll
  for (int j = 0; j < 4; ++j) { offsets[4 * t + j] = base; cursor[4 * t + j] = base; base += v[j]; }
  if (t == 1023) offsets[NN] = base;
}

__global__ void scatter_kernel(const int* __restrict__ src, const int* __restrict__ dst,
    const float* __restrict__ al, const float* __restrict__ ar, const float* __restrict__ ab,
    float* __restrict__ denom, int* __restrict__ cursor,
    int* __restrict__ dstS, float* __restrict__ eS) {
  int e = blockIdx.x * 256 + threadIdx.x;
  int s = src[e], d = dst[e];
  float v = expf(lrelu_f(al[s] + ar[d] + ab[0]));
  atomicAdd(&denom[s], v);
  int p = atomicAdd(&cursor[s], 1);
  dstS[p] = d; eS[p] = v;
}

// ---------------- edge-branch gather: o = 0.5 * nbr ----------------
template<int DH>
__global__ __launch_bounds__(256) void gather_kernel(const float* __restrict__ h,
    const int* __restrict__ offsets, const int* __restrict__ dstS,
    const float* __restrict__ eS, const float* __restrict__ denom,
    float* __restrict__ o) {
  constexpr int NC = DH / 64;
  int wid = threadIdx.x >> 6, lane = threadIdx.x & 63;
  int i = blockIdx.x * 4 + wid;
  int beg = offsets[i], end = offsets[i + 1];
  float rd = (beg < end) ? 1.0f / denom[i] : 0.0f;
  float acc[NC] = {};
  for (int k = beg; k < end; ++k) {
    int d = dstS[k];
    float a = eS[k] * rd;
    #pragma unroll
    for (int c = 0; c < NC; ++c)
      acc[c] = fmaf(a, h[(size_t)d * DH + c * 64 + lane], acc[c]);
  }
  #pragma unroll
  for (int c = 0; c < NC; ++c)
    o[(size_t)i * DH + c * 64 + lane] = 0.5f * acc[c];
}

// ---------------- Pass 1: QK^T (split bf16 MFMA) -> Delta weights W (bf16) + tile flags ----
template<int DH>
__global__ __launch_bounds__(256) void qk_kernel(
    const u16* __restrict__ hhi, const u16* __restrict__ hlo,
    const float* __restrict__ al, const float* __restrict__ ar,
    const float* __restrict__ inv, const float* __restrict__ ab,
    u16* __restrict__ W, int* __restrict__ flags) {
  constexpr int KC = DH / 32;
  __shared__ u16 sA[2][2][64][32];   // [buf][hi/lo][row][col]
  __shared__ u16 sB[2][2][64][32];
  int i0 = blockIdx.x * 64;
  int j0 = blockIdx.y * 64;
  int w = threadIdx.x >> 6, l = threadIdx.x & 63;
  int lr = l & 15, lk = l >> 4;
  int iw = i0 + 16 * w;
  int srow = l >> 2, scol = (l & 3) * 8;   // staging: lane -> (row srow, col scol) of wave quarter

  const u16* gAh = hhi + (size_t)(i0 + 16 * w + srow) * DH + scol;
  const u16* gAl = hlo + (size_t)(i0 + 16 * w + srow) * DH + scol;
  const u16* gBh = hhi + (size_t)(j0 + 16 * w + srow) * DH + scol;
  const u16* gBl = hlo + (size_t)(j0 + 16 * w + srow) * DH + scol;

  f32x4 ahh[4], ahl[4], alh[4];
  #pragma unroll
  for (int s = 0; s < 4; ++s) {
    ahh[s] = (f32x4){0.f, 0.f, 0.f, 0.f};
    ahl[s] = (f32x4){0.f, 0.f, 0.f, 0.f};
    alh[s] = (f32x4){0.f, 0.f, 0.f, 0.f};
  }

  // prologue: stage chunk 0 into buf 0
  gload_lds16(gAh, &sA[0][0][16 * w][0]);
  gload_lds16(gAl, &sA[0][1][16 * w][0]);
  gload_lds16(gBh, &sB[0][0][16 * w][0]);
  gload_lds16(gBl, &sB[0][1][16 * w][0]);
  __syncthreads();

  int cur = 0;
  for (int c = 0; c < KC; ++c) {
    if (c + 1 < KC) {
      int nb = cur ^ 1;
      gload_lds16(gAh + (c + 1) * 32, &sA[nb][0][16 * w][0]);
      gload_lds16(gAl + (c + 1) * 32, &sA[nb][1][16 * w][0]);
      gload_lds16(gBh + (c + 1) * 32, &sB[nb][0][16 * w][0]);
      gload_lds16(gBl + (c + 1) * 32, &sB[nb][1][16 * w][0]);
    }
    short8 Ah = *(const short8*)&sA[cur][0][16 * w + lr][lk * 8];
    short8 Al = *(const short8*)&sA[cur][1][16 * w + lr][lk * 8];
    #pragma unroll
    for (int s = 0; s < 4; ++s) {
      short8 Bh = *(const short8*)&sB[cur][0][16 * s + lr][lk * 8];
      short8 Bl = *(const short8*)&sB[cur][1][16 * s + lr][lk * 8];
      ahh[s] = __builtin_amdgcn_mfma_f32_16x16x32_bf16(Ah, Bh, ahh[s], 0, 0, 0);
      ahl[s] = __builtin_amdgcn_mfma_f32_16x16x32_bf16(Ah, Bl, ahl[s], 0, 0, 0);
      alh[s] = __builtin_amdgcn_mfma_f32_16x16x32_bf16(Al, Bh, alh[s], 0, 0, 0);
    }
    __syncthreads();   // drains vmcnt (next chunk staged) + all reads of cur done
    cur ^= 1;
  }

  float ali[4], invi[4];
  #pragma unroll
  for (int q = 0; q < 4; ++q) { int i = iw + 4 * lk + q; ali[q] = al[i]; invi[q] = inv[i]; }
  float abv = ab[0];
  int wany = 0;
  #pragma unroll
  for (int s = 0; s < 4; ++s) {
    int j = j0 + 16 * s + lr;
    float sv = ar[j] + abv;
    float invj = inv[j];
    #pragma unroll
    for (int q = 0; q < 4; ++q) {
      float sum = ahh[s][q] + ahl[s][q] + alh[s][q];
      float C = sum * invi[q] * invj;
      float wv = 0.0f;
      if (C > 0.36f) wv = expm1f(C * lrelu_f(ali[q] + sv));
      if (wv != 0.0f) wany = 1;
      W[(size_t)(iw + 4 * lk + q) * NN + j] = f2bf(wv);
    }
  }
  if (__any(wany) && l == 0) atomicOr(&flags[(i0 >> 6) * 64 + (j0 >> 6)], 1);
}

// ---------------- Pass 2: o += h + 0.5*cs + 0.5*(W @ h), flag-gated ----------------
template<int DH>
__global__ __launch_bounds__(256) void pv_kernel(
    const u16* __restrict__ W, const u16* __restrict__ hT,
    const int* __restrict__ flags, const float* __restrict__ h,
    const float* __restrict__ cs, float* __restrict__ o) {
  __shared__ u16 sW[2][16][64];      // W tile: rows i0..i0+15, 64 j (swizzled cols)
  __shared__ u16 sT[2][4][16][64];   // per-wave hT tile: rows d0..d0+15, 64 j
  __shared__ int list[64];
  __shared__ int nact_s;
  int ib = blockIdx.x;
  int w = threadIdx.x >> 6, l = threadIdx.x & 63;
  int lr = l & 15, lk = l >> 4;
  int i0 = ib * 16;
  int d0 = blockIdx.y * 64 + w * 16;
  const int* frow = flags + (i0 >> 6) * 64;
  if (threadIdx.x < 64) {
    int f = frow[threadIdx.x] != 0;
    unsigned long long m = __ballot(f);
    int pos = __popcll(m & ((1ULL << threadIdx.x) - 1ULL));
    if (f) list[pos] = threadIdx.x;
    if (threadIdx.x == 0) nact_s = __popcll(m);
  }
  __syncthreads();
  int nact = nact_s;

  int srow0 = l >> 3;                      // row within 8-row group
  int scol = ((l & 7) * 8) ^ ((srow0 & 7) << 3);
  const u16* gW0 = W + (size_t)(i0 + srow0) * NN + scol;       // + m*8*NN + j0
  const u16* gT0 = hT + (size_t)(d0 + srow0) * NN + scol;
  f32x4 acc0 = {0.f, 0.f, 0.f, 0.f};
  f32x4 acc1 = {0.f, 0.f, 0.f, 0.f};

  if (nact > 0) {
    {
      int j0 = list[0] * 64;
      if (w == 0) {
        gload_lds16(gW0 + j0, &sW[0][0][0]);
        gload_lds16(gW0 + 8 * NN + j0, &sW[0][8][0]);
      }
      gload_lds16(gT0 + j0, &sT[0][w][0][0]);
      gload_lds16(gT0 + 8 * NN + j0, &sT[0][w][8][0]);
    }
    __syncthreads();
    int cur = 0;
    for (int t = 0; t < nact; ++t) {
      if (t + 1 < nact) {
        int jn = list[t + 1] * 64;
        int nb = cur ^ 1;
        if (w == 0) {
          gload_lds16(gW0 + jn, &sW[nb][0][0]);
          gload_lds16(gW0 + 8 * NN + jn, &sW[nb][8][0]);
        }
        gload_lds16(gT0 + jn, &sT[nb][w][0][0]);
        gload_lds16(gT0 + 8 * NN + jn, &sT[nb][w][8][0]);
      }
      int sx = (lr & 7) << 3;                    // read-side XOR for row lr
      short8 a0 = *(const short8*)&sW[cur][lr][(lk * 8) ^ sx];
      short8 a1 = *(const short8*)&sW[cur][lr][(32 + lk * 8) ^ sx];
      short8 b0 = *(const short8*)&sT[cur][w][lr][(lk * 8) ^ sx];
      short8 b1 = *(const short8*)&sT[cur][w][lr][(32 + lk * 8) ^ sx];
      acc0 = __builtin_amdgcn_mfma_f32_16x16x32_bf16(a0, b0, acc0, 0, 0, 0);
      acc1 = __builtin_amdgcn_mfma_f32_16x16x32_bf16(a1, b1, acc1, 0, 0, 0);
      __syncthreads();   // drains vmcnt (next tile staged) + all reads of cur done
      cur ^= 1;
    }
  }

  int d = d0 + lr;
  #pragma unroll
  for (int q = 0; q < 4; ++q) {
    int i = i0 + 4 * lk + q;
    size_t idx = (size_t)i * DH + d;
    o[idx] = o[idx] + h[idx] + 0.5f * cs[d] + 0.5f * (acc0[q] + acc1[q]);
  }
}

// ---------------- final row-normalize (in place on d_out) ----------------
__global__ __launch_bounds__(256) void norm_kernel(float* __restrict__ out) {
  int wid = threadIdx.x >> 6, lane = threadIdx.x & 63;
  int i = blockIdx.x * 4 + wid;
  float x = out[(size_t)i * 64 + lane];
  float s = x * x;
  #pragma unroll
  for (int m = 32; m > 0; m >>= 1) s += __shfl_xor(s, m);
  float n = sqrtf(s);
  out[(size_t)i * 64 + lane] = x / fmaxf(n, 1e-12f);
}

// ---------------- host-side orchestration ----------------
struct Scratch {
  float *al, *ar, *inv, *denom, *cs, *eS;
  int *counts, *offsets, *cursor, *dstS, *flags;
  u16 *hhi, *hlo, *hT, *W;
  u16 *ghi, *glo, *wthi, *wtlo;
};

template<int DH>
static void run_attention(const float* h, const float* aw, const float* ab, float* o,
                          const int* src, const int* dst, const Scratch& S, hipStream_t stream) {
  rowstats_kernel<DH><<<NN / 4, 256, 0, stream>>>(h, aw, S.al, S.ar, S.inv);
  hipMemsetAsync(S.cs, 0, DH * sizeof(float), stream);
  colsum_kernel<DH><<<32, DH, 0, stream>>>(h, S.cs);
  convert_kernel<<<NN * DH / 256, 256, 0, stream>>>(h, S.hhi, S.hlo);
  transpose_kernel<DH><<<dim3(DH / 32, NN / 32), 256, 0, stream>>>(h, S.hT);
  hipMemsetAsync(S.flags, 0, 4096 * sizeof(int), stream);
  hipMemsetAsync(S.counts, 0, NN * sizeof(int), stream);
  hist_kernel<<<NE / 256, 256, 0, stream>>>(src, S.counts);
  scan_kernel<<<1, 1024, 0, stream>>>(S.counts, S.offsets, S.cursor);
  hipMemsetAsync(S.denom, 0, NN * sizeof(float), stream);
  scatter_kernel<<<NE / 256, 256, 0, stream>>>(src, dst, S.al, S.ar, ab,
                                               S.denom, S.cursor, S.dstS, S.eS);
  gather_kernel<DH><<<NN / 4, 256, 0, stream>>>(h, S.offsets, S.dstS, S.eS, S.denom, o);
  qk_kernel<DH><<<dim3(NN / 64, NN / 64), 256, 0, stream>>>(
      S.hhi, S.hlo, S.al, S.ar, S.inv, ab, S.W, S.flags);
  pv_kernel<DH><<<dim3(NN / 16, DH / 64), 256, 0, stream>>>(
      S.W, S.hT, S.flags, h, S.cs, o);
}

extern "C" void kernel_launch(void* const* d_in, const int* in_sizes, int n_in,
                              void* d_out, int out_size, void* d_ws, size_t ws_size,
                              hipStream_t stream) {
  const float* X   = (const float*)d_in[0];
  const int*   ei  = (const int*)d_in[1];
  const float* W1  = (const float*)d_in[2];
  const float* b1  = (const float*)d_in[3];
  const float* a1w = (const float*)d_in[4];
  const float* a1b = (const float*)d_in[5];
  const float* W2  = (const float*)d_in[6];
  const float* b2  = (const float*)d_in[7];
  const float* a2w = (const float*)d_in[8];
  const float* a2b = (const float*)d_in[9];
  const float* W3  = (const float*)d_in[10];
  const float* b3  = (const float*)d_in[11];
  float* out = (float*)d_out;

  const int* src = ei;
  const int* dst = ei + NE;

  char* p = (char*)d_ws;
  auto alloc = [&](size_t bytes) { char* r = p; p += (bytes + 255) & ~(size_t)255; return r; };
  float* h1 = (float*)alloc((size_t)NN * 256 * 4);
  float* o1 = (float*)alloc((size_t)NN * 256 * 4);
  float* h2 = (float*)alloc((size_t)NN * 128 * 4);
  float* o2 = (float*)alloc((size_t)NN * 128 * 4);
  Scratch S;
  S.hhi = (u16*)alloc((size_t)NN * 256 * 2);
  S.hlo = (u16*)alloc((size_t)NN * 256 * 2);
  S.hT  = (u16*)alloc((size_t)NN * 256 * 2);
  S.W   = (u16*)alloc((size_t)NN * NN * 2);
  S.ghi = (u16*)alloc((size_t)NN * 256 * 2);
  S.glo = (u16*)alloc((size_t)NN * 256 * 2);
  S.wthi = (u16*)alloc((size_t)256 * 256 * 2);
  S.wtlo = (u16*)alloc((size_t)256 * 256 * 2);
  S.flags = (int*)alloc(4096 * 4);
  S.al    = (float*)alloc(NN * 4);
  S.ar    = (float*)alloc(NN * 4);
  S.inv   = (float*)alloc(NN * 4);
  S.denom = (float*)alloc(NN * 4);
  S.cs    = (float*)alloc(256 * 4);
  S.eS    = (float*)alloc((size_t)NE * 4);
  S.counts  = (int*)alloc(NN * 4);
  S.offsets = (int*)alloc((NN + 1) * 4);
  S.cursor  = (int*)alloc(NN * 4);
  S.dstS    = (int*)alloc((size_t)NE * 4);

  // ---- layer 1: h1 = X @ W1 + b1 (MFMA, split bf16) ----
  wtrans_kernel<<<dim3(256 / 32, 128 / 32), 256, 0, stream>>>(W1, S.wthi, S.wtlo, 128, 256);
  convert_io_kernel<false><<<NN * 128 / 256, 256, 0, stream>>>(X, S.ghi, S.glo);
  mgemm_kernel<128, 256><<<dim3(NN / 16, 256 / 64), 256, 0, stream>>>(
      S.ghi, S.glo, S.wthi, S.wtlo, b1, h1);
  run_attention<256>(h1, a1w, a1b, o1, src, dst, S, stream);

  // ---- layer 2: h2 = relu(o1) @ W2 + b2 ----
  wtrans_kernel<<<dim3(128 / 32, 256 / 32), 256, 0, stream>>>(W2, S.wthi, S.wtlo, 256, 128);
  convert_io_kernel<true><<<NN * 256 / 256, 256, 0, stream>>>(o1, S.ghi, S.glo);
  mgemm_kernel<256, 128><<<dim3(NN / 16, 128 / 64), 256, 0, stream>>>(
      S.ghi, S.glo, S.wthi, S.wtlo, b2, h2);
  run_attention<128>(h2, a2w, a2b, o2, src, dst, S, stream);

  // ---- output layer: out = relu(o2) @ W3 + b3, then normalize ----
  wtrans_kernel<<<dim3(64 / 32, 128 / 32), 256, 0, stream>>>(W3, S.wthi, S.wtlo, 128, 64);
  convert_io_kernel<true><<<NN * 128 / 256, 256, 0, stream>>>(o2, S.ghi, S.glo);
  mgemm_kernel<128, 64><<<dim3(NN / 16, 64 / 64), 256, 0, stream>>>(
      S.ghi, S.glo, S.wthi, S.wtlo, b3, out);
  norm_kernel<<<NN / 4, 256, 0, stream>>>(out);
}

// Round 10
// 335.120 us; speedup vs baseline: 7.0174x; 1.0322x over previous
//
#include <hip/hip_runtime.h>
#include <math.h>

#define NN 4096
#define NE 131072

typedef short short8 __attribute__((ext_vector_type(8)));
typedef float f32x4 __attribute__((ext_vector_type(4)));
typedef unsigned short u16;

__device__ __forceinline__ float lrelu_f(float x) { return x > 0.0f ? x : 0.01f * x; }

__device__ __forceinline__ u16 f2bf(float x) {
  unsigned int u = __float_as_uint(x);
  unsigned int r = (u + 0x7FFF + ((u >> 16) & 1)) >> 16;   // RNE
  return (u16)r;
}
__device__ __forceinline__ float bf2f(u16 b) { return __uint_as_float(((unsigned int)b) << 16); }

__device__ __forceinline__ void gload_lds16(const u16* g, u16* l) {
  __builtin_amdgcn_global_load_lds((const __attribute__((address_space(1))) void*)g,
                                   (__attribute__((address_space(3))) void*)l, 16, 0, 0);
}

// ---------------- weight transpose+split: W[K][P] fp32 -> WT[P][K] bf16 hi/lo ----------------
__global__ __launch_bounds__(256) void wtrans_kernel(const float* __restrict__ W,
    u16* __restrict__ WThi, u16* __restrict__ WTlo, int K, int P) {
  __shared__ u16 th[32][33], tl[32][33];
  int bp = blockIdx.x, bk = blockIdx.y;
  int t = threadIdx.x, tx = t & 31, ty8 = t >> 5;
  #pragma unroll
  for (int r = 0; r < 4; ++r) {
    int k = bk * 32 + ty8 + r * 8;
    int p = bp * 32 + tx;
    float x = W[(size_t)k * P + p];
    u16 hi = f2bf(x);
    th[ty8 + r * 8][tx] = hi;
    tl[ty8 + r * 8][tx] = f2bf(x - bf2f(hi));
  }
  __syncthreads();
  #pragma unroll
  for (int r = 0; r < 4; ++r) {
    int p = bp * 32 + ty8 + r * 8;
    int k = bk * 32 + tx;
    WThi[(size_t)p * K + k] = th[tx][ty8 + r * 8];
    WTlo[(size_t)p * K + k] = tl[tx][ty8 + r * 8];
  }
}

// ---------------- gemm input convert: ghi/glo = bf16 split of (relu?) x ----------------
template<bool RELU>
__global__ __launch_bounds__(256) void convert_io_kernel(const float* __restrict__ x,
    u16* __restrict__ ghi, u16* __restrict__ glo) {
  int idx = blockIdx.x * 256 + threadIdx.x;
  float v = x[idx];
  if (RELU) v = fmaxf(v, 0.0f);
  u16 hi = f2bf(v);
  ghi[idx] = hi;
  glo[idx] = f2bf(v - bf2f(hi));
}

// ---------------- MFMA GEMM: O[NN][P] = Asplit @ WTsplit^T + bias ----------------
template<int K, int P>
__global__ __launch_bounds__(256) void mgemm_kernel(
    const u16* __restrict__ Ahi, const u16* __restrict__ Alo,
    const u16* __restrict__ WThi, const u16* __restrict__ WTlo,
    const float* __restrict__ bias, float* __restrict__ O) {
  constexpr int KC = K / 32;
  int w = threadIdx.x >> 6, l = threadIdx.x & 63;
  int lr = l & 15, lk = l >> 4;
  int i0 = blockIdx.x * 16;
  int p0 = blockIdx.y * 64 + w * 16;
  const u16* arh = Ahi + (size_t)(i0 + lr) * K + lk * 8;
  const u16* arl = Alo + (size_t)(i0 + lr) * K + lk * 8;
  const u16* brh = WThi + (size_t)(p0 + lr) * K + lk * 8;
  const u16* brl = WTlo + (size_t)(p0 + lr) * K + lk * 8;
  f32x4 ahh = {0.f, 0.f, 0.f, 0.f};
  f32x4 ahl = {0.f, 0.f, 0.f, 0.f};
  f32x4 alh = {0.f, 0.f, 0.f, 0.f};
  #pragma unroll
  for (int c = 0; c < KC; ++c) {
    short8 Ah = *(const short8*)(arh + 32 * c);
    short8 Al = *(const short8*)(arl + 32 * c);
    short8 Bh = *(const short8*)(brh + 32 * c);
    short8 Bl = *(const short8*)(brl + 32 * c);
    ahh = __builtin_amdgcn_mfma_f32_16x16x32_bf16(Ah, Bh, ahh, 0, 0, 0);
    ahl = __builtin_amdgcn_mfma_f32_16x16x32_bf16(Ah, Bl, ahl, 0, 0, 0);
    alh = __builtin_amdgcn_mfma_f32_16x16x32_bf16(Al, Bh, alh, 0, 0, 0);
  }
  int p = p0 + lr;
  float bv = bias[p];
  #pragma unroll
  for (int q = 0; q < 4; ++q) {
    int i = i0 + 4 * lk + q;
    O[(size_t)i * P + p] = ahh[q] + ahl[q] + alh[q] + bv;
  }
}

// ---------------- row stats: inv_norm, al, ar ----------------
template<int DH>
__global__ __launch_bounds__(256) void rowstats_kernel(const float* __restrict__ h,
    const float* __restrict__ aw, float* __restrict__ al, float* __restrict__ ar,
    float* __restrict__ inv) {
  constexpr int NC = DH / 64;
  int wid = threadIdx.x >> 6, lane = threadIdx.x & 63;
  int i = blockIdx.x * 4 + wid;
  float s2 = 0.f, sl = 0.f, sr = 0.f;
  #pragma unroll
  for (int c = 0; c < NC; ++c) {
    float x = h[(size_t)i * DH + c * 64 + lane];
    s2 = fmaf(x, x, s2);
    sl = fmaf(x, aw[c * 64 + lane], sl);
    sr = fmaf(x, aw[DH + c * 64 + lane], sr);
  }
  #pragma unroll
  for (int m = 32; m > 0; m >>= 1) {
    s2 += __shfl_xor(s2, m);
    sl += __shfl_xor(sl, m);
    sr += __shfl_xor(sr, m);
  }
  if (lane == 0) { al[i] = sl; ar[i] = sr; inv[i] = rsqrtf(s2); }
}

// ---------------- column sum ----------------
template<int DH>
__global__ void colsum_kernel(const float* __restrict__ h, float* __restrict__ cs) {
  int d = threadIdx.x;             // blockDim == DH
  int r0 = blockIdx.x * (NN / 32);
  float s = 0.f;
  for (int i = 0; i < NN / 32; ++i) s += h[(size_t)(r0 + i) * DH + d];
  atomicAdd(&cs[d], s);
}

// ---------------- convert h -> bf16 hi/lo (row-major) ----------------
__global__ __launch_bounds__(256) void convert_kernel(const float* __restrict__ h,
    u16* __restrict__ hhi, u16* __restrict__ hlo) {
  int idx = blockIdx.x * 256 + threadIdx.x;
  float x = h[idx];
  u16 hi = f2bf(x);
  float lo = x - bf2f(hi);
  hhi[idx] = hi;
  hlo[idx] = f2bf(lo);
}

// ---------------- transpose h(fp32 [NN][DH]) -> hT(bf16 [DH][NN]) ----------------
template<int DH>
__global__ __launch_bounds__(256) void transpose_kernel(const float* __restrict__ h,
    u16* __restrict__ hT) {
  __shared__ u16 tile[32][33];
  int bx = blockIdx.x;   // d / 32
  int by = blockIdx.y;   // i / 32
  int t = threadIdx.x, tx = t & 31, ty8 = t >> 5;   // 32 x 8
  #pragma unroll
  for (int r = 0; r < 4; ++r) {
    int i = by * 32 + ty8 + r * 8;
    int d = bx * 32 + tx;
    tile[ty8 + r * 8][tx] = f2bf(h[(size_t)i * DH + d]);
  }
  __syncthreads();
  #pragma unroll
  for (int r = 0; r < 4; ++r) {
    int d = bx * 32 + ty8 + r * 8;
    int i = by * 32 + tx;
    hT[(size_t)d * NN + i] = tile[tx][ty8 + r * 8];
  }
}

// ---------------- CSR build ----------------
__global__ void hist_kernel(const int* __restrict__ src, int* __restrict__ counts) {
  int e = blockIdx.x * 256 + threadIdx.x;
  atomicAdd(&counts[src[e]], 1);
}

__global__ __launch_bounds__(1024) void scan_kernel(const int* __restrict__ counts,
    int* __restrict__ offsets, int* __restrict__ cursor) {
  __shared__ int part[1024];
  int t = threadIdx.x;
  int v[4]; int run = 0;
  #pragma unroll
  for (int j = 0; j < 4; ++j) { v[j] = counts[4 * t + j]; run += v[j]; }
  part[t] = run;
  __syncthreads();
  for (int off = 1; off < 1024; off <<= 1) {
    int y = (t >= off) ? part[t - off] : 0;
    __syncthreads();
    part[t] += y;
    __syncthreads();
  }
  int base = part[t] - run;
  #pragma unroll
  for (int j = 0; j < 4; ++j) { offsets[4 * t + j] = base; cursor[4 * t + j] = base; base += v[j]; }
  if (t == 1023) offsets[NN] = base;
}

__global__ void scatter_kernel(const int* __restrict__ src, const int* __restrict__ dst,
    const float* __restrict__ al, const float* __restrict__ ar, const float* __restrict__ ab,
    float* __restrict__ denom, int* __restrict__ cursor,
    int* __restrict__ dstS, float* __restrict__ eS) {
  int e = blockIdx.x * 256 + threadIdx.x;
  int s = src[e], d = dst[e];
  float v = expf(lrelu_f(al[s] + ar[d] + ab[0]));
  atomicAdd(&denom[s], v);
  int p = atomicAdd(&cursor[s], 1);
  dstS[p] = d; eS[p] = v;
}

// ---------------- edge-branch gather: o = 0.5 * nbr ----------------
template<int DH>
__global__ __launch_bounds__(256) void gather_kernel(const float* __restrict__ h,
    const int* __restrict__ offsets, const int* __restrict__ dstS,
    const float* __restrict__ eS, const float* __restrict__ denom,
    float* __restrict__ o) {
  constexpr int NC = DH / 64;
  int wid = threadIdx.x >> 6, lane = threadIdx.x & 63;
  int i = blockIdx.x * 4 + wid;
  int beg = offsets[i], end = offsets[i + 1];
  float rd = (beg < end) ? 1.0f / denom[i] : 0.0f;
  float acc[NC] = {};
  for (int k = beg; k < end; ++k) {
    int d = dstS[k];
    float a = eS[k] * rd;
    #pragma unroll
    for (int c = 0; c < NC; ++c)
      acc[c] = fmaf(a, h[(size_t)d * DH + c * 64 + lane], acc[c]);
  }
  #pragma unroll
  for (int c = 0; c < NC; ++c)
    o[(size_t)i * DH + c * 64 + lane] = 0.5f * acc[c];
}

// ---------------- Pass 1: QK^T (split bf16 MFMA) -> Delta weights W (bf16) + tile flags ----
// Grid (NN/128, NN/128). Block 256 = 4 waves in 2x2; wave (wr,wc) owns the 64x64
// quadrant (i0+64wr, j0+64wc) = 16 16x16 subtiles, 3 split terms chained into one
// acc per subtile. A/B staged hi+lo via global_load_lds, BK=32 double-buffered,
// 64KB LDS. Bank-conflict-free reads via pre-swizzled source chunk
// sc = (l&3)^((l>>3)&3) and read chunk lk^((lr>>1)&3) (same involution).
template<int DH>
__global__ __launch_bounds__(256) void qk_kernel(
    const u16* __restrict__ hhi, const u16* __restrict__ hlo,
    const float* __restrict__ al, const float* __restrict__ ar,
    const float* __restrict__ inv, const float* __restrict__ ab,
    u16* __restrict__ W, int* __restrict__ flags) {
  constexpr int KC = DH / 32;
  __shared__ u16 sA[2][2][128][32];   // [buf][hi/lo][row][col-swizzled]  32KB
  __shared__ u16 sB[2][2][128][32];   //                                   32KB
  int i0 = blockIdx.x * 128;
  int j0 = blockIdx.y * 128;
  int w = threadIdx.x >> 6, l = threadIdx.x & 63;
  int wr = w >> 1, wc = w & 1;
  int lr = l & 15, lk = l >> 4;

  // staging: wave w covers rows [32w, 32w+32) via 2 instrs (16 rows each);
  // lane l -> row +(l>>2), LDS chunk (l&3), source chunk sc (pre-swizzle)
  int rl = l >> 2;
  int sc = ((l & 3) ^ ((l >> 3) & 3)) * 8;
  const u16* gAh0 = hhi + (size_t)(i0 + 32 * w + rl) * DH + sc;
  const u16* gAl0 = hlo + (size_t)(i0 + 32 * w + rl) * DH + sc;
  const u16* gBh0 = hhi + (size_t)(j0 + 32 * w + rl) * DH + sc;
  const u16* gBl0 = hlo + (size_t)(j0 + 32 * w + rl) * DH + sc;

  f32x4 acc[4][4];
  #pragma unroll
  for (int q = 0; q < 4; ++q)
    #pragma unroll
    for (int s = 0; s < 4; ++s) acc[q][s] = (f32x4){0.f, 0.f, 0.f, 0.f};

#define QK_STAGE(buf, c) do { \
    gload_lds16(gAh0 + (c) * 32,           &sA[buf][0][32 * w][0]); \
    gload_lds16(gAh0 + 16 * DH + (c) * 32, &sA[buf][0][32 * w + 16][0]); \
    gload_lds16(gAl0 + (c) * 32,           &sA[buf][1][32 * w][0]); \
    gload_lds16(gAl0 + 16 * DH + (c) * 32, &sA[buf][1][32 * w + 16][0]); \
    gload_lds16(gBh0 + (c) * 32,           &sB[buf][0][32 * w][0]); \
    gload_lds16(gBh0 + 16 * DH + (c) * 32, &sB[buf][0][32 * w + 16][0]); \
    gload_lds16(gBl0 + (c) * 32,           &sB[buf][1][32 * w][0]); \
    gload_lds16(gBl0 + 16 * DH + (c) * 32, &sB[buf][1][32 * w + 16][0]); \
  } while (0)

  QK_STAGE(0, 0);
  __syncthreads();

  int cs = (lk ^ ((lr >> 1) & 3)) * 8;   // read-side swizzled chunk
  int cur = 0;
  for (int c = 0; c < KC; ++c) {
    if (c + 1 < KC) QK_STAGE(cur ^ 1, c + 1);
    short8 Ah[4], Al[4], Bh[4], Bl[4];
    #pragma unroll
    for (int q = 0; q < 4; ++q) {
      Ah[q] = *(const short8*)&sA[cur][0][64 * wr + 16 * q + lr][cs];
      Al[q] = *(const short8*)&sA[cur][1][64 * wr + 16 * q + lr][cs];
    }
    #pragma unroll
    for (int s = 0; s < 4; ++s) {
      Bh[s] = *(const short8*)&sB[cur][0][64 * wc + 16 * s + lr][cs];
      Bl[s] = *(const short8*)&sB[cur][1][64 * wc + 16 * s + lr][cs];
    }
    #pragma unroll
    for (int q = 0; q < 4; ++q)
      #pragma unroll
      for (int s = 0; s < 4; ++s) {
        acc[q][s] = __builtin_amdgcn_mfma_f32_16x16x32_bf16(Al[q], Bh[s], acc[q][s], 0, 0, 0);
        acc[q][s] = __builtin_amdgcn_mfma_f32_16x16x32_bf16(Ah[q], Bl[s], acc[q][s], 0, 0, 0);
        acc[q][s] = __builtin_amdgcn_mfma_f32_16x16x32_bf16(Ah[q], Bh[s], acc[q][s], 0, 0, 0);
      }
    __syncthreads();   // drains vmcnt (next chunk staged) + all reads of cur done
    cur ^= 1;
  }
#undef QK_STAGE

  float abv = ab[0];
  int i_base = i0 + 64 * wr + 4 * lk;   // + 16q + qq
  int j_base = j0 + 64 * wc + lr;       // + 16s
  float arj[4], invj[4];
  #pragma unroll
  for (int s = 0; s < 4; ++s) {
    int j = j_base + 16 * s;
    arj[s] = ar[j] + abv;
    invj[s] = inv[j];
  }
  int wany = 0;
  #pragma unroll
  for (int q = 0; q < 4; ++q) {
    float ali_[4], invi_[4];
    #pragma unroll
    for (int qq = 0; qq < 4; ++qq) {
      int i = i_base + 16 * q + qq;
      ali_[qq] = al[i];
      invi_[qq] = inv[i];
    }
    #pragma unroll
    for (int s = 0; s < 4; ++s)
      #pragma unroll
      for (int qq = 0; qq < 4; ++qq) {
        float C = acc[q][s][qq] * invi_[qq] * invj[s];
        float wv = 0.0f;
        if (C > 0.36f) wv = expm1f(C * lrelu_f(ali_[qq] + arj[s]));
        if (wv != 0.0f) wany = 1;
        W[(size_t)(i_base + 16 * q + qq) * NN + j_base + 16 * s] = f2bf(wv);
      }
  }
  if (__any(wany) && l == 0)
    atomicOr(&flags[((i0 >> 6) + wr) * 64 + (j0 >> 6) + wc], 1);
}

// ---------------- Pass 2: o += h + 0.5*cs + 0.5*(W @ h), flag-gated ----------------
template<int DH>
__global__ __launch_bounds__(256) void pv_kernel(
    const u16* __restrict__ W, const u16* __restrict__ hT,
    const int* __restrict__ flags, const float* __restrict__ h,
    const float* __restrict__ cs, float* __restrict__ o) {
  __shared__ u16 sW[2][16][64];      // W tile: rows i0..i0+15, 64 j (swizzled cols)
  __shared__ u16 sT[2][4][16][64];   // per-wave hT tile: rows d0..d0+15, 64 j
  __shared__ int list[64];
  __shared__ int nact_s;
  int ib = blockIdx.x;
  int w = threadIdx.x >> 6, l = threadIdx.x & 63;
  int lr = l & 15, lk = l >> 4;
  int i0 = ib * 16;
  int d0 = blockIdx.y * 64 + w * 16;
  const int* frow = flags + (i0 >> 6) * 64;
  if (threadIdx.x < 64) {
    int f = frow[threadIdx.x] != 0;
    unsigned long long m = __ballot(f);
    int pos = __popcll(m & ((1ULL << threadIdx.x) - 1ULL));
    if (f) list[pos] = threadIdx.x;
    if (threadIdx.x == 0) nact_s = __popcll(m);
  }
  __syncthreads();
  int nact = nact_s;

  int srow0 = l >> 3;                      // row within 8-row group
  int scol = ((l & 7) * 8) ^ ((srow0 & 7) << 3);
  const u16* gW0 = W + (size_t)(i0 + srow0) * NN + scol;       // + m*8*NN + j0
  const u16* gT0 = hT + (size_t)(d0 + srow0) * NN + scol;
  f32x4 acc0 = {0.f, 0.f, 0.f, 0.f};
  f32x4 acc1 = {0.f, 0.f, 0.f, 0.f};

  if (nact > 0) {
    {
      int j0 = list[0] * 64;
      if (w == 0) {
        gload_lds16(gW0 + j0, &sW[0][0][0]);
        gload_lds16(gW0 + 8 * NN + j0, &sW[0][8][0]);
      }
      gload_lds16(gT0 + j0, &sT[0][w][0][0]);
      gload_lds16(gT0 + 8 * NN + j0, &sT[0][w][8][0]);
    }
    __syncthreads();
    int cur = 0;
    for (int t = 0; t < nact; ++t) {
      if (t + 1 < nact) {
        int jn = list[t + 1] * 64;
        int nb = cur ^ 1;
        if (w == 0) {
          gload_lds16(gW0 + jn, &sW[nb][0][0]);
          gload_lds16(gW0 + 8 * NN + jn, &sW[nb][8][0]);
        }
        gload_lds16(gT0 + jn, &sT[nb][w][0][0]);
        gload_lds16(gT0 + 8 * NN + jn, &sT[nb][w][8][0]);
      }
      int sx = (lr & 7) << 3;                    // read-side XOR for row lr
      short8 a0 = *(const short8*)&sW[cur][lr][(lk * 8) ^ sx];
      short8 a1 = *(const short8*)&sW[cur][lr][(32 + lk * 8) ^ sx];
      short8 b0 = *(const short8*)&sT[cur][w][lr][(lk * 8) ^ sx];
      short8 b1 = *(const short8*)&sT[cur][w][lr][(32 + lk * 8) ^ sx];
      acc0 = __builtin_amdgcn_mfma_f32_16x16x32_bf16(a0, b0, acc0, 0, 0, 0);
      acc1 = __builtin_amdgcn_mfma_f32_16x16x32_bf16(a1, b1, acc1, 0, 0, 0);
      __syncthreads();   // drains vmcnt (next tile staged) + all reads of cur done
      cur ^= 1;
    }
  }

  int d = d0 + lr;
  #pragma unroll
  for (int q = 0; q < 4; ++q) {
    int i = i0 + 4 * lk + q;
    size_t idx = (size_t)i * DH + d;
    o[idx] = o[idx] + h[idx] + 0.5f * cs[d] + 0.5f * (acc0[q] + acc1[q]);
  }
}

// ---------------- final row-normalize (in place on d_out) ----------------
__global__ __launch_bounds__(256) void norm_kernel(float* __restrict__ out) {
  int wid = threadIdx.x >> 6, lane = threadIdx.x & 63;
  int i = blockIdx.x * 4 + wid;
  float x = out[(size_t)i * 64 + lane];
  float s = x * x;
  #pragma unroll
  for (int m = 32; m > 0; m >>= 1) s += __shfl_xor(s, m);
  float n = sqrtf(s);
  out[(size_t)i * 64 + lane] = x / fmaxf(n, 1e-12f);
}

// ---------------- host-side orchestration ----------------
struct Scratch {
  float *al, *ar, *inv, *denom, *cs, *eS;
  int *counts, *offsets, *cursor, *dstS, *flags;
  u16 *hhi, *hlo, *hT, *W;
  u16 *ghi, *glo, *wthi, *wtlo;
};

template<int DH>
static void run_attention(const float* h, const float* aw, const float* ab, float* o,
                          const int* src, const int* dst, const Scratch& S, hipStream_t stream) {
  rowstats_kernel<DH><<<NN / 4, 256, 0, stream>>>(h, aw, S.al, S.ar, S.inv);
  hipMemsetAsync(S.cs, 0, DH * sizeof(float), stream);
  colsum_kernel<DH><<<32, DH, 0, stream>>>(h, S.cs);
  convert_kernel<<<NN * DH / 256, 256, 0, stream>>>(h, S.hhi, S.hlo);
  transpose_kernel<DH><<<dim3(DH / 32, NN / 32), 256, 0, stream>>>(h, S.hT);
  hipMemsetAsync(S.flags, 0, 4096 * sizeof(int), stream);
  hipMemsetAsync(S.counts, 0, NN * sizeof(int), stream);
  hist_kernel<<<NE / 256, 256, 0, stream>>>(src, S.counts);
  scan_kernel<<<1, 1024, 0, stream>>>(S.counts, S.offsets, S.cursor);
  hipMemsetAsync(S.denom, 0, NN * sizeof(float), stream);
  scatter_kernel<<<NE / 256, 256, 0, stream>>>(src, dst, S.al, S.ar, ab,
                                               S.denom, S.cursor, S.dstS, S.eS);
  gather_kernel<DH><<<NN / 4, 256, 0, stream>>>(h, S.offsets, S.dstS, S.eS, S.denom, o);
  qk_kernel<DH><<<dim3(NN / 128, NN / 128), 256, 0, stream>>>(
      S.hhi, S.hlo, S.al, S.ar, S.inv, ab, S.W, S.flags);
  pv_kernel<DH><<<dim3(NN / 16, DH / 64), 256, 0, stream>>>(
      S.W, S.hT, S.flags, h, S.cs, o);
}

extern "C" void kernel_launch(void* const* d_in, const int* in_sizes, int n_in,
                              void* d_out, int out_size, void* d_ws, size_t ws_size,
                              hipStream_t stream) {
  const float* X   = (const float*)d_in[0];
  const int*   ei  = (const int*)d_in[1];
  const float* W1  = (const float*)d_in[2];
  const float* b1  = (const float*)d_in[3];
  const float* a1w = (const float*)d_in[4];
  const float* a1b = (const float*)d_in[5];
  const float* W2  = (const float*)d_in[6];
  const float* b2  = (const float*)d_in[7];
  const float* a2w = (const float*)d_in[8];
  const float* a2b = (const float*)d_in[9];
  const float* W3  = (const float*)d_in[10];
  const float* b3  = (const float*)d_in[11];
  float* out = (float*)d_out;

  const int* src = ei;
  const int* dst = ei + NE;

  char* p = (char*)d_ws;
  auto alloc = [&](size_t bytes) { char* r = p; p += (bytes + 255) & ~(size_t)255; return r; };
  float* h1 = (float*)alloc((size_t)NN * 256 * 4);
  float* o1 = (float*)alloc((size_t)NN * 256 * 4);
  float* h2 = (float*)alloc((size_t)NN * 128 * 4);
  float* o2 = (float*)alloc((size_t)NN * 128 * 4);
  Scratch S;
  S.hhi = (u16*)alloc((size_t)NN * 256 * 2);
  S.hlo = (u16*)alloc((size_t)NN * 256 * 2);
  S.hT  = (u16*)alloc((size_t)NN * 256 * 2);
  S.W   = (u16*)alloc((size_t)NN * NN * 2);
  S.ghi = (u16*)alloc((size_t)NN * 256 * 2);
  S.glo = (u16*)alloc((size_t)NN * 256 * 2);
  S.wthi = (u16*)alloc((size_t)256 * 256 * 2);
  S.wtlo = (u16*)alloc((size_t)256 * 256 * 2);
  S.flags = (int*)alloc(4096 * 4);
  S.al    = (float*)alloc(NN * 4);
  S.ar    = (float*)alloc(NN * 4);
  S.inv   = (float*)alloc(NN * 4);
  S.denom = (float*)alloc(NN * 4);
  S.cs    = (float*)alloc(256 * 4);
  S.eS    = (float*)alloc((size_t)NE * 4);
  S.counts  = (int*)alloc(NN * 4);
  S.offsets = (int*)alloc((NN + 1) * 4);
  S.cursor  = (int*)alloc(NN * 4);
  S.dstS    = (int*)alloc((size_t)NE * 4);

  // ---- layer 1: h1 = X @ W1 + b1 (MFMA, split bf16) ----
  wtrans_kernel<<<dim3(256 / 32, 128 / 32), 256, 0, stream>>>(W1, S.wthi, S.wtlo, 128, 256);
  convert_io_kernel<false><<<NN * 128 / 256, 256, 0, stream>>>(X, S.ghi, S.glo);
  mgemm_kernel<128, 256><<<dim3(NN / 16, 256 / 64), 256, 0, stream>>>(
      S.ghi, S.glo, S.wthi, S.wtlo, b1, h1);
  run_attention<256>(h1, a1w, a1b, o1, src, dst, S, stream);

  // ---- layer 2: h2 = relu(o1) @ W2 + b2 ----
  wtrans_kernel<<<dim3(128 / 32, 256 / 32), 256, 0, stream>>>(W2, S.wthi, S.wtlo, 256, 128);
  convert_io_kernel<true><<<NN * 256 / 256, 256, 0, stream>>>(o1, S.ghi, S.glo);
  mgemm_kernel<256, 128><<<dim3(NN / 16, 128 / 64), 256, 0, stream>>>(
      S.ghi, S.glo, S.wthi, S.wtlo, b2, h2);
  run_attention<128>(h2, a2w, a2b, o2, src, dst, S, stream);

  // ---- output layer: out = relu(o2) @ W3 + b3, then normalize ----
  wtrans_kernel<<<dim3(64 / 32, 128 / 32), 256, 0, stream>>>(W3, S.wthi, S.wtlo, 128, 64);
  convert_io_kernel<true><<<NN * 128 / 256, 256, 0, stream>>>(o2, S.ghi, S.glo);
  mgemm_kernel<128, 64><<<dim3(NN / 16, 64 / 64), 256, 0, stream>>>(
      S.ghi, S.glo, S.wthi, S.wtlo, b3, out);
  norm_kernel<<<NN / 4, 256, 0, stream>>>(out);
}

// Round 11
// 277.512 us; speedup vs baseline: 8.4741x; 1.2076x over previous
//
#include <hip/hip_runtime.h>
#include <math.h>

#define NN 4096
#define NE 131072

typedef short short8 __attribute__((ext_vector_type(8)));
typedef float f32x4 __attribute__((ext_vector_type(4)));
typedef unsigned short u16;

__device__ __forceinline__ float lrelu_f(float x) { return x > 0.0f ? x : 0.01f * x; }

__device__ __forceinline__ u16 f2bf(float x) {
  unsigned int u = __float_as_uint(x);
  unsigned int r = (u + 0x7FFF + ((u >> 16) & 1)) >> 16;   // RNE
  return (u16)r;
}
__device__ __forceinline__ float bf2f(u16 b) { return __uint_as_float(((unsigned int)b) << 16); }

__device__ __forceinline__ void gload_lds16(const u16* g, u16* l) {
  __builtin_amdgcn_global_load_lds((const __attribute__((address_space(1))) void*)g,
                                   (__attribute__((address_space(3))) void*)l, 16, 0, 0);
}

// ---------------- weight transpose+split: W[K][P] fp32 -> WT[P][K] bf16 hi/lo ----------------
__global__ __launch_bounds__(256) void wtrans_kernel(const float* __restrict__ W,
    u16* __restrict__ WThi, u16* __restrict__ WTlo, int K, int P) {
  __shared__ u16 th[32][33], tl[32][33];
  int bp = blockIdx.x, bk = blockIdx.y;
  int t = threadIdx.x, tx = t & 31, ty8 = t >> 5;
  #pragma unroll
  for (int r = 0; r < 4; ++r) {
    int k = bk * 32 + ty8 + r * 8;
    int p = bp * 32 + tx;
    float x = W[(size_t)k * P + p];
    u16 hi = f2bf(x);
    th[ty8 + r * 8][tx] = hi;
    tl[ty8 + r * 8][tx] = f2bf(x - bf2f(hi));
  }
  __syncthreads();
  #pragma unroll
  for (int r = 0; r < 4; ++r) {
    int p = bp * 32 + ty8 + r * 8;
    int k = bk * 32 + tx;
    WThi[(size_t)p * K + k] = th[tx][ty8 + r * 8];
    WTlo[(size_t)p * K + k] = tl[tx][ty8 + r * 8];
  }
}

// ---------------- gemm input convert: ghi/glo = bf16 split of (relu?) x ----------------
template<bool RELU>
__global__ __launch_bounds__(256) void convert_io_kernel(const float* __restrict__ x,
    u16* __restrict__ ghi, u16* __restrict__ glo) {
  int idx = blockIdx.x * 256 + threadIdx.x;
  float v = x[idx];
  if (RELU) v = fmaxf(v, 0.0f);
  u16 hi = f2bf(v);
  ghi[idx] = hi;
  glo[idx] = f2bf(v - bf2f(hi));
}

// ---------------- MFMA GEMM: O[NN][P] = Asplit @ WTsplit^T + bias ----------------
template<int K, int P>
__global__ __launch_bounds__(256) void mgemm_kernel(
    const u16* __restrict__ Ahi, const u16* __restrict__ Alo,
    const u16* __restrict__ WThi, const u16* __restrict__ WTlo,
    const float* __restrict__ bias, float* __restrict__ O) {
  constexpr int KC = K / 32;
  int w = threadIdx.x >> 6, l = threadIdx.x & 63;
  int lr = l & 15, lk = l >> 4;
  int i0 = blockIdx.x * 16;
  int p0 = blockIdx.y * 64 + w * 16;
  const u16* arh = Ahi + (size_t)(i0 + lr) * K + lk * 8;
  const u16* arl = Alo + (size_t)(i0 + lr) * K + lk * 8;
  const u16* brh = WThi + (size_t)(p0 + lr) * K + lk * 8;
  const u16* brl = WTlo + (size_t)(p0 + lr) * K + lk * 8;
  f32x4 ahh = {0.f, 0.f, 0.f, 0.f};
  f32x4 ahl = {0.f, 0.f, 0.f, 0.f};
  f32x4 alh = {0.f, 0.f, 0.f, 0.f};
  #pragma unroll
  for (int c = 0; c < KC; ++c) {
    short8 Ah = *(const short8*)(arh + 32 * c);
    short8 Al = *(const short8*)(arl + 32 * c);
    short8 Bh = *(const short8*)(brh + 32 * c);
    short8 Bl = *(const short8*)(brl + 32 * c);
    ahh = __builtin_amdgcn_mfma_f32_16x16x32_bf16(Ah, Bh, ahh, 0, 0, 0);
    ahl = __builtin_amdgcn_mfma_f32_16x16x32_bf16(Ah, Bl, ahl, 0, 0, 0);
    alh = __builtin_amdgcn_mfma_f32_16x16x32_bf16(Al, Bh, alh, 0, 0, 0);
  }
  int p = p0 + lr;
  float bv = bias[p];
  #pragma unroll
  for (int q = 0; q < 4; ++q) {
    int i = i0 + 4 * lk + q;
    O[(size_t)i * P + p] = ahh[q] + ahl[q] + alh[q] + bv;
  }
}

// ---------------- row stats: inv_norm, al, ar ----------------
template<int DH>
__global__ __launch_bounds__(256) void rowstats_kernel(const float* __restrict__ h,
    const float* __restrict__ aw, float* __restrict__ al, float* __restrict__ ar,
    float* __restrict__ inv) {
  constexpr int NC = DH / 64;
  int wid = threadIdx.x >> 6, lane = threadIdx.x & 63;
  int i = blockIdx.x * 4 + wid;
  float s2 = 0.f, sl = 0.f, sr = 0.f;
  #pragma unroll
  for (int c = 0; c < NC; ++c) {
    float x = h[(size_t)i * DH + c * 64 + lane];
    s2 = fmaf(x, x, s2);
    sl = fmaf(x, aw[c * 64 + lane], sl);
    sr = fmaf(x, aw[DH + c * 64 + lane], sr);
  }
  #pragma unroll
  for (int m = 32; m > 0; m >>= 1) {
    s2 += __shfl_xor(s2, m);
    sl += __shfl_xor(sl, m);
    sr += __shfl_xor(sr, m);
  }
  if (lane == 0) { al[i] = sl; ar[i] = sr; inv[i] = rsqrtf(s2); }
}

// ---------------- column sum ----------------
template<int DH>
__global__ void colsum_kernel(const float* __restrict__ h, float* __restrict__ cs) {
  int d = threadIdx.x;             // blockDim == DH
  int r0 = blockIdx.x * (NN / 32);
  float s = 0.f;
  for (int i = 0; i < NN / 32; ++i) s += h[(size_t)(r0 + i) * DH + d];
  atomicAdd(&cs[d], s);
}

// ---------------- fused convert+transpose: h fp32 -> hhi/hlo [NN][DH] + hT bf16 [DH][NN] ----
template<int DH>
__global__ __launch_bounds__(256) void convtrans_kernel(const float* __restrict__ h,
    u16* __restrict__ hhi, u16* __restrict__ hlo, u16* __restrict__ hT) {
  __shared__ u16 tile[32][33];
  int bx = blockIdx.x;   // d / 32
  int by = blockIdx.y;   // i / 32
  int t = threadIdx.x, tx = t & 31, ty8 = t >> 5;   // 32 x 8
  #pragma unroll
  for (int r = 0; r < 4; ++r) {
    int i = by * 32 + ty8 + r * 8;
    int d = bx * 32 + tx;
    float x = h[(size_t)i * DH + d];
    u16 hi = f2bf(x);
    hhi[(size_t)i * DH + d] = hi;
    hlo[(size_t)i * DH + d] = f2bf(x - bf2f(hi));
    tile[ty8 + r * 8][tx] = hi;
  }
  __syncthreads();
  #pragma unroll
  for (int r = 0; r < 4; ++r) {
    int d = bx * 32 + ty8 + r * 8;
    int i = by * 32 + tx;
    hT[(size_t)d * NN + i] = tile[tx][ty8 + r * 8];
  }
}

// ---------------- CSR build (once per launch; structure only) ----------------
__global__ void hist_kernel(const int* __restrict__ src, int* __restrict__ counts) {
  int e = blockIdx.x * 256 + threadIdx.x;
  atomicAdd(&counts[src[e]], 1);
}

__global__ __launch_bounds__(1024) void scan_kernel(const int* __restrict__ counts,
    int* __restrict__ offsets, int* __restrict__ cursor) {
  __shared__ int part[1024];
  int t = threadIdx.x;
  int v[4]; int run = 0;
  #pragma unroll
  for (int j = 0; j < 4; ++j) { v[j] = counts[4 * t + j]; run += v[j]; }
  part[t] = run;
  __syncthreads();
  for (int off = 1; off < 1024; off <<= 1) {
    int y = (t >= off) ? part[t - off] : 0;
    __syncthreads();
    part[t] += y;
    __syncthreads();
  }
  int base = part[t] - run;
  #pragma unroll
  for (int j = 0; j < 4; ++j) { offsets[4 * t + j] = base; cursor[4 * t + j] = base; base += v[j]; }
  if (t == 1023) offsets[NN] = base;
}

__global__ void scatter_idx_kernel(const int* __restrict__ src, const int* __restrict__ dst,
    int* __restrict__ cursor, int* __restrict__ dstS) {
  int e = blockIdx.x * 256 + threadIdx.x;
  int s = src[e];
  int p = atomicAdd(&cursor[s], 1);
  dstS[p] = dst[e];
}

// ---------------- fused edge branch: o = 0.5 * (sum_e e*h[d]) / (sum_e e) ----------------
template<int DH>
__global__ __launch_bounds__(256) void gather_kernel(const float* __restrict__ h,
    const int* __restrict__ offsets, const int* __restrict__ dstS,
    const float* __restrict__ al, const float* __restrict__ ar,
    const float* __restrict__ ab, float* __restrict__ o) {
  constexpr int NC = DH / 64;
  int wid = threadIdx.x >> 6, lane = threadIdx.x & 63;
  int i = blockIdx.x * 4 + wid;
  int beg = offsets[i], end = offsets[i + 1];
  float base = al[i] + ab[0];
  float acc[NC] = {};
  float esum = 0.f;
  for (int k = beg; k < end; ++k) {
    int d = dstS[k];
    float e = expf(lrelu_f(base + ar[d]));
    esum += e;
    #pragma unroll
    for (int c = 0; c < NC; ++c)
      acc[c] = fmaf(e, h[(size_t)d * DH + c * 64 + lane], acc[c]);
  }
  float rd = (beg < end) ? 0.5f / esum : 0.0f;
  #pragma unroll
  for (int c = 0; c < NC; ++c)
    o[(size_t)i * DH + c * 64 + lane] = acc[c] * rd;
}

// ---------------- Pass 1: QK^T (split bf16 MFMA) -> Delta weights W (bf16) + tile flags ----
// Grid (NN/128, NN/128). Block 256 = 4 waves in 2x2; wave (wr,wc) owns the 64x64
// quadrant (i0+64wr, j0+64wc). Flags: each 64x64 cell owned by exactly one wave ->
// plain store (no memset, no atomic).
template<int DH>
__global__ __launch_bounds__(256) void qk_kernel(
    const u16* __restrict__ hhi, const u16* __restrict__ hlo,
    const float* __restrict__ al, const float* __restrict__ ar,
    const float* __restrict__ inv, const float* __restrict__ ab,
    u16* __restrict__ W, int* __restrict__ flags) {
  constexpr int KC = DH / 32;
  __shared__ u16 sA[2][2][128][32];   // [buf][hi/lo][row][col-swizzled]  32KB
  __shared__ u16 sB[2][2][128][32];   //                                   32KB
  int i0 = blockIdx.x * 128;
  int j0 = blockIdx.y * 128;
  int w = threadIdx.x >> 6, l = threadIdx.x & 63;
  int wr = w >> 1, wc = w & 1;
  int lr = l & 15, lk = l >> 4;

  int rl = l >> 2;
  int sc = ((l & 3) ^ ((l >> 3) & 3)) * 8;
  const u16* gAh0 = hhi + (size_t)(i0 + 32 * w + rl) * DH + sc;
  const u16* gAl0 = hlo + (size_t)(i0 + 32 * w + rl) * DH + sc;
  const u16* gBh0 = hhi + (size_t)(j0 + 32 * w + rl) * DH + sc;
  const u16* gBl0 = hlo + (size_t)(j0 + 32 * w + rl) * DH + sc;

  f32x4 acc[4][4];
  #pragma unroll
  for (int q = 0; q < 4; ++q)
    #pragma unroll
    for (int s = 0; s < 4; ++s) acc[q][s] = (f32x4){0.f, 0.f, 0.f, 0.f};

#define QK_STAGE(buf, c) do { \
    gload_lds16(gAh0 + (c) * 32,           &sA[buf][0][32 * w][0]); \
    gload_lds16(gAh0 + 16 * DH + (c) * 32, &sA[buf][0][32 * w + 16][0]); \
    gload_lds16(gAl0 + (c) * 32,           &sA[buf][1][32 * w][0]); \
    gload_lds16(gAl0 + 16 * DH + (c) * 32, &sA[buf][1][32 * w + 16][0]); \
    gload_lds16(gBh0 + (c) * 32,           &sB[buf][0][32 * w][0]); \
    gload_lds16(gBh0 + 16 * DH + (c) * 32, &sB[buf][0][32 * w + 16][0]); \
    gload_lds16(gBl0 + (c) * 32,           &sB[buf][1][32 * w][0]); \
    gload_lds16(gBl0 + 16 * DH + (c) * 32, &sB[buf][1][32 * w + 16][0]); \
  } while (0)

  QK_STAGE(0, 0);
  __syncthreads();

  int cs = (lk ^ ((lr >> 1) & 3)) * 8;   // read-side swizzled chunk
  int cur = 0;
  for (int c = 0; c < KC; ++c) {
    if (c + 1 < KC) QK_STAGE(cur ^ 1, c + 1);
    short8 Ah[4], Al[4], Bh[4], Bl[4];
    #pragma unroll
    for (int q = 0; q < 4; ++q) {
      Ah[q] = *(const short8*)&sA[cur][0][64 * wr + 16 * q + lr][cs];
      Al[q] = *(const short8*)&sA[cur][1][64 * wr + 16 * q + lr][cs];
    }
    #pragma unroll
    for (int s = 0; s < 4; ++s) {
      Bh[s] = *(const short8*)&sB[cur][0][64 * wc + 16 * s + lr][cs];
      Bl[s] = *(const short8*)&sB[cur][1][64 * wc + 16 * s + lr][cs];
    }
    #pragma unroll
    for (int q = 0; q < 4; ++q)
      #pragma unroll
      for (int s = 0; s < 4; ++s) {
        acc[q][s] = __builtin_amdgcn_mfma_f32_16x16x32_bf16(Al[q], Bh[s], acc[q][s], 0, 0, 0);
        acc[q][s] = __builtin_amdgcn_mfma_f32_16x16x32_bf16(Ah[q], Bl[s], acc[q][s], 0, 0, 0);
        acc[q][s] = __builtin_amdgcn_mfma_f32_16x16x32_bf16(Ah[q], Bh[s], acc[q][s], 0, 0, 0);
      }
    __syncthreads();   // drains vmcnt (next chunk staged) + all reads of cur done
    cur ^= 1;
  }
#undef QK_STAGE

  float abv = ab[0];
  int i_base = i0 + 64 * wr + 4 * lk;   // + 16q + qq
  int j_base = j0 + 64 * wc + lr;       // + 16s
  float arj[4], invj[4];
  #pragma unroll
  for (int s = 0; s < 4; ++s) {
    int j = j_base + 16 * s;
    arj[s] = ar[j] + abv;
    invj[s] = inv[j];
  }
  int wany = 0;
  #pragma unroll
  for (int q = 0; q < 4; ++q) {
    float ali_[4], invi_[4];
    #pragma unroll
    for (int qq = 0; qq < 4; ++qq) {
      int i = i_base + 16 * q + qq;
      ali_[qq] = al[i];
      invi_[qq] = inv[i];
    }
    #pragma unroll
    for (int s = 0; s < 4; ++s)
      #pragma unroll
      for (int qq = 0; qq < 4; ++qq) {
        float C = acc[q][s][qq] * invi_[qq] * invj[s];
        float wv = 0.0f;
        if (C > 0.36f) wv = expm1f(C * lrelu_f(ali_[qq] + arj[s]));
        if (wv != 0.0f) wany = 1;
        W[(size_t)(i_base + 16 * q + qq) * NN + j_base + 16 * s] = f2bf(wv);
      }
  }
  int anyv = __any(wany) ? 1 : 0;
  if (l == 0)
    flags[((i0 >> 6) + wr) * 64 + (j0 >> 6) + wc] = anyv;
}

// ---------------- Pass 2: o += h + 0.5*cs + 0.5*(W @ h), flag-gated ----------------
template<int DH>
__global__ __launch_bounds__(256) void pv_kernel(
    const u16* __restrict__ W, const u16* __restrict__ hT,
    const int* __restrict__ flags, const float* __restrict__ h,
    const float* __restrict__ cs, float* __restrict__ o) {
  __shared__ u16 sW[2][16][64];      // W tile: rows i0..i0+15, 64 j (swizzled cols)
  __shared__ u16 sT[2][4][16][64];   // per-wave hT tile: rows d0..d0+15, 64 j
  __shared__ int list[64];
  __shared__ int nact_s;
  int ib = blockIdx.x;
  int w = threadIdx.x >> 6, l = threadIdx.x & 63;
  int lr = l & 15, lk = l >> 4;
  int i0 = ib * 16;
  int d0 = blockIdx.y * 64 + w * 16;
  const int* frow = flags + (i0 >> 6) * 64;
  if (threadIdx.x < 64) {
    int f = frow[threadIdx.x] != 0;
    unsigned long long m = __ballot(f);
    int pos = __popcll(m & ((1ULL << threadIdx.x) - 1ULL));
    if (f) list[pos] = threadIdx.x;
    if (threadIdx.x == 0) nact_s = __popcll(m);
  }
  __syncthreads();
  int nact = nact_s;

  int srow0 = l >> 3;                      // row within 8-row group
  int scol = ((l & 7) * 8) ^ ((srow0 & 7) << 3);
  const u16* gW0 = W + (size_t)(i0 + srow0) * NN + scol;       // + m*8*NN + j0
  const u16* gT0 = hT + (size_t)(d0 + srow0) * NN + scol;
  f32x4 acc0 = {0.f, 0.f, 0.f, 0.f};
  f32x4 acc1 = {0.f, 0.f, 0.f, 0.f};

  if (nact > 0) {
    {
      int j0 = list[0] * 64;
      if (w == 0) {
        gload_lds16(gW0 + j0, &sW[0][0][0]);
        gload_lds16(gW0 + 8 * NN + j0, &sW[0][8][0]);
      }
      gload_lds16(gT0 + j0, &sT[0][w][0][0]);
      gload_lds16(gT0 + 8 * NN + j0, &sT[0][w][8][0]);
    }
    __syncthreads();
    int cur = 0;
    for (int t = 0; t < nact; ++t) {
      if (t + 1 < nact) {
        int jn = list[t + 1] * 64;
        int nb = cur ^ 1;
        if (w == 0) {
          gload_lds16(gW0 + jn, &sW[nb][0][0]);
          gload_lds16(gW0 + 8 * NN + jn, &sW[nb][8][0]);
        }
        gload_lds16(gT0 + jn, &sT[nb][w][0][0]);
        gload_lds16(gT0 + 8 * NN + jn, &sT[nb][w][8][0]);
      }
      int sx = (lr & 7) << 3;                    // read-side XOR for row lr
      short8 a0 = *(const short8*)&sW[cur][lr][(lk * 8) ^ sx];
      short8 a1 = *(const short8*)&sW[cur][lr][(32 + lk * 8) ^ sx];
      short8 b0 = *(const short8*)&sT[cur][w][lr][(lk * 8) ^ sx];
      short8 b1 = *(const short8*)&sT[cur][w][lr][(32 + lk * 8) ^ sx];
      acc0 = __builtin_amdgcn_mfma_f32_16x16x32_bf16(a0, b0, acc0, 0, 0, 0);
      acc1 = __builtin_amdgcn_mfma_f32_16x16x32_bf16(a1, b1, acc1, 0, 0, 0);
      __syncthreads();   // drains vmcnt (next tile staged) + all reads of cur done
      cur ^= 1;
    }
  }

  int d = d0 + lr;
  #pragma unroll
  for (int q = 0; q < 4; ++q) {
    int i = i0 + 4 * lk + q;
    size_t idx = (size_t)i * DH + d;
    o[idx] = o[idx] + h[idx] + 0.5f * cs[d] + 0.5f * (acc0[q] + acc1[q]);
  }
}

// ---------------- final row-normalize (in place on d_out) ----------------
__global__ __launch_bounds__(256) void norm_kernel(float* __restrict__ out) {
  int wid = threadIdx.x >> 6, lane = threadIdx.x & 63;
  int i = blockIdx.x * 4 + wid;
  float x = out[(size_t)i * 64 + lane];
  float s = x * x;
  #pragma unroll
  for (int m = 32; m > 0; m >>= 1) s += __shfl_xor(s, m);
  float n = sqrtf(s);
  out[(size_t)i * 64 + lane] = x / fmaxf(n, 1e-12f);
}

// ---------------- host-side orchestration ----------------
struct Scratch {
  float *al, *ar, *inv, *cs;
  int *counts, *offsets, *cursor, *dstS, *flags;
  u16 *hhi, *hlo, *hT, *W;
  u16 *ghi, *glo, *wthi, *wtlo;
};

template<int DH>
static void run_attention(const float* h, const float* aw, const float* ab, float* o,
                          const Scratch& S, hipStream_t stream) {
  rowstats_kernel<DH><<<NN / 4, 256, 0, stream>>>(h, aw, S.al, S.ar, S.inv);
  hipMemsetAsync(S.cs, 0, DH * sizeof(float), stream);
  colsum_kernel<DH><<<32, DH, 0, stream>>>(h, S.cs);
  convtrans_kernel<DH><<<dim3(DH / 32, NN / 32), 256, 0, stream>>>(h, S.hhi, S.hlo, S.hT);
  gather_kernel<DH><<<NN / 4, 256, 0, stream>>>(h, S.offsets, S.dstS, S.al, S.ar, ab, o);
  qk_kernel<DH><<<dim3(NN / 128, NN / 128), 256, 0, stream>>>(
      S.hhi, S.hlo, S.al, S.ar, S.inv, ab, S.W, S.flags);
  pv_kernel<DH><<<dim3(NN / 16, DH / 64), 256, 0, stream>>>(
      S.W, S.hT, S.flags, h, S.cs, o);
}

extern "C" void kernel_launch(void* const* d_in, const int* in_sizes, int n_in,
                              void* d_out, int out_size, void* d_ws, size_t ws_size,
                              hipStream_t stream) {
  const float* X   = (const float*)d_in[0];
  const int*   ei  = (const int*)d_in[1];
  const float* W1  = (const float*)d_in[2];
  const float* b1  = (const float*)d_in[3];
  const float* a1w = (const float*)d_in[4];
  const float* a1b = (const float*)d_in[5];
  const float* W2  = (const float*)d_in[6];
  const float* b2  = (const float*)d_in[7];
  const float* a2w = (const float*)d_in[8];
  const float* a2b = (const float*)d_in[9];
  const float* W3  = (const float*)d_in[10];
  const float* b3  = (const float*)d_in[11];
  float* out = (float*)d_out;

  const int* src = ei;
  const int* dst = ei + NE;

  char* p = (char*)d_ws;
  auto alloc = [&](size_t bytes) { char* r = p; p += (bytes + 255) & ~(size_t)255; return r; };
  float* h1 = (float*)alloc((size_t)NN * 256 * 4);
  float* o1 = (float*)alloc((size_t)NN * 256 * 4);
  float* h2 = (float*)alloc((size_t)NN * 128 * 4);
  float* o2 = (float*)alloc((size_t)NN * 128 * 4);
  Scratch S;
  S.hhi = (u16*)alloc((size_t)NN * 256 * 2);
  S.hlo = (u16*)alloc((size_t)NN * 256 * 2);
  S.hT  = (u16*)alloc((size_t)NN * 256 * 2);
  S.W   = (u16*)alloc((size_t)NN * NN * 2);
  S.ghi = (u16*)alloc((size_t)NN * 256 * 2);
  S.glo = (u16*)alloc((size_t)NN * 256 * 2);
  S.wthi = (u16*)alloc((size_t)256 * 256 * 2);
  S.wtlo = (u16*)alloc((size_t)256 * 256 * 2);
  S.flags = (int*)alloc(4096 * 4);
  S.al    = (float*)alloc(NN * 4);
  S.ar    = (float*)alloc(NN * 4);
  S.inv   = (float*)alloc(NN * 4);
  S.cs    = (float*)alloc(256 * 4);
  S.counts  = (int*)alloc(NN * 4);
  S.offsets = (int*)alloc((NN + 1) * 4);
  S.cursor  = (int*)alloc(NN * 4);
  S.dstS    = (int*)alloc((size_t)NE * 4);

  // ---- CSR structure: depends only on edge_index; build once ----
  hipMemsetAsync(S.counts, 0, NN * sizeof(int), stream);
  hist_kernel<<<NE / 256, 256, 0, stream>>>(src, S.counts);
  scan_kernel<<<1, 1024, 0, stream>>>(S.counts, S.offsets, S.cursor);
  scatter_idx_kernel<<<NE / 256, 256, 0, stream>>>(src, dst, S.cursor, S.dstS);

  // ---- layer 1: h1 = X @ W1 + b1 (MFMA, split bf16) ----
  wtrans_kernel<<<dim3(256 / 32, 128 / 32), 256, 0, stream>>>(W1, S.wthi, S.wtlo, 128, 256);
  convert_io_kernel<false><<<NN * 128 / 256, 256, 0, stream>>>(X, S.ghi, S.glo);
  mgemm_kernel<128, 256><<<dim3(NN / 16, 256 / 64), 256, 0, stream>>>(
      S.ghi, S.glo, S.wthi, S.wtlo, b1, h1);
  run_attention<256>(h1, a1w, a1b, o1, S, stream);

  // ---- layer 2: h2 = relu(o1) @ W2 + b2 ----
  wtrans_kernel<<<dim3(128 / 32, 256 / 32), 256, 0, stream>>>(W2, S.wthi, S.wtlo, 256, 128);
  convert_io_kernel<true><<<NN * 256 / 256, 256, 0, stream>>>(o1, S.ghi, S.glo);
  mgemm_kernel<256, 128><<<dim3(NN / 16, 128 / 64), 256, 0, stream>>>(
      S.ghi, S.glo, S.wthi, S.wtlo, b2, h2);
  run_attention<128>(h2, a2w, a2b, o2, S, stream);

  // ---- output layer: out = relu(o2) @ W3 + b3, then normalize ----
  wtrans_kernel<<<dim3(64 / 32, 128 / 32), 256, 0, stream>>>(W3, S.wthi, S.wtlo, 128, 64);
  convert_io_kernel<true><<<NN * 128 / 256, 256, 0, stream>>>(o2, S.ghi, S.glo);
  mgemm_kernel<128, 64><<<dim3(NN / 16, 64 / 64), 256, 0, stream>>>(
      S.ghi, S.glo, S.wthi, S.wtlo, b3, out);
  norm_kernel<<<NN / 4, 256, 0, stream>>>(out);
}